// Round 7
// baseline (306.442 us; speedup 1.0000x reference)
//
#include <hip/hip_runtime.h>

// SLAYER constants
#define ALPHA  0.90483741803595952f   /* exp(-1/10) */
#define ALPHA8 0.44932896411722156f   /* exp(-0.8)  */
#define THETA  10.0f
#define BF1    ((unsigned short)0x3F80) /* 1.0f as bf16 */

typedef short   bf16x8 __attribute__((ext_vector_type(8)));
typedef float   f32x4  __attribute__((ext_vector_type(4)));
typedef float   f32x4v __attribute__((ext_vector_type(4)));
typedef unsigned short ushort4v __attribute__((ext_vector_type(4)));
typedef unsigned short ushort8v __attribute__((ext_vector_type(8)));

// RNE float -> bf16 bits
__device__ __forceinline__ unsigned short f2bf(float f) {
    unsigned int x = __float_as_uint(f);
    unsigned int r = (x + 0x7FFFu + ((x >> 16) & 1u)) >> 16;
    return (unsigned short)r;
}
__device__ __forceinline__ float bf2f(unsigned short h) {
    return __uint_as_float(((unsigned int)h) << 16);
}
// 2-way bf16 split: w ~= h0+h1 (residual ~2^-17 rel; spike margins are huge)
__device__ __forceinline__ void split2(float w, unsigned short& h0,
                                       unsigned short& h1) {
    h0 = f2bf(w);          float r0 = w - bf2f(h0);
    h1 = f2bf(r0);
}

// ---------------------------------------------------------------------------
// Prep: In fp32 [32][156][2048] -> Inbf ushort [32*156][2048] (row-major bf16)
//                               -> InT  ushort [32][2048][160] (transposed, c pad 160)
// ---------------------------------------------------------------------------
__global__ __launch_bounds__(256) void prep_in(
    const float* __restrict__ In, unsigned short* __restrict__ Inbf,
    unsigned short* __restrict__ InT)
{
    __shared__ float Tile[64][65];
    const int t0 = blockIdx.x * 64;
    const int c0 = blockIdx.y * 64;
    const int b  = blockIdx.z;
    const int tid = threadIdx.x;

    #pragma unroll
    for (int s = 0; s < 4; ++s) {
        int id = tid + s * 256;
        int cc = id >> 4;
        int t4 = (id & 15) * 4;
        f32x4v v = {0.f, 0.f, 0.f, 0.f};
        if (c0 + cc < 156)
            v = *(const f32x4v*)(In + ((long long)(b * 156 + c0 + cc) * 2048 + t0 + t4));
        *(f32x4v*)&Tile[cc][t4] = v;
    }
    __syncthreads();

    #pragma unroll
    for (int s = 0; s < 2; ++s) {
        int id = tid + s * 256;
        int t  = id >> 3;
        int c8 = (id & 7) * 8;
        unsigned short r[8];
        #pragma unroll
        for (int j = 0; j < 8; ++j) r[j] = f2bf(Tile[c8 + j][t]);
        *(ushort8v*)(InT + (long long)b * 327680 + (long long)(t0 + t) * 160 + c0 + c8)
            = *(ushort8v*)r;
    }
    #pragma unroll
    for (int s = 0; s < 2; ++s) {
        int id = tid + s * 256;
        int cc = id >> 3;
        int t8 = (id & 7) * 8;
        if (c0 + cc < 156) {
            unsigned short r[8];
            #pragma unroll
            for (int j = 0; j < 8; ++j) r[j] = f2bf(Tile[cc][t8 + j]);
            *(ushort8v*)(Inbf + (long long)(b * 156 + c0 + cc) * 2048 + t0 + t8)
                = *(ushort8v*)r;
        }
    }
}

// ---------------------------------------------------------------------------
// Pack all 4 weight matrices into split-2 bf16 planes in ONE launch.
// grid: 512 (W1) + 32 (W2) + 512 (Wl1) + 32 (Wl2) = 1088 blocks.
// ---------------------------------------------------------------------------
__global__ __launch_bounds__(256) void pack_all(
    const float* __restrict__ W1,  const float* __restrict__ W2,
    const float* __restrict__ Wl1, const float* __restrict__ Wl2,
    unsigned short* __restrict__ W1p,  unsigned short* __restrict__ W2p,
    unsigned short* __restrict__ Wl1p, unsigned short* __restrict__ Wl2p)
{
    const int bidx = blockIdx.x;
    const float* W; unsigned short* P; int M, K, Kp, Mp, m;
    if (bidx < 512)       { W = W1;  P = W1p;  M = 512; K = 156;  Kp = 160;  Mp = 512; m = bidx; }
    else if (bidx < 544)  { W = W2;  P = W2p;  M = 20;  K = 512;  Kp = 512;  Mp = 32;  m = bidx - 512; }
    else if (bidx < 1056) { W = Wl1; P = Wl1p; M = 512; K = 2048; Kp = 2048; Mp = 512; m = bidx - 544; }
    else                  { W = Wl2; P = Wl2p; M = 20;  K = 512;  Kp = 512;  Mp = 32;  m = bidx - 1056; }

    for (int k = threadIdx.x; k < Kp; k += 256) {
        float v = (m < M && k < K) ? W[(long long)m * K + k] : 0.f;
        unsigned short h0, h1;
        split2(v, h0, h1);
        P[(long long)m * Kp + k] = h0;
        P[(long long)Mp * Kp + (long long)m * Kp + k] = h1;
    }
}

// ---------------------------------------------------------------------------
// Branch-1 GEMM1 (MFMA, packed split-2):
//   D1[b][m][n] = sum_c W1[m][c] * In[b][c][n],  M=512, N=2048, K=160
// Tile 128x128, BK=32, 5 iters. grid (16 n, 4 m, 32 b).
// ---------------------------------------------------------------------------
__global__ __launch_bounds__(256) void gemm1_mfma(
    const unsigned short* __restrict__ W1p,
    const unsigned short* __restrict__ InT,
    float* __restrict__ D1)
{
    __shared__ alignas(16) unsigned short As[2][128][40];
    __shared__ alignas(16) unsigned short Bs[128][40];

    const int z  = blockIdx.z;
    const int m0 = blockIdx.y * 128;
    const int n0 = blockIdx.x * 128;
    const int tid  = threadIdx.x;
    const int lane = tid & 63, w = tid >> 6;
    const int wy = w >> 1, wx = w & 1;
    const int l15 = lane & 15, kq = lane >> 4;

    const unsigned short* Tb = InT + (long long)z * 327680;

    f32x4 acc[4][4] = {};

    for (int k0 = 0; k0 < 160; k0 += 32) {
        #pragma unroll
        for (int s = 0; s < 4; ++s) {
            int id = tid + s * 256;
            int pl = id >> 9, rem = id & 511;
            int m = rem >> 2, k8 = (rem & 3) * 8;
            ushort8v v = *(const ushort8v*)(W1p + (long long)pl * 81920 +
                                            (long long)(m0 + m) * 160 + k0 + k8);
            *(ushort8v*)&As[pl][m][k8] = v;
        }
        #pragma unroll
        for (int s = 0; s < 2; ++s) {
            int id = tid + s * 256;
            int t = id >> 2, c8 = (id & 3) * 8;
            ushort8v v = *(const ushort8v*)(Tb + (long long)(n0 + t) * 160 + k0 + c8);
            *(ushort8v*)&Bs[t][c8] = v;
        }
        __syncthreads();

        bf16x8 bfr[4];
        #pragma unroll
        for (int nt = 0; nt < 4; ++nt)
            bfr[nt] = *(const bf16x8*)&Bs[wx * 64 + nt * 16 + l15][kq * 8];
        #pragma unroll
        for (int s = 0; s < 2; ++s) {
            #pragma unroll
            for (int mt = 0; mt < 4; ++mt) {
                bf16x8 afr = *(const bf16x8*)&As[s][wy * 64 + mt * 16 + l15][kq * 8];
                #pragma unroll
                for (int nt = 0; nt < 4; ++nt)
                    acc[mt][nt] = __builtin_amdgcn_mfma_f32_16x16x32_bf16(
                        afr, bfr[nt], acc[mt][nt], 0, 0, 0);
            }
        }
        __syncthreads();
    }

    float* Db = D1 + (long long)z * 512 * 2048;
    #pragma unroll
    for (int mt = 0; mt < 4; ++mt) {
        #pragma unroll
        for (int i = 0; i < 4; ++i) {
            int m = m0 + wy * 64 + mt * 16 + kq * 4 + i;
            #pragma unroll
            for (int nt = 0; nt < 4; ++nt) {
                int n = n0 + wx * 64 + nt * 16 + l15;
                Db[(long long)m * 2048 + n] = acc[mt][nt][i];
            }
        }
    }
}

// ---------------------------------------------------------------------------
// Branch-2 GEMM1 (MFMA, packed split-2), batch merged into N, SPLIT-K x4:
//   Zp[s][c][b*512+m] (c-major) = sum_{k in slice s} Wl1[m][k] * InF[n][k]
//   n = b*156+c.  M=512, N=4992, K=2048 (4 slices of 512).
// Tile 64m x 128n, BK=64. grid (39, 8, 4) = 1248 blocks, LDS 36.9 KB.
// Epilogue: LDS transpose (overlaid on staging LDS) -> coalesced c-major.
// ---------------------------------------------------------------------------
__global__ __launch_bounds__(256) void gemmL1_mfma(
    const unsigned short* __restrict__ Wl1p,  // [2][512][2048]
    const unsigned short* __restrict__ InF,   // [4992][2048] bf16
    float* __restrict__ Zp)                   // [4][156][16384] c-major partials
{
    __shared__ alignas(16) unsigned short SMEM[18432];  // 36.9 KB
    auto As = (unsigned short (*)[64][72])SMEM;         // [2][64][72]
    auto Bs = (unsigned short (*)[72])(SMEM + 9216);    // [128][72]

    const int n0  = blockIdx.x * 128;
    const int m0  = blockIdx.y * 64;
    const int ks0 = blockIdx.z * 512;
    const int tid  = threadIdx.x;
    const int lane = tid & 63, w = tid >> 6;
    const int wy = w >> 1, wx = w & 1;   // wy: m-half (32), wx: n-half (64)
    const int l15 = lane & 15, kq = lane >> 4;

    f32x4 acc[2][4] = {};

    for (int kk = 0; kk < 512; kk += 64) {
        const int k0 = ks0 + kk;
        // A: 2 planes x 64m x 64k = 1024 ushort8 chunks, 4/thread
        #pragma unroll
        for (int s = 0; s < 4; ++s) {
            int id = tid + s * 256;
            int pl = id >> 9, rem = id & 511;
            int m = rem >> 3, k8 = (rem & 7) * 8;
            ushort8v v = *(const ushort8v*)(Wl1p + (long long)pl * 1048576 +
                                            (long long)(m0 + m) * 2048 + k0 + k8);
            *(ushort8v*)&As[pl][m][k8] = v;
        }
        // B: 128n x 64k = 1024 chunks, 4/thread (rows k-contiguous)
        #pragma unroll
        for (int s = 0; s < 4; ++s) {
            int id = tid + s * 256;
            int n = id >> 3, k8 = (id & 7) * 8;
            ushort8v v = *(const ushort8v*)(InF + (long long)(n0 + n) * 2048 + k0 + k8);
            *(ushort8v*)&Bs[n][k8] = v;
        }
        __syncthreads();

        #pragma unroll
        for (int ks = 0; ks < 2; ++ks) {
            bf16x8 bfr[4];
            #pragma unroll
            for (int nt = 0; nt < 4; ++nt)
                bfr[nt] = *(const bf16x8*)&Bs[wx * 64 + nt * 16 + l15][ks * 32 + kq * 8];
            #pragma unroll
            for (int s = 0; s < 2; ++s) {
                #pragma unroll
                for (int mt = 0; mt < 2; ++mt) {
                    bf16x8 afr = *(const bf16x8*)&As[s][wy * 32 + mt * 16 + l15][ks * 32 + kq * 8];
                    #pragma unroll
                    for (int nt = 0; nt < 4; ++nt)
                        acc[mt][nt] = __builtin_amdgcn_mfma_f32_16x16x32_bf16(
                            afr, bfr[nt], acc[mt][nt], 0, 0, 0);
                }
            }
        }
        __syncthreads();
    }

    // Epilogue: transpose 64m x 128n tile through LDS (64 x 129 floats =
    // 33 KB, fits in the 36.9 KB staging buffer), then c-major stores.
    float* T = (float*)SMEM;
    #pragma unroll
    for (int mt = 0; mt < 2; ++mt) {
        #pragma unroll
        for (int i = 0; i < 4; ++i) {
            int mL = wy * 32 + mt * 16 + kq * 4 + i;
            #pragma unroll
            for (int nt = 0; nt < 4; ++nt) {
                int nL = wx * 64 + nt * 16 + l15;
                T[mL * 129 + nL] = acc[mt][nt][i];
            }
        }
    }
    __syncthreads();

    float* Zs = Zp + (long long)blockIdx.z * 2555904;
    #pragma unroll
    for (int s2 = 0; s2 < 32; ++s2) {
        int id = tid + s2 * 256;       // 0..8191
        int cL = id >> 6;              // local n 0..127
        int mL = id & 63;
        int n = n0 + cL;
        int bb = n / 156, cc = n - bb * 156;
        Zs[(long long)cc * 16384 + bb * 512 + m0 + mL] = T[mL * 129 + cL];
    }
}

// ---------------------------------------------------------------------------
// Branch-1 GEMM2 (MFMA, packed split-2 A, split-K via blockIdx.y):
//   Cpart[y][b][m][n] = sum_{k in slice y} A[m][k] * Bsp[b][k][n]
// Tile 32m x 128n, BK=64. grid (16, 2, 32).
// ---------------------------------------------------------------------------
__global__ __launch_bounds__(256) void gemm2_mfma(
    const unsigned short* __restrict__ Ap,
    const unsigned short* __restrict__ Bsp,
    float* __restrict__ C,
    int N, int ldb, long long bStrideB, long long cStride,
    int kPerSlice, long long partStride)
{
    __shared__ alignas(16) unsigned short As[2][32][72];
    __shared__ alignas(16) unsigned short Bs[128][72];

    const int b   = blockIdx.z;
    const int n0  = blockIdx.x * 128;
    const int ks0 = blockIdx.y * kPerSlice;
    const int tid  = threadIdx.x;
    const int lane = tid & 63, w = tid >> 6;
    const int l15 = lane & 15, kq = lane >> 4;

    const unsigned short* Bb = Bsp + (long long)b * bStrideB;

    f32x4 acc[2][2] = {};

    for (int kk = 0; kk < kPerSlice; kk += 64) {
        const int k0 = ks0 + kk;
        #pragma unroll
        for (int s = 0; s < 2; ++s) {
            int id = tid + s * 256;
            int pl = id >> 8, rem = id & 255;
            int m = rem >> 3, k8 = (rem & 7) * 8;
            ushort8v v = *(const ushort8v*)(Ap + (long long)pl * 16384 +
                                            (long long)m * 512 + k0 + k8);
            *(ushort8v*)&As[pl][m][k8] = v;
        }
        {
            int kb = (tid >> 4) * 4;
            int nb = (tid & 15) * 8;
            unsigned short rv[4][8];
            #pragma unroll
            for (int kk2 = 0; kk2 < 4; ++kk2) {
                const unsigned short* src =
                    Bb + (long long)(k0 + kb + kk2) * ldb + n0 + nb;
                *(ushort8v*)rv[kk2] = *(const ushort8v*)src;
            }
            #pragma unroll
            for (int j = 0; j < 8; ++j) {
                ushort4v v4 = { rv[0][j], rv[1][j], rv[2][j], rv[3][j] };
                *(ushort4v*)&Bs[nb + j][kb] = v4;
            }
        }
        __syncthreads();

        #pragma unroll
        for (int ks = 0; ks < 2; ++ks) {
            bf16x8 bfr[2];
            #pragma unroll
            for (int nt = 0; nt < 2; ++nt)
                bfr[nt] = *(const bf16x8*)&Bs[w * 32 + nt * 16 + l15][ks * 32 + kq * 8];
            #pragma unroll
            for (int s = 0; s < 2; ++s) {
                #pragma unroll
                for (int mt = 0; mt < 2; ++mt) {
                    bf16x8 afr = *(const bf16x8*)&As[s][mt * 16 + l15][ks * 32 + kq * 8];
                    #pragma unroll
                    for (int nt = 0; nt < 2; ++nt)
                        acc[mt][nt] = __builtin_amdgcn_mfma_f32_16x16x32_bf16(
                            afr, bfr[nt], acc[mt][nt], 0, 0, 0);
                }
            }
        }
        __syncthreads();
    }

    float* Cb = C + (long long)b * cStride + (long long)blockIdx.y * partStride;
    #pragma unroll
    for (int mt = 0; mt < 2; ++mt) {
        #pragma unroll
        for (int i = 0; i < 4; ++i) {
            int m = mt * 16 + kq * 4 + i;
            if (m >= 20) continue;
            #pragma unroll
            for (int nt = 0; nt < 2; ++nt) {
                int n = n0 + w * 32 + nt * 16 + l15;
                Cb[(long long)m * N + n] = acc[mt][nt][i];
            }
        }
    }
}

// ---------------------------------------------------------------------------
// Branch-2 layer-2 GEMM: C[b][m][c] = sum_h Wl2[m][h] * L1T[c][b*512+h]
// ---------------------------------------------------------------------------
__global__ __launch_bounds__(256) void gemm2B_mfma(
    const unsigned short* __restrict__ Ap,   // [2][32][512] Wl2 planes
    const unsigned short* __restrict__ L1T,  // [156][16384] bf16 spikes
    float* __restrict__ Cl2)                 // [32][20][156]
{
    __shared__ alignas(16) unsigned short As[2][32][72];
    __shared__ alignas(16) unsigned short Bs[128][72];

    const int b  = blockIdx.z;
    const int n0 = blockIdx.x * 128;
    const int tid  = threadIdx.x;
    const int lane = tid & 63, w = tid >> 6;
    const int l15 = lane & 15, kq = lane >> 4;

    f32x4 acc[2][2] = {};

    for (int k0 = 0; k0 < 512; k0 += 64) {
        #pragma unroll
        for (int s = 0; s < 2; ++s) {
            int id = tid + s * 256;
            int pl = id >> 8, rem = id & 255;
            int m = rem >> 3, k8 = (rem & 7) * 8;
            ushort8v v = *(const ushort8v*)(Ap + (long long)pl * 16384 +
                                            (long long)m * 512 + k0 + k8);
            *(ushort8v*)&As[pl][m][k8] = v;
        }
        #pragma unroll
        for (int s = 0; s < 4; ++s) {
            int id = tid + s * 256;
            int n = id >> 3, k8 = (id & 7) * 8;
            ushort8v v = {0,0,0,0,0,0,0,0};
            if (n0 + n < 156)
                v = *(const ushort8v*)(L1T + (long long)(n0 + n) * 16384 +
                                       b * 512 + k0 + k8);
            *(ushort8v*)&Bs[n][k8] = v;
        }
        __syncthreads();

        #pragma unroll
        for (int ks = 0; ks < 2; ++ks) {
            bf16x8 bfr[2];
            #pragma unroll
            for (int nt = 0; nt < 2; ++nt)
                bfr[nt] = *(const bf16x8*)&Bs[w * 32 + nt * 16 + l15][ks * 32 + kq * 8];
            #pragma unroll
            for (int s = 0; s < 2; ++s) {
                #pragma unroll
                for (int mt = 0; mt < 2; ++mt) {
                    bf16x8 afr = *(const bf16x8*)&As[s][mt * 16 + l15][ks * 32 + kq * 8];
                    #pragma unroll
                    for (int nt = 0; nt < 2; ++nt)
                        acc[mt][nt] = __builtin_amdgcn_mfma_f32_16x16x32_bf16(
                            afr, bfr[nt], acc[mt][nt], 0, 0, 0);
                }
            }
        }
        __syncthreads();
    }

    float* Cb = Cl2 + (long long)b * 20 * 156;
    #pragma unroll
    for (int mt = 0; mt < 2; ++mt) {
        #pragma unroll
        for (int i = 0; i < 4; ++i) {
            int m = mt * 16 + kq * 4 + i;
            if (m >= 20) continue;
            #pragma unroll
            for (int nt = 0; nt < 2; ++nt) {
                int n = n0 + w * 32 + nt * 16 + l15;
                if (n < 156) Cb[(long long)m * 156 + n] = acc[mt][nt][i];
            }
        }
    }
}

// ---------------------------------------------------------------------------
// Parallel alpha-scan + spike over T=2048 per row -> bf16 (in-place overlay).
// ---------------------------------------------------------------------------
template <typename OutT>
__global__ __launch_bounds__(256) void scan_spike_T(
    const float* in, OutT* out, long long out_stride, int out_offset)
{
    const int row = blockIdx.x;
    const int tid = threadIdx.x;
    const float* x = in + (long long)row * 2048 + tid * 8;

    float v[8];
    #pragma unroll
    for (int k = 0; k < 8; ++k) v[k] = x[k];

    float y = 0.f;
    #pragma unroll
    for (int k = 0; k < 8; ++k) { y = ALPHA * y + v[k]; v[k] = y; }

    __shared__ float sc[256];
    float val = y;
    sc[tid] = val;
    float m = ALPHA8;
    for (int d = 1; d < 256; d <<= 1) {
        __syncthreads();
        float p = (tid >= d) ? sc[tid - d] : 0.f;
        __syncthreads();
        val += m * p;
        sc[tid] = val;
        m *= m;
    }
    __syncthreads();
    float carry = (tid > 0) ? sc[tid - 1] : 0.f;

    OutT* o = out + (long long)row * out_stride + out_offset + tid * 8;
    float ak = ALPHA;
    OutT ovals[8];
    #pragma unroll
    for (int k = 0; k < 8; ++k) {
        float yk = v[k] + ak * carry;
        ak *= ALPHA;
        bool sp = (yk >= THETA);
        if constexpr (sizeof(OutT) == 2)
            ovals[k] = sp ? (OutT)BF1 : (OutT)0;
        else
            ovals[k] = sp ? (OutT)1.0f : (OutT)0.0f;
    }
    #pragma unroll
    for (int k = 0; k < 8; ++k) o[k] = ovals[k];
}

// ---------------------------------------------------------------------------
// Final T-scan summing two split-K partials -> fp32 spikes to d_out.
// ---------------------------------------------------------------------------
__global__ __launch_bounds__(256) void scan_spike_T2(
    const float* __restrict__ in, long long partStride,
    float* __restrict__ out, long long out_stride)
{
    const int row = blockIdx.x;
    const int tid = threadIdx.x;
    const float* x = in + (long long)row * 2048 + tid * 8;

    float v[8];
    #pragma unroll
    for (int k = 0; k < 8; ++k) v[k] = x[k] + x[k + partStride];

    float y = 0.f;
    #pragma unroll
    for (int k = 0; k < 8; ++k) { y = ALPHA * y + v[k]; v[k] = y; }

    __shared__ float sc[256];
    float val = y;
    sc[tid] = val;
    float m = ALPHA8;
    for (int d = 1; d < 256; d <<= 1) {
        __syncthreads();
        float p = (tid >= d) ? sc[tid - d] : 0.f;
        __syncthreads();
        val += m * p;
        sc[tid] = val;
        m *= m;
    }
    __syncthreads();
    float carry = (tid > 0) ? sc[tid - 1] : 0.f;

    float* o = out + (long long)row * out_stride + tid * 8;
    float ak = ALPHA;
    #pragma unroll
    for (int k = 0; k < 8; ++k) {
        float yk = v[k] + ak * carry;
        ak *= ALPHA;
        o[k] = (yk >= THETA) ? 1.0f : 0.0f;
    }
}

// ---------------------------------------------------------------------------
// Branch-2 layer-1 scan, c-major: sum 4 partials Zp[s][c][row] (coalesced),
// scan over c in perm order via LDS, write spikes c-major to L1T[c][row].
// ---------------------------------------------------------------------------
__global__ __launch_bounds__(256) void scan_sum4_perm(
    const float* __restrict__ Zp, const int* __restrict__ perm,
    unsigned short* __restrict__ L1T)
{
    __shared__ float Xs[156][64];   // 39.9 KB
    __shared__ int p[156];

    const int r0  = blockIdx.x * 64;
    const int tid = threadIdx.x;
    for (int i = tid; i < 156; i += 256) p[i] = perm[i];

    const int row = tid & 63;
    const int cq  = tid >> 6;
    #pragma unroll
    for (int it = 0; it < 39; ++it) {
        int c = it * 4 + cq;
        long long base = (long long)c * 16384 + r0 + row;
        float s = Zp[base] + Zp[base + 2555904] +
                  Zp[base + 2 * 2555904] + Zp[base + 3 * 2555904];
        Xs[c][row] = s;
    }
    __syncthreads();

    if (tid < 64) {
        float y = 0.f;
        for (int c = 0; c < 156; ++c) {
            y = ALPHA * y + Xs[p[c]][tid];
            L1T[(long long)c * 16384 + r0 + tid] = (y >= THETA) ? BF1 : 0;
        }
    }
}

__global__ __launch_bounds__(256) void scan_spike_C_out(
    const float* __restrict__ in, float* __restrict__ out, int rows)
{
    int row = blockIdx.x * blockDim.x + threadIdx.x;
    if (row >= rows) return;
    const float* x = in + (long long)row * 156;
    float* o = out + (long long)row * 2204 + 2048;
    float y = 0.f;
    for (int c = 0; c < 156; ++c) {
        y = ALPHA * y + x[c];
        o[c] = (y >= THETA) ? 1.0f : 0.0f;
    }
}

// ---------------------------------------------------------------------------
// B=32, C_IN=156, T=2048, HID=512, OUT=20. Output [32,20,2204].
// ---------------------------------------------------------------------------
extern "C" void kernel_launch(void* const* d_in, const int* in_sizes, int n_in,
                              void* d_out, int out_size, void* d_ws, size_t ws_size,
                              hipStream_t stream)
{
    const float* In  = (const float*)d_in[0];  // [32][156][2048]
    const float* W1  = (const float*)d_in[1];  // [512][156]
    const float* W2  = (const float*)d_in[2];  // [20][512]
    const float* Wl1 = (const float*)d_in[3];  // [512][2048]
    const float* Wl2 = (const float*)d_in[4];  // [20][512]
    const int*  perm = (const int*)d_in[5];    // [156]
    float* out = (float*)d_out;                // [32][20][2204]

    float* ws = (float*)d_ws;
    // Full-batch layout (float offsets), total 190.8 MB (ws is 256 MiB):
    float* D1  = ws;                                   // [32][512][2048] fp32
    unsigned short* S1 = (unsigned short*)D1;          // overlay, row stride 4096 ush
    float* C2p = ws + 33554432LL;                      // [2][32][20][2048] partials
    unsigned short* Inbf = (unsigned short*)(ws + 36175872LL); // [4992][2048]
    unsigned short* InT  = (unsigned short*)(ws + 41287680LL); // [32][2048][160]
    unsigned short* W1p  = (unsigned short*)(ws + 46530560LL); // [2][512][160]
    unsigned short* W2p  = (unsigned short*)(ws + 46612480LL); // [2][32][512]
    unsigned short* Wl1p = (unsigned short*)(ws + 46628864LL); // [2][512][2048]
    unsigned short* Wl2p = (unsigned short*)(ws + 47677440LL); // [2][32][512]
    // Branch-2 phase reuses the dead D1 region:
    float* Zp = ws;                                    // [4][156][16384] c-major
    unsigned short* L1T = (unsigned short*)(ws + 10223616LL);  // [156][16384] bf16
    float* Cl2 = ws + 11501568LL;                      // [32][20][156]

    dim3 blk(256);

    // ---- Preprocess ----
    prep_in<<<dim3(32, 3, 32), blk, 0, stream>>>(In, Inbf, InT);
    pack_all<<<dim3(1088), blk, 0, stream>>>(W1, W2, Wl1, Wl2,
                                             W1p, W2p, Wl1p, Wl2p);

    // ---- Branch 1 (full batch) ----
    gemm1_mfma<<<dim3(16, 4, 32), blk, 0, stream>>>(W1p, InT, D1);
    scan_spike_T<unsigned short><<<dim3(16384), blk, 0, stream>>>(D1, S1, 4096, 0);
    gemm2_mfma<<<dim3(16, 2, 32), blk, 0, stream>>>(
        W2p, S1, C2p, 2048, 4096, 512LL * 4096, 20LL * 2048, 256, 1310720LL);
    scan_spike_T2<<<dim3(640), blk, 0, stream>>>(C2p, 1310720LL, out, 2204);

    // ---- Branch 2 ----
    gemmL1_mfma<<<dim3(39, 8, 4), blk, 0, stream>>>(Wl1p, Inbf, Zp);
    scan_sum4_perm<<<dim3(256), blk, 0, stream>>>(Zp, perm, L1T);
    gemm2B_mfma<<<dim3(2, 1, 32), blk, 0, stream>>>(Wl2p, L1T, Cl2);
    scan_spike_C_out<<<dim3(3), blk, 0, stream>>>(Cl2, out, 640);

    (void)in_sizes; (void)n_in; (void)out_size; (void)ws_size;
}

// Round 8
// 266.582 us; speedup vs baseline: 1.1495x; 1.1495x over previous
//
#include <hip/hip_runtime.h>

// SLAYER constants
#define ALPHA  0.90483741803595952f   /* exp(-1/10) */
#define ALPHA8 0.44932896411722156f   /* exp(-0.8)  */
#define THETA  10.0f
#define BF1    ((unsigned short)0x3F80) /* 1.0f as bf16 */

typedef short   bf16x8 __attribute__((ext_vector_type(8)));
typedef float   f32x4  __attribute__((ext_vector_type(4)));
typedef float   f32x4v __attribute__((ext_vector_type(4)));
typedef unsigned short ushort4v __attribute__((ext_vector_type(4)));
typedef unsigned short ushort8v __attribute__((ext_vector_type(8)));

// RNE float -> bf16 bits
__device__ __forceinline__ unsigned short f2bf(float f) {
    unsigned int x = __float_as_uint(f);
    unsigned int r = (x + 0x7FFFu + ((x >> 16) & 1u)) >> 16;
    return (unsigned short)r;
}
__device__ __forceinline__ float bf2f(unsigned short h) {
    return __uint_as_float(((unsigned int)h) << 16);
}
// 2-way bf16 split: w ~= h0+h1 (residual ~2^-17 rel; spike margins are ~6 sigma)
__device__ __forceinline__ void split2(float w, unsigned short& h0,
                                       unsigned short& h1) {
    h0 = f2bf(w);          float r0 = w - bf2f(h0);
    h1 = f2bf(r0);
}

// ---------------------------------------------------------------------------
// Prep: In fp32 [32][156][2048] -> Inbf ushort [32*156][2048] (row-major bf16)
//                               -> InT  ushort [32][2048][160] (transposed, c pad 160)
// ---------------------------------------------------------------------------
__global__ __launch_bounds__(256) void prep_in(
    const float* __restrict__ In, unsigned short* __restrict__ Inbf,
    unsigned short* __restrict__ InT)
{
    __shared__ float Tile[64][65];
    const int t0 = blockIdx.x * 64;
    const int c0 = blockIdx.y * 64;
    const int b  = blockIdx.z;
    const int tid = threadIdx.x;

    #pragma unroll
    for (int s = 0; s < 4; ++s) {
        int id = tid + s * 256;
        int cc = id >> 4;
        int t4 = (id & 15) * 4;
        f32x4v v = {0.f, 0.f, 0.f, 0.f};
        if (c0 + cc < 156)
            v = *(const f32x4v*)(In + ((long long)(b * 156 + c0 + cc) * 2048 + t0 + t4));
        *(f32x4v*)&Tile[cc][t4] = v;
    }
    __syncthreads();

    #pragma unroll
    for (int s = 0; s < 2; ++s) {
        int id = tid + s * 256;
        int t  = id >> 3;
        int c8 = (id & 7) * 8;
        unsigned short r[8];
        #pragma unroll
        for (int j = 0; j < 8; ++j) r[j] = f2bf(Tile[c8 + j][t]);
        *(ushort8v*)(InT + (long long)b * 327680 + (long long)(t0 + t) * 160 + c0 + c8)
            = *(ushort8v*)r;
    }
    #pragma unroll
    for (int s = 0; s < 2; ++s) {
        int id = tid + s * 256;
        int cc = id >> 3;
        int t8 = (id & 7) * 8;
        if (c0 + cc < 156) {
            unsigned short r[8];
            #pragma unroll
            for (int j = 0; j < 8; ++j) r[j] = f2bf(Tile[cc][t8 + j]);
            *(ushort8v*)(Inbf + (long long)(b * 156 + c0 + cc) * 2048 + t0 + t8)
                = *(ushort8v*)r;
        }
    }
}

// ---------------------------------------------------------------------------
// Pack all 4 weight matrices into split-2 bf16 planes in ONE launch.
// ---------------------------------------------------------------------------
__global__ __launch_bounds__(256) void pack_all(
    const float* __restrict__ W1,  const float* __restrict__ W2,
    const float* __restrict__ Wl1, const float* __restrict__ Wl2,
    unsigned short* __restrict__ W1p,  unsigned short* __restrict__ W2p,
    unsigned short* __restrict__ Wl1p, unsigned short* __restrict__ Wl2p)
{
    const int bidx = blockIdx.x;
    const float* W; unsigned short* P; int M, K, Kp, Mp, m;
    if (bidx < 512)       { W = W1;  P = W1p;  M = 512; K = 156;  Kp = 160;  Mp = 512; m = bidx; }
    else if (bidx < 544)  { W = W2;  P = W2p;  M = 20;  K = 512;  Kp = 512;  Mp = 32;  m = bidx - 512; }
    else if (bidx < 1056) { W = Wl1; P = Wl1p; M = 512; K = 2048; Kp = 2048; Mp = 512; m = bidx - 544; }
    else                  { W = Wl2; P = Wl2p; M = 20;  K = 512;  Kp = 512;  Mp = 32;  m = bidx - 1056; }

    for (int k = threadIdx.x; k < Kp; k += 256) {
        float v = (m < M && k < K) ? W[(long long)m * K + k] : 0.f;
        unsigned short h0, h1;
        split2(v, h0, h1);
        P[(long long)m * Kp + k] = h0;
        P[(long long)Mp * Kp + (long long)m * Kp + k] = h1;
    }
}

// ---------------------------------------------------------------------------
// Branch-1 GEMM1 (MFMA, packed split-2), OUTPUT IN BF16:
//   D1[b][m][n] = sum_c W1[m][c] * In[b][c][n],  M=512, N=2048, K=160
// Tile 128x128, BK=32, 5 iters. grid (16 n, 4 m, 32 b).
// ---------------------------------------------------------------------------
__global__ __launch_bounds__(256) void gemm1_mfma(
    const unsigned short* __restrict__ W1p,
    const unsigned short* __restrict__ InT,
    unsigned short* __restrict__ D1)     // [32][512][2048] bf16
{
    __shared__ alignas(16) unsigned short As[2][128][40];
    __shared__ alignas(16) unsigned short Bs[128][40];

    const int z  = blockIdx.z;
    const int m0 = blockIdx.y * 128;
    const int n0 = blockIdx.x * 128;
    const int tid  = threadIdx.x;
    const int lane = tid & 63, w = tid >> 6;
    const int wy = w >> 1, wx = w & 1;
    const int l15 = lane & 15, kq = lane >> 4;

    const unsigned short* Tb = InT + (long long)z * 327680;

    f32x4 acc[4][4] = {};

    for (int k0 = 0; k0 < 160; k0 += 32) {
        #pragma unroll
        for (int s = 0; s < 4; ++s) {
            int id = tid + s * 256;
            int pl = id >> 9, rem = id & 511;
            int m = rem >> 2, k8 = (rem & 3) * 8;
            ushort8v v = *(const ushort8v*)(W1p + (long long)pl * 81920 +
                                            (long long)(m0 + m) * 160 + k0 + k8);
            *(ushort8v*)&As[pl][m][k8] = v;
        }
        #pragma unroll
        for (int s = 0; s < 2; ++s) {
            int id = tid + s * 256;
            int t = id >> 2, c8 = (id & 3) * 8;
            ushort8v v = *(const ushort8v*)(Tb + (long long)(n0 + t) * 160 + k0 + c8);
            *(ushort8v*)&Bs[t][c8] = v;
        }
        __syncthreads();

        bf16x8 bfr[4];
        #pragma unroll
        for (int nt = 0; nt < 4; ++nt)
            bfr[nt] = *(const bf16x8*)&Bs[wx * 64 + nt * 16 + l15][kq * 8];
        #pragma unroll
        for (int s = 0; s < 2; ++s) {
            #pragma unroll
            for (int mt = 0; mt < 4; ++mt) {
                bf16x8 afr = *(const bf16x8*)&As[s][wy * 64 + mt * 16 + l15][kq * 8];
                #pragma unroll
                for (int nt = 0; nt < 4; ++nt)
                    acc[mt][nt] = __builtin_amdgcn_mfma_f32_16x16x32_bf16(
                        afr, bfr[nt], acc[mt][nt], 0, 0, 0);
            }
        }
        __syncthreads();
    }

    unsigned short* Db = D1 + (long long)z * 512 * 2048;
    #pragma unroll
    for (int mt = 0; mt < 4; ++mt) {
        #pragma unroll
        for (int i = 0; i < 4; ++i) {
            int m = m0 + wy * 64 + mt * 16 + kq * 4 + i;
            #pragma unroll
            for (int nt = 0; nt < 4; ++nt) {
                int n = n0 + wx * 64 + nt * 16 + l15;
                Db[(long long)m * 2048 + n] = f2bf(acc[mt][nt][i]);
            }
        }
    }
}

// ---------------------------------------------------------------------------
// Branch-2 GEMM1 (MFMA, packed split-2), batch merged into N, SPLIT-K x4.
// ROUND-6 CONFIG (measured best): tile 64m x 64n, BK=64, grid (80, 8, 4).
// grid.x padded 78->80 so the 8 m-blocks sharing a B n-tile have linear ids
// congruent mod 8 -> same XCD -> B-tile fetched once per XCD (L2 reuse).
// Epilogue: LDS transpose -> coalesced c-major stores Zp[s][c][b*512+m].
// ---------------------------------------------------------------------------
__global__ __launch_bounds__(256) void gemmL1_mfma(
    const unsigned short* __restrict__ Wl1p,  // [2][512][2048]
    const unsigned short* __restrict__ InF,   // [4992][2048] bf16
    float* __restrict__ Zp)                   // [4][156][16384] c-major partials
{
    __shared__ alignas(16) unsigned short As[2][64][72];
    __shared__ alignas(16) unsigned short Bs[64][72];

    if (blockIdx.x >= 78) return;
    const int n0  = blockIdx.x * 64;
    const int m0  = blockIdx.y * 64;
    const int ks0 = blockIdx.z * 512;
    const int tid  = threadIdx.x;
    const int lane = tid & 63, w = tid >> 6;
    const int wy = w >> 1, wx = w & 1;
    const int l15 = lane & 15, kq = lane >> 4;

    f32x4 acc[2][2] = {};

    for (int kk = 0; kk < 512; kk += 64) {
        const int k0 = ks0 + kk;
        #pragma unroll
        for (int s = 0; s < 4; ++s) {
            int id = tid + s * 256;
            int pl = id >> 9, rem = id & 511;
            int m = rem >> 3, k8 = (rem & 7) * 8;
            ushort8v v = *(const ushort8v*)(Wl1p + (long long)pl * 1048576 +
                                            (long long)(m0 + m) * 2048 + k0 + k8);
            *(ushort8v*)&As[pl][m][k8] = v;
        }
        #pragma unroll
        for (int s = 0; s < 2; ++s) {
            int id = tid + s * 256;
            int n = id >> 3, k8 = (id & 7) * 8;
            ushort8v v = *(const ushort8v*)(InF + (long long)(n0 + n) * 2048 + k0 + k8);
            *(ushort8v*)&Bs[n][k8] = v;
        }
        __syncthreads();

        #pragma unroll
        for (int ks = 0; ks < 2; ++ks) {
            bf16x8 bfr[2];
            #pragma unroll
            for (int nt = 0; nt < 2; ++nt)
                bfr[nt] = *(const bf16x8*)&Bs[wx * 32 + nt * 16 + l15][ks * 32 + kq * 8];
            #pragma unroll
            for (int s = 0; s < 2; ++s) {
                #pragma unroll
                for (int mt = 0; mt < 2; ++mt) {
                    bf16x8 afr = *(const bf16x8*)&As[s][wy * 32 + mt * 16 + l15][ks * 32 + kq * 8];
                    #pragma unroll
                    for (int nt = 0; nt < 2; ++nt)
                        acc[mt][nt] = __builtin_amdgcn_mfma_f32_16x16x32_bf16(
                            afr, bfr[nt], acc[mt][nt], 0, 0, 0);
                }
            }
        }
        __syncthreads();
    }

    // Epilogue: transpose 64x64 tile through LDS (64x65 floats = 16.6 KB,
    // fits in As' 18.4 KB), then store c-major coalesced.
    float* T = (float*)As;
    #pragma unroll
    for (int mt = 0; mt < 2; ++mt) {
        #pragma unroll
        for (int i = 0; i < 4; ++i) {
            int mL = wy * 32 + mt * 16 + kq * 4 + i;
            #pragma unroll
            for (int nt = 0; nt < 2; ++nt) {
                int nL = wx * 32 + nt * 16 + l15;
                T[mL * 65 + nL] = acc[mt][nt][i];
            }
        }
    }
    __syncthreads();

    float* Zs = Zp + (long long)blockIdx.z * 2555904;
    #pragma unroll
    for (int s2 = 0; s2 < 16; ++s2) {
        int id = tid + s2 * 256;       // 0..4095
        int cL = id >> 6;              // local n 0..63
        int mL = id & 63;
        int n = n0 + cL;
        int bb = n / 156, cc = n - bb * 156;
        Zs[(long long)cc * 16384 + bb * 512 + m0 + mL] = T[mL * 65 + cL];
    }
}

// ---------------------------------------------------------------------------
// Branch-1 GEMM2 (MFMA, packed split-2 A, split-K via blockIdx.y):
//   Cpart[y][b][m][n] = sum_{k in slice y} A[m][k] * Bsp[b][k][n]
// Tile 32m x 128n, BK=64. grid (16, 2, 32).
// ---------------------------------------------------------------------------
__global__ __launch_bounds__(256) void gemm2_mfma(
    const unsigned short* __restrict__ Ap,
    const unsigned short* __restrict__ Bsp,
    float* __restrict__ C,
    int N, int ldb, long long bStrideB, long long cStride,
    int kPerSlice, long long partStride)
{
    __shared__ alignas(16) unsigned short As[2][32][72];
    __shared__ alignas(16) unsigned short Bs[128][72];

    const int b   = blockIdx.z;
    const int n0  = blockIdx.x * 128;
    const int ks0 = blockIdx.y * kPerSlice;
    const int tid  = threadIdx.x;
    const int lane = tid & 63, w = tid >> 6;
    const int l15 = lane & 15, kq = lane >> 4;

    const unsigned short* Bb = Bsp + (long long)b * bStrideB;

    f32x4 acc[2][2] = {};

    for (int kk = 0; kk < kPerSlice; kk += 64) {
        const int k0 = ks0 + kk;
        #pragma unroll
        for (int s = 0; s < 2; ++s) {
            int id = tid + s * 256;
            int pl = id >> 8, rem = id & 255;
            int m = rem >> 3, k8 = (rem & 7) * 8;
            ushort8v v = *(const ushort8v*)(Ap + (long long)pl * 16384 +
                                            (long long)m * 512 + k0 + k8);
            *(ushort8v*)&As[pl][m][k8] = v;
        }
        {
            int kb = (tid >> 4) * 4;
            int nb = (tid & 15) * 8;
            unsigned short rv[4][8];
            #pragma unroll
            for (int kk2 = 0; kk2 < 4; ++kk2) {
                const unsigned short* src =
                    Bb + (long long)(k0 + kb + kk2) * ldb + n0 + nb;
                *(ushort8v*)rv[kk2] = *(const ushort8v*)src;
            }
            #pragma unroll
            for (int j = 0; j < 8; ++j) {
                ushort4v v4 = { rv[0][j], rv[1][j], rv[2][j], rv[3][j] };
                *(ushort4v*)&Bs[nb + j][kb] = v4;
            }
        }
        __syncthreads();

        #pragma unroll
        for (int ks = 0; ks < 2; ++ks) {
            bf16x8 bfr[2];
            #pragma unroll
            for (int nt = 0; nt < 2; ++nt)
                bfr[nt] = *(const bf16x8*)&Bs[w * 32 + nt * 16 + l15][ks * 32 + kq * 8];
            #pragma unroll
            for (int s = 0; s < 2; ++s) {
                #pragma unroll
                for (int mt = 0; mt < 2; ++mt) {
                    bf16x8 afr = *(const bf16x8*)&As[s][mt * 16 + l15][ks * 32 + kq * 8];
                    #pragma unroll
                    for (int nt = 0; nt < 2; ++nt)
                        acc[mt][nt] = __builtin_amdgcn_mfma_f32_16x16x32_bf16(
                            afr, bfr[nt], acc[mt][nt], 0, 0, 0);
                }
            }
        }
        __syncthreads();
    }

    float* Cb = C + (long long)b * cStride + (long long)blockIdx.y * partStride;
    #pragma unroll
    for (int mt = 0; mt < 2; ++mt) {
        #pragma unroll
        for (int i = 0; i < 4; ++i) {
            int m = mt * 16 + kq * 4 + i;
            if (m >= 20) continue;
            #pragma unroll
            for (int nt = 0; nt < 2; ++nt) {
                int n = n0 + w * 32 + nt * 16 + l15;
                Cb[(long long)m * N + n] = acc[mt][nt][i];
            }
        }
    }
}

// ---------------------------------------------------------------------------
// Branch-2 layer-2 GEMM: C[b][m][c] = sum_h Wl2[m][h] * L1T[c][b*512+h]
// ---------------------------------------------------------------------------
__global__ __launch_bounds__(256) void gemm2B_mfma(
    const unsigned short* __restrict__ Ap,   // [2][32][512] Wl2 planes
    const unsigned short* __restrict__ L1T,  // [156][16384] bf16 spikes
    float* __restrict__ Cl2)                 // [32][20][156]
{
    __shared__ alignas(16) unsigned short As[2][32][72];
    __shared__ alignas(16) unsigned short Bs[128][72];

    const int b  = blockIdx.z;
    const int n0 = blockIdx.x * 128;
    const int tid  = threadIdx.x;
    const int lane = tid & 63, w = tid >> 6;
    const int l15 = lane & 15, kq = lane >> 4;

    f32x4 acc[2][2] = {};

    for (int k0 = 0; k0 < 512; k0 += 64) {
        #pragma unroll
        for (int s = 0; s < 2; ++s) {
            int id = tid + s * 256;
            int pl = id >> 8, rem = id & 255;
            int m = rem >> 3, k8 = (rem & 7) * 8;
            ushort8v v = *(const ushort8v*)(Ap + (long long)pl * 16384 +
                                            (long long)m * 512 + k0 + k8);
            *(ushort8v*)&As[pl][m][k8] = v;
        }
        #pragma unroll
        for (int s = 0; s < 4; ++s) {
            int id = tid + s * 256;
            int n = id >> 3, k8 = (id & 7) * 8;
            ushort8v v = {0,0,0,0,0,0,0,0};
            if (n0 + n < 156)
                v = *(const ushort8v*)(L1T + (long long)(n0 + n) * 16384 +
                                       b * 512 + k0 + k8);
            *(ushort8v*)&Bs[n][k8] = v;
        }
        __syncthreads();

        #pragma unroll
        for (int ks = 0; ks < 2; ++ks) {
            bf16x8 bfr[2];
            #pragma unroll
            for (int nt = 0; nt < 2; ++nt)
                bfr[nt] = *(const bf16x8*)&Bs[w * 32 + nt * 16 + l15][ks * 32 + kq * 8];
            #pragma unroll
            for (int s = 0; s < 2; ++s) {
                #pragma unroll
                for (int mt = 0; mt < 2; ++mt) {
                    bf16x8 afr = *(const bf16x8*)&As[s][mt * 16 + l15][ks * 32 + kq * 8];
                    #pragma unroll
                    for (int nt = 0; nt < 2; ++nt)
                        acc[mt][nt] = __builtin_amdgcn_mfma_f32_16x16x32_bf16(
                            afr, bfr[nt], acc[mt][nt], 0, 0, 0);
                }
            }
        }
        __syncthreads();
    }

    float* Cb = Cl2 + (long long)b * 20 * 156;
    #pragma unroll
    for (int mt = 0; mt < 2; ++mt) {
        #pragma unroll
        for (int i = 0; i < 4; ++i) {
            int m = mt * 16 + kq * 4 + i;
            if (m >= 20) continue;
            #pragma unroll
            for (int nt = 0; nt < 2; ++nt) {
                int n = n0 + w * 32 + nt * 16 + l15;
                if (n < 156) Cb[(long long)m * 156 + n] = acc[mt][nt][i];
            }
        }
    }
}

// ---------------------------------------------------------------------------
// Alpha-scan + spike over T=2048 per row, bf16 in -> bf16 spikes, IN PLACE.
// All global loads complete before the first __syncthreads; all stores happen
// after the last one -> in-place safe (block touches only its own row).
// ---------------------------------------------------------------------------
__global__ __launch_bounds__(256) void scan_spike_bf(unsigned short* data)
{
    const int row = blockIdx.x;
    const int tid = threadIdx.x;
    unsigned short* x = data + (long long)row * 2048 + tid * 8;

    ushort8v raw = *(const ushort8v*)x;
    float v[8];
    #pragma unroll
    for (int k = 0; k < 8; ++k) v[k] = bf2f(raw[k]);

    float y = 0.f;
    #pragma unroll
    for (int k = 0; k < 8; ++k) { y = ALPHA * y + v[k]; v[k] = y; }

    __shared__ float sc[256];
    float val = y;
    sc[tid] = val;
    float m = ALPHA8;
    for (int d = 1; d < 256; d <<= 1) {
        __syncthreads();
        float p = (tid >= d) ? sc[tid - d] : 0.f;
        __syncthreads();
        val += m * p;
        sc[tid] = val;
        m *= m;
    }
    __syncthreads();
    float carry = (tid > 0) ? sc[tid - 1] : 0.f;

    ushort8v ov;
    float ak = ALPHA;
    #pragma unroll
    for (int k = 0; k < 8; ++k) {
        float yk = v[k] + ak * carry;
        ak *= ALPHA;
        ov[k] = (yk >= THETA) ? BF1 : 0;
    }
    *(ushort8v*)x = ov;
}

// ---------------------------------------------------------------------------
// Final T-scan summing two split-K partials -> fp32 spikes to d_out.
// ---------------------------------------------------------------------------
__global__ __launch_bounds__(256) void scan_spike_T2(
    const float* __restrict__ in, long long partStride,
    float* __restrict__ out, long long out_stride)
{
    const int row = blockIdx.x;
    const int tid = threadIdx.x;
    const float* x = in + (long long)row * 2048 + tid * 8;

    float v[8];
    #pragma unroll
    for (int k = 0; k < 8; ++k) v[k] = x[k] + x[k + partStride];

    float y = 0.f;
    #pragma unroll
    for (int k = 0; k < 8; ++k) { y = ALPHA * y + v[k]; v[k] = y; }

    __shared__ float sc[256];
    float val = y;
    sc[tid] = val;
    float m = ALPHA8;
    for (int d = 1; d < 256; d <<= 1) {
        __syncthreads();
        float p = (tid >= d) ? sc[tid - d] : 0.f;
        __syncthreads();
        val += m * p;
        sc[tid] = val;
        m *= m;
    }
    __syncthreads();
    float carry = (tid > 0) ? sc[tid - 1] : 0.f;

    float* o = out + (long long)row * out_stride + tid * 8;
    float ak = ALPHA;
    #pragma unroll
    for (int k = 0; k < 8; ++k) {
        float yk = v[k] + ak * carry;
        ak *= ALPHA;
        o[k] = (yk >= THETA) ? 1.0f : 0.0f;
    }
}

// ---------------------------------------------------------------------------
// Branch-2 layer-1 scan, c-major: sum 4 partials Zp[s][c][row] (coalesced),
// scan over c in perm order via LDS, write spikes c-major to L1T[c][row].
// ---------------------------------------------------------------------------
__global__ __launch_bounds__(256) void scan_sum4_perm(
    const float* __restrict__ Zp, const int* __restrict__ perm,
    unsigned short* __restrict__ L1T)
{
    __shared__ float Xs[156][64];   // 39.9 KB
    __shared__ int p[156];

    const int r0  = blockIdx.x * 64;
    const int tid = threadIdx.x;
    for (int i = tid; i < 156; i += 256) p[i] = perm[i];

    const int row = tid & 63;
    const int cq  = tid >> 6;
    #pragma unroll
    for (int it = 0; it < 39; ++it) {
        int c = it * 4 + cq;
        long long base = (long long)c * 16384 + r0 + row;
        float s = Zp[base] + Zp[base + 2555904] +
                  Zp[base + 2 * 2555904] + Zp[base + 3 * 2555904];
        Xs[c][row] = s;
    }
    __syncthreads();

    if (tid < 64) {
        float y = 0.f;
        for (int c = 0; c < 156; ++c) {
            y = ALPHA * y + Xs[p[c]][tid];
            L1T[(long long)c * 16384 + r0 + tid] = (y >= THETA) ? BF1 : 0;
        }
    }
}

__global__ __launch_bounds__(256) void scan_spike_C_out(
    const float* __restrict__ in, float* __restrict__ out, int rows)
{
    int row = blockIdx.x * blockDim.x + threadIdx.x;
    if (row >= rows) return;
    const float* x = in + (long long)row * 156;
    float* o = out + (long long)row * 2204 + 2048;
    float y = 0.f;
    for (int c = 0; c < 156; ++c) {
        y = ALPHA * y + x[c];
        o[c] = (y >= THETA) ? 1.0f : 0.0f;
    }
}

// ---------------------------------------------------------------------------
// B=32, C_IN=156, T=2048, HID=512, OUT=20. Output [32,20,2204].
// ---------------------------------------------------------------------------
extern "C" void kernel_launch(void* const* d_in, const int* in_sizes, int n_in,
                              void* d_out, int out_size, void* d_ws, size_t ws_size,
                              hipStream_t stream)
{
    const float* In  = (const float*)d_in[0];  // [32][156][2048]
    const float* W1  = (const float*)d_in[1];  // [512][156]
    const float* W2  = (const float*)d_in[2];  // [20][512]
    const float* Wl1 = (const float*)d_in[3];  // [512][2048]
    const float* Wl2 = (const float*)d_in[4];  // [20][512]
    const int*  perm = (const int*)d_in[5];    // [156]
    float* out = (float*)d_out;                // [32][20][2204]

    float* ws = (float*)d_ws;
    // Layout (float offsets), total 123.7 MB (ws is 256 MiB):
    unsigned short* D1bf = (unsigned short*)ws;        // [32][512][2048] bf16 (in-place spikes)
    float* C2p = ws + 16777216LL;                      // [2][32][20][2048] partials
    unsigned short* Inbf = (unsigned short*)(ws + 19398656LL); // [4992][2048]
    unsigned short* InT  = (unsigned short*)(ws + 24510464LL); // [32][2048][160]
    unsigned short* W1p  = (unsigned short*)(ws + 29753344LL); // [2][512][160]
    unsigned short* W2p  = (unsigned short*)(ws + 29835264LL); // [2][32][512]
    unsigned short* Wl1p = (unsigned short*)(ws + 29851648LL); // [2][512][2048]
    unsigned short* Wl2p = (unsigned short*)(ws + 30900224LL); // [2][32][512]
    // Branch-2 phase reuses the dead D1bf region (16.7M floats available):
    float* Zp = ws;                                    // [4][156][16384] c-major
    unsigned short* L1T = (unsigned short*)(ws + 10223616LL);  // [156][16384] bf16
    float* Cl2 = ws + 11501568LL;                      // [32][20][156]

    dim3 blk(256);

    // ---- Preprocess ----
    prep_in<<<dim3(32, 3, 32), blk, 0, stream>>>(In, Inbf, InT);
    pack_all<<<dim3(1088), blk, 0, stream>>>(W1, W2, Wl1, Wl2,
                                             W1p, W2p, Wl1p, Wl2p);

    // ---- Branch 1 (full batch, bf16 D1 roundtrip) ----
    gemm1_mfma<<<dim3(16, 4, 32), blk, 0, stream>>>(W1p, InT, D1bf);
    scan_spike_bf<<<dim3(16384), blk, 0, stream>>>(D1bf);
    gemm2_mfma<<<dim3(16, 2, 32), blk, 0, stream>>>(
        W2p, D1bf, C2p, 2048, 2048, 512LL * 2048, 20LL * 2048, 256, 1310720LL);
    scan_spike_T2<<<dim3(640), blk, 0, stream>>>(C2p, 1310720LL, out, 2204);

    // ---- Branch 2 ----
    gemmL1_mfma<<<dim3(80, 8, 4), blk, 0, stream>>>(Wl1p, Inbf, Zp);
    scan_sum4_perm<<<dim3(256), blk, 0, stream>>>(Zp, perm, L1T);
    gemm2B_mfma<<<dim3(2, 1, 32), blk, 0, stream>>>(Wl2p, L1T, Cl2);
    scan_spike_C_out<<<dim3(3), blk, 0, stream>>>(Cl2, out, 640);

    (void)in_sizes; (void)n_in; (void)out_size; (void)ws_size;
}

// Round 9
// 256.647 us; speedup vs baseline: 1.1940x; 1.0387x over previous
//
#include <hip/hip_runtime.h>

// SLAYER constants
#define ALPHA  0.90483741803595952f   /* exp(-1/10) */
#define ALPHA8 0.44932896411722156f   /* exp(-0.8)  */
#define THETA  10.0f
#define BF1    ((unsigned short)0x3F80) /* 1.0f as bf16 */

typedef short   bf16x8 __attribute__((ext_vector_type(8)));
typedef float   f32x4  __attribute__((ext_vector_type(4)));
typedef float   f32x4v __attribute__((ext_vector_type(4)));
typedef unsigned short ushort4v __attribute__((ext_vector_type(4)));
typedef unsigned short ushort8v __attribute__((ext_vector_type(8)));

// RNE float -> bf16 bits
__device__ __forceinline__ unsigned short f2bf(float f) {
    unsigned int x = __float_as_uint(f);
    unsigned int r = (x + 0x7FFFu + ((x >> 16) & 1u)) >> 16;
    return (unsigned short)r;
}
__device__ __forceinline__ float bf2f(unsigned short h) {
    return __uint_as_float(((unsigned int)h) << 16);
}
// 2-way bf16 split: w ~= h0+h1 (residual ~2^-17 rel; spike margins are ~6 sigma)
__device__ __forceinline__ void split2(float w, unsigned short& h0,
                                       unsigned short& h1) {
    h0 = f2bf(w);          float r0 = w - bf2f(h0);
    h1 = f2bf(r0);
}

// ---------------------------------------------------------------------------
// Prep: In fp32 [32][156][2048] -> Inbf ushort [32*156][2048] (row-major bf16)
//                               -> InT  ushort [32][2048][160] (transposed, c pad 160)
// ---------------------------------------------------------------------------
__global__ __launch_bounds__(256) void prep_in(
    const float* __restrict__ In, unsigned short* __restrict__ Inbf,
    unsigned short* __restrict__ InT)
{
    __shared__ float Tile[64][65];
    const int t0 = blockIdx.x * 64;
    const int c0 = blockIdx.y * 64;
    const int b  = blockIdx.z;
    const int tid = threadIdx.x;

    #pragma unroll
    for (int s = 0; s < 4; ++s) {
        int id = tid + s * 256;
        int cc = id >> 4;
        int t4 = (id & 15) * 4;
        f32x4v v = {0.f, 0.f, 0.f, 0.f};
        if (c0 + cc < 156)
            v = *(const f32x4v*)(In + ((long long)(b * 156 + c0 + cc) * 2048 + t0 + t4));
        *(f32x4v*)&Tile[cc][t4] = v;
    }
    __syncthreads();

    #pragma unroll
    for (int s = 0; s < 2; ++s) {
        int id = tid + s * 256;
        int t  = id >> 3;
        int c8 = (id & 7) * 8;
        unsigned short r[8];
        #pragma unroll
        for (int j = 0; j < 8; ++j) r[j] = f2bf(Tile[c8 + j][t]);
        *(ushort8v*)(InT + (long long)b * 327680 + (long long)(t0 + t) * 160 + c0 + c8)
            = *(ushort8v*)r;
    }
    #pragma unroll
    for (int s = 0; s < 2; ++s) {
        int id = tid + s * 256;
        int cc = id >> 3;
        int t8 = (id & 7) * 8;
        if (c0 + cc < 156) {
            unsigned short r[8];
            #pragma unroll
            for (int j = 0; j < 8; ++j) r[j] = f2bf(Tile[cc][t8 + j]);
            *(ushort8v*)(Inbf + (long long)(b * 156 + c0 + cc) * 2048 + t0 + t8)
                = *(ushort8v*)r;
        }
    }
}

// ---------------------------------------------------------------------------
// Pack all 4 weight matrices into split-2 bf16 planes in ONE launch.
// ---------------------------------------------------------------------------
__global__ __launch_bounds__(256) void pack_all(
    const float* __restrict__ W1,  const float* __restrict__ W2,
    const float* __restrict__ Wl1, const float* __restrict__ Wl2,
    unsigned short* __restrict__ W1p,  unsigned short* __restrict__ W2p,
    unsigned short* __restrict__ Wl1p, unsigned short* __restrict__ Wl2p)
{
    const int bidx = blockIdx.x;
    const float* W; unsigned short* P; int M, K, Kp, Mp, m;
    if (bidx < 512)       { W = W1;  P = W1p;  M = 512; K = 156;  Kp = 160;  Mp = 512; m = bidx; }
    else if (bidx < 544)  { W = W2;  P = W2p;  M = 20;  K = 512;  Kp = 512;  Mp = 32;  m = bidx - 512; }
    else if (bidx < 1056) { W = Wl1; P = Wl1p; M = 512; K = 2048; Kp = 2048; Mp = 512; m = bidx - 544; }
    else                  { W = Wl2; P = Wl2p; M = 20;  K = 512;  Kp = 512;  Mp = 32;  m = bidx - 1056; }

    for (int k = threadIdx.x; k < Kp; k += 256) {
        float v = (m < M && k < K) ? W[(long long)m * K + k] : 0.f;
        unsigned short h0, h1;
        split2(v, h0, h1);
        P[(long long)m * Kp + k] = h0;
        P[(long long)Mp * Kp + (long long)m * Kp + k] = h1;
    }
}

// ---------------------------------------------------------------------------
// Branch-1 GEMM1 (MFMA, packed split-2), bf16 output, REGISTER-PREFETCH
// pipeline: iteration k+1's global loads issue before iteration k's MFMAs,
// ds_write only after the post-MFMA barrier -> L2 latency hidden.
//   D1[b][m][n] = sum_c W1[m][c] * In[b][c][n],  M=512, N=2048, K=160
// Tile 128x128, BK=32, 5 iters. grid (16 n, 4 m, 32 b).
// ---------------------------------------------------------------------------
__global__ __launch_bounds__(256) void gemm1_mfma(
    const unsigned short* __restrict__ W1p,
    const unsigned short* __restrict__ InT,
    unsigned short* __restrict__ D1)     // [32][512][2048] bf16
{
    __shared__ alignas(16) unsigned short As[2][128][40];
    __shared__ alignas(16) unsigned short Bs[128][40];

    const int z  = blockIdx.z;
    const int m0 = blockIdx.y * 128;
    const int n0 = blockIdx.x * 128;
    const int tid  = threadIdx.x;
    const int lane = tid & 63, w = tid >> 6;
    const int wy = w >> 1, wx = w & 1;
    const int l15 = lane & 15, kq = lane >> 4;

    const unsigned short* Tb = InT + (long long)z * 327680;

    // staging coordinates
    int aPl[4], aM[4], aK8[4];
    #pragma unroll
    for (int s = 0; s < 4; ++s) {
        int id = tid + s * 256;
        aPl[s] = id >> 9; int rem = id & 511;
        aM[s] = rem >> 2; aK8[s] = (rem & 3) * 8;
    }
    int bT[2], bC8[2];
    #pragma unroll
    for (int s = 0; s < 2; ++s) {
        int id = tid + s * 256;
        bT[s] = id >> 2; bC8[s] = (id & 3) * 8;
    }

    f32x4 acc[4][4] = {};
    ushort8v aReg[4], bReg[2];

    // prologue: load k0 = 0 tile and stage it
    #pragma unroll
    for (int s = 0; s < 4; ++s)
        aReg[s] = *(const ushort8v*)(W1p + (long long)aPl[s] * 81920 +
                                     (long long)(m0 + aM[s]) * 160 + aK8[s]);
    #pragma unroll
    for (int s = 0; s < 2; ++s)
        bReg[s] = *(const ushort8v*)(Tb + (long long)(n0 + bT[s]) * 160 + bC8[s]);
    #pragma unroll
    for (int s = 0; s < 4; ++s) *(ushort8v*)&As[aPl[s]][aM[s]][aK8[s]] = aReg[s];
    #pragma unroll
    for (int s = 0; s < 2; ++s) *(ushort8v*)&Bs[bT[s]][bC8[s]] = bReg[s];
    __syncthreads();

    #pragma unroll
    for (int it = 0; it < 5; ++it) {
        const int kn = (it + 1) * 32;
        if (it < 4) {   // prefetch next tile into registers
            #pragma unroll
            for (int s = 0; s < 4; ++s)
                aReg[s] = *(const ushort8v*)(W1p + (long long)aPl[s] * 81920 +
                                             (long long)(m0 + aM[s]) * 160 + kn + aK8[s]);
            #pragma unroll
            for (int s = 0; s < 2; ++s)
                bReg[s] = *(const ushort8v*)(Tb + (long long)(n0 + bT[s]) * 160 + kn + bC8[s]);
        }

        bf16x8 bfr[4];
        #pragma unroll
        for (int nt = 0; nt < 4; ++nt)
            bfr[nt] = *(const bf16x8*)&Bs[wx * 64 + nt * 16 + l15][kq * 8];
        #pragma unroll
        for (int s = 0; s < 2; ++s) {
            #pragma unroll
            for (int mt = 0; mt < 4; ++mt) {
                bf16x8 afr = *(const bf16x8*)&As[s][wy * 64 + mt * 16 + l15][kq * 8];
                #pragma unroll
                for (int nt = 0; nt < 4; ++nt)
                    acc[mt][nt] = __builtin_amdgcn_mfma_f32_16x16x32_bf16(
                        afr, bfr[nt], acc[mt][nt], 0, 0, 0);
            }
        }
        __syncthreads();
        if (it < 4) {
            #pragma unroll
            for (int s = 0; s < 4; ++s) *(ushort8v*)&As[aPl[s]][aM[s]][aK8[s]] = aReg[s];
            #pragma unroll
            for (int s = 0; s < 2; ++s) *(ushort8v*)&Bs[bT[s]][bC8[s]] = bReg[s];
            __syncthreads();
        }
    }

    unsigned short* Db = D1 + (long long)z * 512 * 2048;
    #pragma unroll
    for (int mt = 0; mt < 4; ++mt) {
        #pragma unroll
        for (int i = 0; i < 4; ++i) {
            int m = m0 + wy * 64 + mt * 16 + kq * 4 + i;
            #pragma unroll
            for (int nt = 0; nt < 4; ++nt) {
                int n = n0 + wx * 64 + nt * 16 + l15;
                Db[(long long)m * 2048 + n] = f2bf(acc[mt][nt][i]);
            }
        }
    }
}

// ---------------------------------------------------------------------------
// Branch-2 GEMM1 (MFMA, packed split-2), batch merged into N, SPLIT-K x4,
// REGISTER-PREFETCH pipeline. Tile 64m x 64n, BK=64, grid (80, 8, 4)
// (grid.x padded 78->80 for XCD-aligned L2 reuse of the B n-tile).
// Epilogue: LDS transpose -> coalesced c-major stores Zp[s][c][b*512+m].
// ---------------------------------------------------------------------------
__global__ __launch_bounds__(256) void gemmL1_mfma(
    const unsigned short* __restrict__ Wl1p,  // [2][512][2048]
    const unsigned short* __restrict__ InF,   // [4992][2048] bf16
    float* __restrict__ Zp)                   // [4][156][16384] c-major partials
{
    __shared__ alignas(16) unsigned short As[2][64][72];
    __shared__ alignas(16) unsigned short Bs[64][72];

    if (blockIdx.x >= 78) return;
    const int n0  = blockIdx.x * 64;
    const int m0  = blockIdx.y * 64;
    const int ks0 = blockIdx.z * 512;
    const int tid  = threadIdx.x;
    const int lane = tid & 63, w = tid >> 6;
    const int wy = w >> 1, wx = w & 1;
    const int l15 = lane & 15, kq = lane >> 4;

    // staging coordinates
    int aPl[4], aM[4], aK8[4];
    #pragma unroll
    for (int s = 0; s < 4; ++s) {
        int id = tid + s * 256;
        aPl[s] = id >> 9; int rem = id & 511;
        aM[s] = rem >> 3; aK8[s] = (rem & 7) * 8;
    }
    int bN[2], bK8[2];
    #pragma unroll
    for (int s = 0; s < 2; ++s) {
        int id = tid + s * 256;
        bN[s] = id >> 3; bK8[s] = (id & 7) * 8;
    }

    f32x4 acc[2][2] = {};
    ushort8v aReg[4], bReg[2];

    // prologue: load slice-local k = 0
    #pragma unroll
    for (int s = 0; s < 4; ++s)
        aReg[s] = *(const ushort8v*)(Wl1p + (long long)aPl[s] * 1048576 +
                                     (long long)(m0 + aM[s]) * 2048 + ks0 + aK8[s]);
    #pragma unroll
    for (int s = 0; s < 2; ++s)
        bReg[s] = *(const ushort8v*)(InF + (long long)(n0 + bN[s]) * 2048 + ks0 + bK8[s]);
    #pragma unroll
    for (int s = 0; s < 4; ++s) *(ushort8v*)&As[aPl[s]][aM[s]][aK8[s]] = aReg[s];
    #pragma unroll
    for (int s = 0; s < 2; ++s) *(ushort8v*)&Bs[bN[s]][bK8[s]] = bReg[s];
    __syncthreads();

    for (int it = 0; it < 8; ++it) {
        const int kn = ks0 + (it + 1) * 64;
        if (it < 7) {
            #pragma unroll
            for (int s = 0; s < 4; ++s)
                aReg[s] = *(const ushort8v*)(Wl1p + (long long)aPl[s] * 1048576 +
                                             (long long)(m0 + aM[s]) * 2048 + kn + aK8[s]);
            #pragma unroll
            for (int s = 0; s < 2; ++s)
                bReg[s] = *(const ushort8v*)(InF + (long long)(n0 + bN[s]) * 2048 + kn + bK8[s]);
        }

        #pragma unroll
        for (int ks = 0; ks < 2; ++ks) {
            bf16x8 bfr[2];
            #pragma unroll
            for (int nt = 0; nt < 2; ++nt)
                bfr[nt] = *(const bf16x8*)&Bs[wx * 32 + nt * 16 + l15][ks * 32 + kq * 8];
            #pragma unroll
            for (int s = 0; s < 2; ++s) {
                #pragma unroll
                for (int mt = 0; mt < 2; ++mt) {
                    bf16x8 afr = *(const bf16x8*)&As[s][wy * 32 + mt * 16 + l15][ks * 32 + kq * 8];
                    #pragma unroll
                    for (int nt = 0; nt < 2; ++nt)
                        acc[mt][nt] = __builtin_amdgcn_mfma_f32_16x16x32_bf16(
                            afr, bfr[nt], acc[mt][nt], 0, 0, 0);
                }
            }
        }
        __syncthreads();
        if (it < 7) {
            #pragma unroll
            for (int s = 0; s < 4; ++s) *(ushort8v*)&As[aPl[s]][aM[s]][aK8[s]] = aReg[s];
            #pragma unroll
            for (int s = 0; s < 2; ++s) *(ushort8v*)&Bs[bN[s]][bK8[s]] = bReg[s];
            __syncthreads();
        }
    }

    // Epilogue: transpose 64x64 tile through LDS (64x65 floats = 16.6 KB),
    // then store c-major coalesced.
    float* T = (float*)As;
    __syncthreads();
    #pragma unroll
    for (int mt = 0; mt < 2; ++mt) {
        #pragma unroll
        for (int i = 0; i < 4; ++i) {
            int mL = wy * 32 + mt * 16 + kq * 4 + i;
            #pragma unroll
            for (int nt = 0; nt < 2; ++nt) {
                int nL = wx * 32 + nt * 16 + l15;
                T[mL * 65 + nL] = acc[mt][nt][i];
            }
        }
    }
    __syncthreads();

    float* Zs = Zp + (long long)blockIdx.z * 2555904;
    #pragma unroll
    for (int s2 = 0; s2 < 16; ++s2) {
        int id = tid + s2 * 256;       // 0..4095
        int cL = id >> 6;              // local n 0..63
        int mL = id & 63;
        int n = n0 + cL;
        int bb = n / 156, cc = n - bb * 156;
        Zs[(long long)cc * 16384 + bb * 512 + m0 + mL] = T[mL * 65 + cL];
    }
}

// ---------------------------------------------------------------------------
// Branch-1 GEMM2 (MFMA, packed split-2 A, split-K via blockIdx.y):
//   Cpart[y][b][m][n] = sum_{k in slice y} A[m][k] * Bsp[b][k][n]
// Tile 32m x 128n, BK=64. grid (16, 2, 32).
// ---------------------------------------------------------------------------
__global__ __launch_bounds__(256) void gemm2_mfma(
    const unsigned short* __restrict__ Ap,
    const unsigned short* __restrict__ Bsp,
    float* __restrict__ C,
    int N, int ldb, long long bStrideB, long long cStride,
    int kPerSlice, long long partStride)
{
    __shared__ alignas(16) unsigned short As[2][32][72];
    __shared__ alignas(16) unsigned short Bs[128][72];

    const int b   = blockIdx.z;
    const int n0  = blockIdx.x * 128;
    const int ks0 = blockIdx.y * kPerSlice;
    const int tid  = threadIdx.x;
    const int lane = tid & 63, w = tid >> 6;
    const int l15 = lane & 15, kq = lane >> 4;

    const unsigned short* Bb = Bsp + (long long)b * bStrideB;

    f32x4 acc[2][2] = {};

    for (int kk = 0; kk < kPerSlice; kk += 64) {
        const int k0 = ks0 + kk;
        #pragma unroll
        for (int s = 0; s < 2; ++s) {
            int id = tid + s * 256;
            int pl = id >> 8, rem = id & 255;
            int m = rem >> 3, k8 = (rem & 7) * 8;
            ushort8v v = *(const ushort8v*)(Ap + (long long)pl * 16384 +
                                            (long long)m * 512 + k0 + k8);
            *(ushort8v*)&As[pl][m][k8] = v;
        }
        {
            int kb = (tid >> 4) * 4;
            int nb = (tid & 15) * 8;
            unsigned short rv[4][8];
            #pragma unroll
            for (int kk2 = 0; kk2 < 4; ++kk2) {
                const unsigned short* src =
                    Bb + (long long)(k0 + kb + kk2) * ldb + n0 + nb;
                *(ushort8v*)rv[kk2] = *(const ushort8v*)src;
            }
            #pragma unroll
            for (int j = 0; j < 8; ++j) {
                ushort4v v4 = { rv[0][j], rv[1][j], rv[2][j], rv[3][j] };
                *(ushort4v*)&Bs[nb + j][kb] = v4;
            }
        }
        __syncthreads();

        #pragma unroll
        for (int ks = 0; ks < 2; ++ks) {
            bf16x8 bfr[2];
            #pragma unroll
            for (int nt = 0; nt < 2; ++nt)
                bfr[nt] = *(const bf16x8*)&Bs[w * 32 + nt * 16 + l15][ks * 32 + kq * 8];
            #pragma unroll
            for (int s = 0; s < 2; ++s) {
                #pragma unroll
                for (int mt = 0; mt < 2; ++mt) {
                    bf16x8 afr = *(const bf16x8*)&As[s][mt * 16 + l15][ks * 32 + kq * 8];
                    #pragma unroll
                    for (int nt = 0; nt < 2; ++nt)
                        acc[mt][nt] = __builtin_amdgcn_mfma_f32_16x16x32_bf16(
                            afr, bfr[nt], acc[mt][nt], 0, 0, 0);
                }
            }
        }
        __syncthreads();
    }

    float* Cb = C + (long long)b * cStride + (long long)blockIdx.y * partStride;
    #pragma unroll
    for (int mt = 0; mt < 2; ++mt) {
        #pragma unroll
        for (int i = 0; i < 4; ++i) {
            int m = mt * 16 + kq * 4 + i;
            if (m >= 20) continue;
            #pragma unroll
            for (int nt = 0; nt < 2; ++nt) {
                int n = n0 + w * 32 + nt * 16 + l15;
                Cb[(long long)m * N + n] = acc[mt][nt][i];
            }
        }
    }
}

// ---------------------------------------------------------------------------
// Branch-2 layer-2 GEMM: C[b][m][c] = sum_h Wl2[m][h] * L1T[c][b*512+h]
// ---------------------------------------------------------------------------
__global__ __launch_bounds__(256) void gemm2B_mfma(
    const unsigned short* __restrict__ Ap,   // [2][32][512] Wl2 planes
    const unsigned short* __restrict__ L1T,  // [156][16384] bf16 spikes
    float* __restrict__ Cl2)                 // [32][20][156]
{
    __shared__ alignas(16) unsigned short As[2][32][72];
    __shared__ alignas(16) unsigned short Bs[128][72];

    const int b  = blockIdx.z;
    const int n0 = blockIdx.x * 128;
    const int tid  = threadIdx.x;
    const int lane = tid & 63, w = tid >> 6;
    const int l15 = lane & 15, kq = lane >> 4;

    f32x4 acc[2][2] = {};

    for (int k0 = 0; k0 < 512; k0 += 64) {
        #pragma unroll
        for (int s = 0; s < 2; ++s) {
            int id = tid + s * 256;
            int pl = id >> 8, rem = id & 255;
            int m = rem >> 3, k8 = (rem & 7) * 8;
            ushort8v v = *(const ushort8v*)(Ap + (long long)pl * 16384 +
                                            (long long)m * 512 + k0 + k8);
            *(ushort8v*)&As[pl][m][k8] = v;
        }
        #pragma unroll
        for (int s = 0; s < 4; ++s) {
            int id = tid + s * 256;
            int n = id >> 3, k8 = (id & 7) * 8;
            ushort8v v = {0,0,0,0,0,0,0,0};
            if (n0 + n < 156)
                v = *(const ushort8v*)(L1T + (long long)(n0 + n) * 16384 +
                                       b * 512 + k0 + k8);
            *(ushort8v*)&Bs[n][k8] = v;
        }
        __syncthreads();

        #pragma unroll
        for (int ks = 0; ks < 2; ++ks) {
            bf16x8 bfr[2];
            #pragma unroll
            for (int nt = 0; nt < 2; ++nt)
                bfr[nt] = *(const bf16x8*)&Bs[w * 32 + nt * 16 + l15][ks * 32 + kq * 8];
            #pragma unroll
            for (int s = 0; s < 2; ++s) {
                #pragma unroll
                for (int mt = 0; mt < 2; ++mt) {
                    bf16x8 afr = *(const bf16x8*)&As[s][mt * 16 + l15][ks * 32 + kq * 8];
                    #pragma unroll
                    for (int nt = 0; nt < 2; ++nt)
                        acc[mt][nt] = __builtin_amdgcn_mfma_f32_16x16x32_bf16(
                            afr, bfr[nt], acc[mt][nt], 0, 0, 0);
                }
            }
        }
        __syncthreads();
    }

    float* Cb = Cl2 + (long long)b * 20 * 156;
    #pragma unroll
    for (int mt = 0; mt < 2; ++mt) {
        #pragma unroll
        for (int i = 0; i < 4; ++i) {
            int m = mt * 16 + kq * 4 + i;
            if (m >= 20) continue;
            #pragma unroll
            for (int nt = 0; nt < 2; ++nt) {
                int n = n0 + w * 32 + nt * 16 + l15;
                if (n < 156) Cb[(long long)m * 156 + n] = acc[mt][nt][i];
            }
        }
    }
}

// ---------------------------------------------------------------------------
// Alpha-scan + spike over T=2048 per row, bf16 in -> bf16 spikes, IN PLACE.
// ---------------------------------------------------------------------------
__global__ __launch_bounds__(256) void scan_spike_bf(unsigned short* data)
{
    const int row = blockIdx.x;
    const int tid = threadIdx.x;
    unsigned short* x = data + (long long)row * 2048 + tid * 8;

    ushort8v raw = *(const ushort8v*)x;
    float v[8];
    #pragma unroll
    for (int k = 0; k < 8; ++k) v[k] = bf2f(raw[k]);

    float y = 0.f;
    #pragma unroll
    for (int k = 0; k < 8; ++k) { y = ALPHA * y + v[k]; v[k] = y; }

    __shared__ float sc[256];
    float val = y;
    sc[tid] = val;
    float m = ALPHA8;
    for (int d = 1; d < 256; d <<= 1) {
        __syncthreads();
        float p = (tid >= d) ? sc[tid - d] : 0.f;
        __syncthreads();
        val += m * p;
        sc[tid] = val;
        m *= m;
    }
    __syncthreads();
    float carry = (tid > 0) ? sc[tid - 1] : 0.f;

    ushort8v ov;
    float ak = ALPHA;
    #pragma unroll
    for (int k = 0; k < 8; ++k) {
        float yk = v[k] + ak * carry;
        ak *= ALPHA;
        ov[k] = (yk >= THETA) ? BF1 : 0;
    }
    *(ushort8v*)x = ov;
}

// ---------------------------------------------------------------------------
// Final T-scan summing two split-K partials -> fp32 spikes to d_out.
// ---------------------------------------------------------------------------
__global__ __launch_bounds__(256) void scan_spike_T2(
    const float* __restrict__ in, long long partStride,
    float* __restrict__ out, long long out_stride)
{
    const int row = blockIdx.x;
    const int tid = threadIdx.x;
    const float* x = in + (long long)row * 2048 + tid * 8;

    float v[8];
    #pragma unroll
    for (int k = 0; k < 8; ++k) v[k] = x[k] + x[k + partStride];

    float y = 0.f;
    #pragma unroll
    for (int k = 0; k < 8; ++k) { y = ALPHA * y + v[k]; v[k] = y; }

    __shared__ float sc[256];
    float val = y;
    sc[tid] = val;
    float m = ALPHA8;
    for (int d = 1; d < 256; d <<= 1) {
        __syncthreads();
        float p = (tid >= d) ? sc[tid - d] : 0.f;
        __syncthreads();
        val += m * p;
        sc[tid] = val;
        m *= m;
    }
    __syncthreads();
    float carry = (tid > 0) ? sc[tid - 1] : 0.f;

    float* o = out + (long long)row * out_stride + tid * 8;
    float ak = ALPHA;
    #pragma unroll
    for (int k = 0; k < 8; ++k) {
        float yk = v[k] + ak * carry;
        ak *= ALPHA;
        o[k] = (yk >= THETA) ? 1.0f : 0.0f;
    }
}

// ---------------------------------------------------------------------------
// Branch-2 layer-1 scan, c-major: sum 4 partials Zp[s][c][row] (coalesced),
// scan over c in perm order via LDS, write spikes c-major to L1T[c][row].
// ---------------------------------------------------------------------------
__global__ __launch_bounds__(256) void scan_sum4_perm(
    const float* __restrict__ Zp, const int* __restrict__ perm,
    unsigned short* __restrict__ L1T)
{
    __shared__ float Xs[156][64];   // 39.9 KB
    __shared__ int p[156];

    const int r0  = blockIdx.x * 64;
    const int tid = threadIdx.x;
    for (int i = tid; i < 156; i += 256) p[i] = perm[i];

    const int row = tid & 63;
    const int cq  = tid >> 6;
    #pragma unroll
    for (int it = 0; it < 39; ++it) {
        int c = it * 4 + cq;
        long long base = (long long)c * 16384 + r0 + row;
        float s = Zp[base] + Zp[base + 2555904] +
                  Zp[base + 2 * 2555904] + Zp[base + 3 * 2555904];
        Xs[c][row] = s;
    }
    __syncthreads();

    if (tid < 64) {
        float y = 0.f;
        for (int c = 0; c < 156; ++c) {
            y = ALPHA * y + Xs[p[c]][tid];
            L1T[(long long)c * 16384 + r0 + tid] = (y >= THETA) ? BF1 : 0;
        }
    }
}

__global__ __launch_bounds__(256) void scan_spike_C_out(
    const float* __restrict__ in, float* __restrict__ out, int rows)
{
    int row = blockIdx.x * blockDim.x + threadIdx.x;
    if (row >= rows) return;
    const float* x = in + (long long)row * 156;
    float* o = out + (long long)row * 2204 + 2048;
    float y = 0.f;
    for (int c = 0; c < 156; ++c) {
        y = ALPHA * y + x[c];
        o[c] = (y >= THETA) ? 1.0f : 0.0f;
    }
}

// ---------------------------------------------------------------------------
// B=32, C_IN=156, T=2048, HID=512, OUT=20. Output [32,20,2204].
// ---------------------------------------------------------------------------
extern "C" void kernel_launch(void* const* d_in, const int* in_sizes, int n_in,
                              void* d_out, int out_size, void* d_ws, size_t ws_size,
                              hipStream_t stream)
{
    const float* In  = (const float*)d_in[0];  // [32][156][2048]
    const float* W1  = (const float*)d_in[1];  // [512][156]
    const float* W2  = (const float*)d_in[2];  // [20][512]
    const float* Wl1 = (const float*)d_in[3];  // [512][2048]
    const float* Wl2 = (const float*)d_in[4];  // [20][512]
    const int*  perm = (const int*)d_in[5];    // [156]
    float* out = (float*)d_out;                // [32][20][2204]

    float* ws = (float*)d_ws;
    // Layout (float offsets), total 123.7 MB (ws is 256 MiB):
    unsigned short* D1bf = (unsigned short*)ws;        // [32][512][2048] bf16 (in-place spikes)
    float* C2p = ws + 16777216LL;                      // [2][32][20][2048] partials
    unsigned short* Inbf = (unsigned short*)(ws + 19398656LL); // [4992][2048]
    unsigned short* InT  = (unsigned short*)(ws + 24510464LL); // [32][2048][160]
    unsigned short* W1p  = (unsigned short*)(ws + 29753344LL); // [2][512][160]
    unsigned short* W2p  = (unsigned short*)(ws + 29835264LL); // [2][32][512]
    unsigned short* Wl1p = (unsigned short*)(ws + 29851648LL); // [2][512][2048]
    unsigned short* Wl2p = (unsigned short*)(ws + 30900224LL); // [2][32][512]
    // Branch-2 phase reuses the dead D1bf region:
    float* Zp = ws;                                    // [4][156][16384] c-major
    unsigned short* L1T = (unsigned short*)(ws + 10223616LL);  // [156][16384] bf16
    float* Cl2 = ws + 11501568LL;                      // [32][20][156]

    dim3 blk(256);

    // ---- Preprocess ----
    prep_in<<<dim3(32, 3, 32), blk, 0, stream>>>(In, Inbf, InT);
    pack_all<<<dim3(1088), blk, 0, stream>>>(W1, W2, Wl1, Wl2,
                                             W1p, W2p, Wl1p, Wl2p);

    // ---- Branch 1 (full batch, bf16 D1 roundtrip) ----
    gemm1_mfma<<<dim3(16, 4, 32), blk, 0, stream>>>(W1p, InT, D1bf);
    scan_spike_bf<<<dim3(16384), blk, 0, stream>>>(D1bf);
    gemm2_mfma<<<dim3(16, 2, 32), blk, 0, stream>>>(
        W2p, D1bf, C2p, 2048, 2048, 512LL * 2048, 20LL * 2048, 256, 1310720LL);
    scan_spike_T2<<<dim3(640), blk, 0, stream>>>(C2p, 1310720LL, out, 2204);

    // ---- Branch 2 ----
    gemmL1_mfma<<<dim3(80, 8, 4), blk, 0, stream>>>(Wl1p, Inbf, Zp);
    scan_sum4_perm<<<dim3(256), blk, 0, stream>>>(Zp, perm, L1T);
    gemm2B_mfma<<<dim3(2, 1, 32), blk, 0, stream>>>(Wl2p, L1T, Cl2);
    scan_spike_C_out<<<dim3(3), blk, 0, stream>>>(Cl2, out, 640);

    (void)in_sizes; (void)n_in; (void)out_size; (void)ws_size;
}

// Round 10
// 255.585 us; speedup vs baseline: 1.1990x; 1.0042x over previous
//
#include <hip/hip_runtime.h>

// SLAYER constants
#define ALPHA  0.90483741803595952f   /* exp(-1/10) */
#define ALPHA8 0.44932896411722156f   /* exp(-0.8)  */
#define THETA  10.0f
#define BF1    ((unsigned short)0x3F80) /* 1.0f as bf16 */

typedef short   bf16x8 __attribute__((ext_vector_type(8)));
typedef float   f32x4  __attribute__((ext_vector_type(4)));
typedef float   f32x4v __attribute__((ext_vector_type(4)));
typedef unsigned short ushort4v __attribute__((ext_vector_type(4)));
typedef unsigned short ushort8v __attribute__((ext_vector_type(8)));

// RNE float -> bf16 bits
__device__ __forceinline__ unsigned short f2bf(float f) {
    unsigned int x = __float_as_uint(f);
    unsigned int r = (x + 0x7FFFu + ((x >> 16) & 1u)) >> 16;
    return (unsigned short)r;
}
__device__ __forceinline__ float bf2f(unsigned short h) {
    return __uint_as_float(((unsigned int)h) << 16);
}
// 2-way bf16 split: w ~= h0+h1 (residual ~2^-17 rel; spike margins are ~6 sigma)
__device__ __forceinline__ void split2(float w, unsigned short& h0,
                                       unsigned short& h1) {
    h0 = f2bf(w);          float r0 = w - bf2f(h0);
    h1 = f2bf(r0);
}

// ---------------------------------------------------------------------------
// Prep: In fp32 [32][156][2048] -> Inbf ushort [32*156][2048] (row-major bf16)
//                               -> InT  ushort [32][2048][160] (transposed, c pad 160)
// ---------------------------------------------------------------------------
__global__ __launch_bounds__(256) void prep_in(
    const float* __restrict__ In, unsigned short* __restrict__ Inbf,
    unsigned short* __restrict__ InT)
{
    __shared__ float Tile[64][65];
    const int t0 = blockIdx.x * 64;
    const int c0 = blockIdx.y * 64;
    const int b  = blockIdx.z;
    const int tid = threadIdx.x;

    #pragma unroll
    for (int s = 0; s < 4; ++s) {
        int id = tid + s * 256;
        int cc = id >> 4;
        int t4 = (id & 15) * 4;
        f32x4v v = {0.f, 0.f, 0.f, 0.f};
        if (c0 + cc < 156)
            v = *(const f32x4v*)(In + ((long long)(b * 156 + c0 + cc) * 2048 + t0 + t4));
        *(f32x4v*)&Tile[cc][t4] = v;
    }
    __syncthreads();

    #pragma unroll
    for (int s = 0; s < 2; ++s) {
        int id = tid + s * 256;
        int t  = id >> 3;
        int c8 = (id & 7) * 8;
        unsigned short r[8];
        #pragma unroll
        for (int j = 0; j < 8; ++j) r[j] = f2bf(Tile[c8 + j][t]);
        *(ushort8v*)(InT + (long long)b * 327680 + (long long)(t0 + t) * 160 + c0 + c8)
            = *(ushort8v*)r;
    }
    #pragma unroll
    for (int s = 0; s < 2; ++s) {
        int id = tid + s * 256;
        int cc = id >> 3;
        int t8 = (id & 7) * 8;
        if (c0 + cc < 156) {
            unsigned short r[8];
            #pragma unroll
            for (int j = 0; j < 8; ++j) r[j] = f2bf(Tile[cc][t8 + j]);
            *(ushort8v*)(Inbf + (long long)(b * 156 + c0 + cc) * 2048 + t0 + t8)
                = *(ushort8v*)r;
        }
    }
}

// ---------------------------------------------------------------------------
// Pack all 4 weight matrices into split-2 bf16 planes in ONE launch.
// ---------------------------------------------------------------------------
__global__ __launch_bounds__(256) void pack_all(
    const float* __restrict__ W1,  const float* __restrict__ W2,
    const float* __restrict__ Wl1, const float* __restrict__ Wl2,
    unsigned short* __restrict__ W1p,  unsigned short* __restrict__ W2p,
    unsigned short* __restrict__ Wl1p, unsigned short* __restrict__ Wl2p)
{
    const int bidx = blockIdx.x;
    const float* W; unsigned short* P; int M, K, Kp, Mp, m;
    if (bidx < 512)       { W = W1;  P = W1p;  M = 512; K = 156;  Kp = 160;  Mp = 512; m = bidx; }
    else if (bidx < 544)  { W = W2;  P = W2p;  M = 20;  K = 512;  Kp = 512;  Mp = 32;  m = bidx - 512; }
    else if (bidx < 1056) { W = Wl1; P = Wl1p; M = 512; K = 2048; Kp = 2048; Mp = 512; m = bidx - 544; }
    else                  { W = Wl2; P = Wl2p; M = 20;  K = 512;  Kp = 512;  Mp = 32;  m = bidx - 1056; }

    for (int k = threadIdx.x; k < Kp; k += 256) {
        float v = (m < M && k < K) ? W[(long long)m * K + k] : 0.f;
        unsigned short h0, h1;
        split2(v, h0, h1);
        P[(long long)m * Kp + k] = h0;
        P[(long long)Mp * Kp + (long long)m * Kp + k] = h1;
    }
}

// ---------------------------------------------------------------------------
// Branch-1 GEMM1 (MFMA, packed split-2), bf16 output, register prefetch.
//   D1[b][m][n] = sum_c W1[m][c] * In[b][c][n],  M=512, N=2048, K=160
// Tile 128x128, BK=32, 5 iters. grid (16 n, 4 m, 32 b).
// ---------------------------------------------------------------------------
__global__ __launch_bounds__(256) void gemm1_mfma(
    const unsigned short* __restrict__ W1p,
    const unsigned short* __restrict__ InT,
    unsigned short* __restrict__ D1)     // [32][512][2048] bf16
{
    __shared__ alignas(16) unsigned short As[2][128][40];
    __shared__ alignas(16) unsigned short Bs[128][40];

    const int z  = blockIdx.z;
    const int m0 = blockIdx.y * 128;
    const int n0 = blockIdx.x * 128;
    const int tid  = threadIdx.x;
    const int lane = tid & 63, w = tid >> 6;
    const int wy = w >> 1, wx = w & 1;
    const int l15 = lane & 15, kq = lane >> 4;

    const unsigned short* Tb = InT + (long long)z * 327680;

    int aPl[4], aM[4], aK8[4];
    #pragma unroll
    for (int s = 0; s < 4; ++s) {
        int id = tid + s * 256;
        aPl[s] = id >> 9; int rem = id & 511;
        aM[s] = rem >> 2; aK8[s] = (rem & 3) * 8;
    }
    int bT[2], bC8[2];
    #pragma unroll
    for (int s = 0; s < 2; ++s) {
        int id = tid + s * 256;
        bT[s] = id >> 2; bC8[s] = (id & 3) * 8;
    }

    f32x4 acc[4][4] = {};
    ushort8v aReg[4], bReg[2];

    #pragma unroll
    for (int s = 0; s < 4; ++s)
        aReg[s] = *(const ushort8v*)(W1p + (long long)aPl[s] * 81920 +
                                     (long long)(m0 + aM[s]) * 160 + aK8[s]);
    #pragma unroll
    for (int s = 0; s < 2; ++s)
        bReg[s] = *(const ushort8v*)(Tb + (long long)(n0 + bT[s]) * 160 + bC8[s]);
    #pragma unroll
    for (int s = 0; s < 4; ++s) *(ushort8v*)&As[aPl[s]][aM[s]][aK8[s]] = aReg[s];
    #pragma unroll
    for (int s = 0; s < 2; ++s) *(ushort8v*)&Bs[bT[s]][bC8[s]] = bReg[s];
    __syncthreads();

    #pragma unroll
    for (int it = 0; it < 5; ++it) {
        const int kn = (it + 1) * 32;
        if (it < 4) {
            #pragma unroll
            for (int s = 0; s < 4; ++s)
                aReg[s] = *(const ushort8v*)(W1p + (long long)aPl[s] * 81920 +
                                             (long long)(m0 + aM[s]) * 160 + kn + aK8[s]);
            #pragma unroll
            for (int s = 0; s < 2; ++s)
                bReg[s] = *(const ushort8v*)(Tb + (long long)(n0 + bT[s]) * 160 + kn + bC8[s]);
        }

        bf16x8 bfr[4];
        #pragma unroll
        for (int nt = 0; nt < 4; ++nt)
            bfr[nt] = *(const bf16x8*)&Bs[wx * 64 + nt * 16 + l15][kq * 8];
        #pragma unroll
        for (int s = 0; s < 2; ++s) {
            #pragma unroll
            for (int mt = 0; mt < 4; ++mt) {
                bf16x8 afr = *(const bf16x8*)&As[s][wy * 64 + mt * 16 + l15][kq * 8];
                #pragma unroll
                for (int nt = 0; nt < 4; ++nt)
                    acc[mt][nt] = __builtin_amdgcn_mfma_f32_16x16x32_bf16(
                        afr, bfr[nt], acc[mt][nt], 0, 0, 0);
            }
        }
        __syncthreads();
        if (it < 4) {
            #pragma unroll
            for (int s = 0; s < 4; ++s) *(ushort8v*)&As[aPl[s]][aM[s]][aK8[s]] = aReg[s];
            #pragma unroll
            for (int s = 0; s < 2; ++s) *(ushort8v*)&Bs[bT[s]][bC8[s]] = bReg[s];
            __syncthreads();
        }
    }

    unsigned short* Db = D1 + (long long)z * 512 * 2048;
    #pragma unroll
    for (int mt = 0; mt < 4; ++mt) {
        #pragma unroll
        for (int i = 0; i < 4; ++i) {
            int m = m0 + wy * 64 + mt * 16 + kq * 4 + i;
            #pragma unroll
            for (int nt = 0; nt < 4; ++nt) {
                int n = n0 + wx * 64 + nt * 16 + l15;
                Db[(long long)m * 2048 + n] = f2bf(acc[mt][nt][i]);
            }
        }
    }
}

// ---------------------------------------------------------------------------
// Branch-2 GEMM1 (MFMA, packed split-2), batch merged into N, SPLIT-K x4,
// register prefetch. Tile 64m x 128n (wave tile 32x64: 2x more B reuse per
// ds_read than 64x64 -> attacks the LDS-throughput bound). grid (40, 8, 4):
// grid.x padded 39->40 so the 8 m-blocks sharing a B n-tile have ids
// congruent mod 8 -> same XCD -> no round-7-style FETCH blowup.
// Epilogue: LDS transpose -> coalesced c-major stores Zp[s][c][b*512+m].
// ---------------------------------------------------------------------------
__global__ __launch_bounds__(256) void gemmL1_mfma(
    const unsigned short* __restrict__ Wl1p,  // [2][512][2048]
    const unsigned short* __restrict__ InF,   // [4992][2048] bf16
    float* __restrict__ Zp)                   // [4][156][16384] c-major partials
{
    __shared__ alignas(16) unsigned short SMEM[18432];  // 36.9 KB
    auto As = (unsigned short (*)[64][72])SMEM;         // [2][64][72]
    auto Bs = (unsigned short (*)[72])(SMEM + 9216);    // [128][72]

    if (blockIdx.x >= 39) return;
    const int n0  = blockIdx.x * 128;
    const int m0  = blockIdx.y * 64;
    const int ks0 = blockIdx.z * 512;
    const int tid  = threadIdx.x;
    const int lane = tid & 63, w = tid >> 6;
    const int wy = w >> 1, wx = w & 1;   // wy: m-half (32), wx: n-half (64)
    const int l15 = lane & 15, kq = lane >> 4;

    // staging coordinates: A = 2x64x64 (4 chunks/thread), B = 128x64 (4/thread)
    int aPl[4], aM[4], aK8[4];
    #pragma unroll
    for (int s = 0; s < 4; ++s) {
        int id = tid + s * 256;
        aPl[s] = id >> 9; int rem = id & 511;
        aM[s] = rem >> 3; aK8[s] = (rem & 7) * 8;
    }
    int bN[4], bK8[4];
    #pragma unroll
    for (int s = 0; s < 4; ++s) {
        int id = tid + s * 256;
        bN[s] = id >> 3; bK8[s] = (id & 7) * 8;
    }

    f32x4 acc[2][4] = {};
    ushort8v aReg[4], bReg[4];

    // prologue: load slice-local k = 0 and stage
    #pragma unroll
    for (int s = 0; s < 4; ++s)
        aReg[s] = *(const ushort8v*)(Wl1p + (long long)aPl[s] * 1048576 +
                                     (long long)(m0 + aM[s]) * 2048 + ks0 + aK8[s]);
    #pragma unroll
    for (int s = 0; s < 4; ++s)
        bReg[s] = *(const ushort8v*)(InF + (long long)(n0 + bN[s]) * 2048 + ks0 + bK8[s]);
    #pragma unroll
    for (int s = 0; s < 4; ++s) *(ushort8v*)&As[aPl[s]][aM[s]][aK8[s]] = aReg[s];
    #pragma unroll
    for (int s = 0; s < 4; ++s) *(ushort8v*)&Bs[bN[s]][bK8[s]] = bReg[s];
    __syncthreads();

    for (int it = 0; it < 8; ++it) {
        const int kn = ks0 + (it + 1) * 64;
        if (it < 7) {
            #pragma unroll
            for (int s = 0; s < 4; ++s)
                aReg[s] = *(const ushort8v*)(Wl1p + (long long)aPl[s] * 1048576 +
                                             (long long)(m0 + aM[s]) * 2048 + kn + aK8[s]);
            #pragma unroll
            for (int s = 0; s < 4; ++s)
                bReg[s] = *(const ushort8v*)(InF + (long long)(n0 + bN[s]) * 2048 + kn + bK8[s]);
        }

        #pragma unroll
        for (int ks = 0; ks < 2; ++ks) {
            bf16x8 bfr[4];
            #pragma unroll
            for (int nt = 0; nt < 4; ++nt)
                bfr[nt] = *(const bf16x8*)&Bs[wx * 64 + nt * 16 + l15][ks * 32 + kq * 8];
            #pragma unroll
            for (int s = 0; s < 2; ++s) {
                #pragma unroll
                for (int mt = 0; mt < 2; ++mt) {
                    bf16x8 afr = *(const bf16x8*)&As[s][wy * 32 + mt * 16 + l15][ks * 32 + kq * 8];
                    #pragma unroll
                    for (int nt = 0; nt < 4; ++nt)
                        acc[mt][nt] = __builtin_amdgcn_mfma_f32_16x16x32_bf16(
                            afr, bfr[nt], acc[mt][nt], 0, 0, 0);
                }
            }
        }
        __syncthreads();
        if (it < 7) {
            #pragma unroll
            for (int s = 0; s < 4; ++s) *(ushort8v*)&As[aPl[s]][aM[s]][aK8[s]] = aReg[s];
            #pragma unroll
            for (int s = 0; s < 4; ++s) *(ushort8v*)&Bs[bN[s]][bK8[s]] = bReg[s];
            __syncthreads();
        }
    }

    // Epilogue: transpose 64m x 128n tile through LDS (64 x 129 floats =
    // 33 KB <= 36.9 KB), then c-major coalesced stores.
    float* T = (float*)SMEM;
    __syncthreads();
    #pragma unroll
    for (int mt = 0; mt < 2; ++mt) {
        #pragma unroll
        for (int i = 0; i < 4; ++i) {
            int mL = wy * 32 + mt * 16 + kq * 4 + i;
            #pragma unroll
            for (int nt = 0; nt < 4; ++nt) {
                int nL = wx * 64 + nt * 16 + l15;
                T[mL * 129 + nL] = acc[mt][nt][i];
            }
        }
    }
    __syncthreads();

    float* Zs = Zp + (long long)blockIdx.z * 2555904;
    #pragma unroll
    for (int s2 = 0; s2 < 32; ++s2) {
        int id = tid + s2 * 256;       // 0..8191
        int cL = id >> 6;              // local n 0..127
        int mL = id & 63;
        int n = n0 + cL;
        int bb = n / 156, cc = n - bb * 156;
        Zs[(long long)cc * 16384 + bb * 512 + m0 + mL] = T[mL * 129 + cL];
    }
}

// ---------------------------------------------------------------------------
// Branch-1 GEMM2 (MFMA, packed split-2 A, split-K via blockIdx.y), register
// prefetch:  Cpart[y][b][m][n] = sum_{k in slice y} A[m][k] * Bsp[b][k][n]
// Tile 32m x 128n, BK=64. grid (16, 2, 32).
// ---------------------------------------------------------------------------
__global__ __launch_bounds__(256) void gemm2_mfma(
    const unsigned short* __restrict__ Ap,
    const unsigned short* __restrict__ Bsp,
    float* __restrict__ C,
    int N, int ldb, long long bStrideB, long long cStride,
    int kPerSlice, long long partStride)
{
    __shared__ alignas(16) unsigned short As[2][32][72];
    __shared__ alignas(16) unsigned short Bs[128][72];

    const int b   = blockIdx.z;
    const int n0  = blockIdx.x * 128;
    const int ks0 = blockIdx.y * kPerSlice;
    const int tid  = threadIdx.x;
    const int lane = tid & 63, w = tid >> 6;
    const int l15 = lane & 15, kq = lane >> 4;

    const unsigned short* Bb = Bsp + (long long)b * bStrideB;

    // staging coordinates
    int aPl[2], aM[2], aK8[2];
    #pragma unroll
    for (int s = 0; s < 2; ++s) {
        int id = tid + s * 256;
        aPl[s] = id >> 8; int rem = id & 255;
        aM[s] = rem >> 3; aK8[s] = (rem & 7) * 8;
    }
    const int kb = (tid >> 4) * 4;
    const int nb = (tid & 15) * 8;

    f32x4 acc[2][2] = {};
    ushort8v aReg[2], bReg[4];

    auto loadA = [&](int k0) {
        #pragma unroll
        for (int s = 0; s < 2; ++s)
            aReg[s] = *(const ushort8v*)(Ap + (long long)aPl[s] * 16384 +
                                         (long long)aM[s] * 512 + k0 + aK8[s]);
    };
    auto loadB = [&](int k0) {
        #pragma unroll
        for (int kk2 = 0; kk2 < 4; ++kk2)
            bReg[kk2] = *(const ushort8v*)(Bb + (long long)(k0 + kb + kk2) * ldb + n0 + nb);
    };
    auto stage = [&]() {
        #pragma unroll
        for (int s = 0; s < 2; ++s) *(ushort8v*)&As[aPl[s]][aM[s]][aK8[s]] = aReg[s];
        #pragma unroll
        for (int j = 0; j < 8; ++j) {
            ushort4v v4 = { bReg[0][j], bReg[1][j], bReg[2][j], bReg[3][j] };
            *(ushort4v*)&Bs[nb + j][kb] = v4;
        }
    };

    const int nIter = kPerSlice >> 6;
    loadA(ks0); loadB(ks0);
    stage();
    __syncthreads();

    for (int it = 0; it < nIter; ++it) {
        const int kn = ks0 + (it + 1) * 64;
        if (it < nIter - 1) { loadA(kn); loadB(kn); }

        #pragma unroll
        for (int ks = 0; ks < 2; ++ks) {
            bf16x8 bfr[2];
            #pragma unroll
            for (int nt = 0; nt < 2; ++nt)
                bfr[nt] = *(const bf16x8*)&Bs[w * 32 + nt * 16 + l15][ks * 32 + kq * 8];
            #pragma unroll
            for (int s = 0; s < 2; ++s) {
                #pragma unroll
                for (int mt = 0; mt < 2; ++mt) {
                    bf16x8 afr = *(const bf16x8*)&As[s][mt * 16 + l15][ks * 32 + kq * 8];
                    #pragma unroll
                    for (int nt = 0; nt < 2; ++nt)
                        acc[mt][nt] = __builtin_amdgcn_mfma_f32_16x16x32_bf16(
                            afr, bfr[nt], acc[mt][nt], 0, 0, 0);
                }
            }
        }
        __syncthreads();
        if (it < nIter - 1) {
            stage();
            __syncthreads();
        }
    }

    float* Cb = C + (long long)b * cStride + (long long)blockIdx.y * partStride;
    #pragma unroll
    for (int mt = 0; mt < 2; ++mt) {
        #pragma unroll
        for (int i = 0; i < 4; ++i) {
            int m = mt * 16 + kq * 4 + i;
            if (m >= 20) continue;
            #pragma unroll
            for (int nt = 0; nt < 2; ++nt) {
                int n = n0 + w * 32 + nt * 16 + l15;
                Cb[(long long)m * N + n] = acc[mt][nt][i];
            }
        }
    }
}

// ---------------------------------------------------------------------------
// Branch-2 layer-2 GEMM: C[b][m][c] = sum_h Wl2[m][h] * L1T[c][b*512+h]
// ---------------------------------------------------------------------------
__global__ __launch_bounds__(256) void gemm2B_mfma(
    const unsigned short* __restrict__ Ap,   // [2][32][512] Wl2 planes
    const unsigned short* __restrict__ L1T,  // [156][16384] bf16 spikes
    float* __restrict__ Cl2)                 // [32][20][156]
{
    __shared__ alignas(16) unsigned short As[2][32][72];
    __shared__ alignas(16) unsigned short Bs[128][72];

    const int b  = blockIdx.z;
    const int n0 = blockIdx.x * 128;
    const int tid  = threadIdx.x;
    const int lane = tid & 63, w = tid >> 6;
    const int l15 = lane & 15, kq = lane >> 4;

    f32x4 acc[2][2] = {};

    for (int k0 = 0; k0 < 512; k0 += 64) {
        #pragma unroll
        for (int s = 0; s < 2; ++s) {
            int id = tid + s * 256;
            int pl = id >> 8, rem = id & 255;
            int m = rem >> 3, k8 = (rem & 7) * 8;
            ushort8v v = *(const ushort8v*)(Ap + (long long)pl * 16384 +
                                            (long long)m * 512 + k0 + k8);
            *(ushort8v*)&As[pl][m][k8] = v;
        }
        #pragma unroll
        for (int s = 0; s < 4; ++s) {
            int id = tid + s * 256;
            int n = id >> 3, k8 = (id & 7) * 8;
            ushort8v v = {0,0,0,0,0,0,0,0};
            if (n0 + n < 156)
                v = *(const ushort8v*)(L1T + (long long)(n0 + n) * 16384 +
                                       b * 512 + k0 + k8);
            *(ushort8v*)&Bs[n][k8] = v;
        }
        __syncthreads();

        #pragma unroll
        for (int ks = 0; ks < 2; ++ks) {
            bf16x8 bfr[2];
            #pragma unroll
            for (int nt = 0; nt < 2; ++nt)
                bfr[nt] = *(const bf16x8*)&Bs[w * 32 + nt * 16 + l15][ks * 32 + kq * 8];
            #pragma unroll
            for (int s = 0; s < 2; ++s) {
                #pragma unroll
                for (int mt = 0; mt < 2; ++mt) {
                    bf16x8 afr = *(const bf16x8*)&As[s][mt * 16 + l15][ks * 32 + kq * 8];
                    #pragma unroll
                    for (int nt = 0; nt < 2; ++nt)
                        acc[mt][nt] = __builtin_amdgcn_mfma_f32_16x16x32_bf16(
                            afr, bfr[nt], acc[mt][nt], 0, 0, 0);
                }
            }
        }
        __syncthreads();
    }

    float* Cb = Cl2 + (long long)b * 20 * 156;
    #pragma unroll
    for (int mt = 0; mt < 2; ++mt) {
        #pragma unroll
        for (int i = 0; i < 4; ++i) {
            int m = mt * 16 + kq * 4 + i;
            if (m >= 20) continue;
            #pragma unroll
            for (int nt = 0; nt < 2; ++nt) {
                int n = n0 + w * 32 + nt * 16 + l15;
                if (n < 156) Cb[(long long)m * 156 + n] = acc[mt][nt][i];
            }
        }
    }
}

// ---------------------------------------------------------------------------
// Alpha-scan + spike over T=2048 per row, bf16 in -> bf16 spikes, IN PLACE.
// ---------------------------------------------------------------------------
__global__ __launch_bounds__(256) void scan_spike_bf(unsigned short* data)
{
    const int row = blockIdx.x;
    const int tid = threadIdx.x;
    unsigned short* x = data + (long long)row * 2048 + tid * 8;

    ushort8v raw = *(const ushort8v*)x;
    float v[8];
    #pragma unroll
    for (int k = 0; k < 8; ++k) v[k] = bf2f(raw[k]);

    float y = 0.f;
    #pragma unroll
    for (int k = 0; k < 8; ++k) { y = ALPHA * y + v[k]; v[k] = y; }

    __shared__ float sc[256];
    float val = y;
    sc[tid] = val;
    float m = ALPHA8;
    for (int d = 1; d < 256; d <<= 1) {
        __syncthreads();
        float p = (tid >= d) ? sc[tid - d] : 0.f;
        __syncthreads();
        val += m * p;
        sc[tid] = val;
        m *= m;
    }
    __syncthreads();
    float carry = (tid > 0) ? sc[tid - 1] : 0.f;

    ushort8v ov;
    float ak = ALPHA;
    #pragma unroll
    for (int k = 0; k < 8; ++k) {
        float yk = v[k] + ak * carry;
        ak *= ALPHA;
        ov[k] = (yk >= THETA) ? BF1 : 0;
    }
    *(ushort8v*)x = ov;
}

// ---------------------------------------------------------------------------
// Final T-scan summing two split-K partials -> fp32 spikes to d_out.
// ---------------------------------------------------------------------------
__global__ __launch_bounds__(256) void scan_spike_T2(
    const float* __restrict__ in, long long partStride,
    float* __restrict__ out, long long out_stride)
{
    const int row = blockIdx.x;
    const int tid = threadIdx.x;
    const float* x = in + (long long)row * 2048 + tid * 8;

    float v[8];
    #pragma unroll
    for (int k = 0; k < 8; ++k) v[k] = x[k] + x[k + partStride];

    float y = 0.f;
    #pragma unroll
    for (int k = 0; k < 8; ++k) { y = ALPHA * y + v[k]; v[k] = y; }

    __shared__ float sc[256];
    float val = y;
    sc[tid] = val;
    float m = ALPHA8;
    for (int d = 1; d < 256; d <<= 1) {
        __syncthreads();
        float p = (tid >= d) ? sc[tid - d] : 0.f;
        __syncthreads();
        val += m * p;
        sc[tid] = val;
        m *= m;
    }
    __syncthreads();
    float carry = (tid > 0) ? sc[tid - 1] : 0.f;

    float* o = out + (long long)row * out_stride + tid * 8;
    float ak = ALPHA;
    #pragma unroll
    for (int k = 0; k < 8; ++k) {
        float yk = v[k] + ak * carry;
        ak *= ALPHA;
        o[k] = (yk >= THETA) ? 1.0f : 0.0f;
    }
}

// ---------------------------------------------------------------------------
// Branch-2 layer-1 scan, c-major: sum 4 partials Zp[s][c][row] (coalesced),
// scan over c in perm order via LDS, write spikes c-major to L1T[c][row].
// ---------------------------------------------------------------------------
__global__ __launch_bounds__(256) void scan_sum4_perm(
    const float* __restrict__ Zp, const int* __restrict__ perm,
    unsigned short* __restrict__ L1T)
{
    __shared__ float Xs[156][64];   // 39.9 KB
    __shared__ int p[156];

    const int r0  = blockIdx.x * 64;
    const int tid = threadIdx.x;
    for (int i = tid; i < 156; i += 256) p[i] = perm[i];

    const int row = tid & 63;
    const int cq  = tid >> 6;
    #pragma unroll
    for (int it = 0; it < 39; ++it) {
        int c = it * 4 + cq;
        long long base = (long long)c * 16384 + r0 + row;
        float s = Zp[base] + Zp[base + 2555904] +
                  Zp[base + 2 * 2555904] + Zp[base + 3 * 2555904];
        Xs[c][row] = s;
    }
    __syncthreads();

    if (tid < 64) {
        float y = 0.f;
        for (int c = 0; c < 156; ++c) {
            y = ALPHA * y + Xs[p[c]][tid];
            L1T[(long long)c * 16384 + r0 + tid] = (y >= THETA) ? BF1 : 0;
        }
    }
}

__global__ __launch_bounds__(256) void scan_spike_C_out(
    const float* __restrict__ in, float* __restrict__ out, int rows)
{
    int row = blockIdx.x * blockDim.x + threadIdx.x;
    if (row >= rows) return;
    const float* x = in + (long long)row * 156;
    float* o = out + (long long)row * 2204 + 2048;
    float y = 0.f;
    for (int c = 0; c < 156; ++c) {
        y = ALPHA * y + x[c];
        o[c] = (y >= THETA) ? 1.0f : 0.0f;
    }
}

// ---------------------------------------------------------------------------
// B=32, C_IN=156, T=2048, HID=512, OUT=20. Output [32,20,2204].
// ---------------------------------------------------------------------------
extern "C" void kernel_launch(void* const* d_in, const int* in_sizes, int n_in,
                              void* d_out, int out_size, void* d_ws, size_t ws_size,
                              hipStream_t stream)
{
    const float* In  = (const float*)d_in[0];  // [32][156][2048]
    const float* W1  = (const float*)d_in[1];  // [512][156]
    const float* W2  = (const float*)d_in[2];  // [20][512]
    const float* Wl1 = (const float*)d_in[3];  // [512][2048]
    const float* Wl2 = (const float*)d_in[4];  // [20][512]
    const int*  perm = (const int*)d_in[5];    // [156]
    float* out = (float*)d_out;                // [32][20][2204]

    float* ws = (float*)d_ws;
    // Layout (float offsets), total 123.7 MB (ws is 256 MiB):
    unsigned short* D1bf = (unsigned short*)ws;        // [32][512][2048] bf16 (in-place spikes)
    float* C2p = ws + 16777216LL;                      // [2][32][20][2048] partials
    unsigned short* Inbf = (unsigned short*)(ws + 19398656LL); // [4992][2048]
    unsigned short* InT  = (unsigned short*)(ws + 24510464LL); // [32][2048][160]
    unsigned short* W1p  = (unsigned short*)(ws + 29753344LL); // [2][512][160]
    unsigned short* W2p  = (unsigned short*)(ws + 29835264LL); // [2][32][512]
    unsigned short* Wl1p = (unsigned short*)(ws + 29851648LL); // [2][512][2048]
    unsigned short* Wl2p = (unsigned short*)(ws + 30900224LL); // [2][32][512]
    // Branch-2 phase reuses the dead D1bf region:
    float* Zp = ws;                                    // [4][156][16384] c-major
    unsigned short* L1T = (unsigned short*)(ws + 10223616LL);  // [156][16384] bf16
    float* Cl2 = ws + 11501568LL;                      // [32][20][156]

    dim3 blk(256);

    // ---- Preprocess ----
    prep_in<<<dim3(32, 3, 32), blk, 0, stream>>>(In, Inbf, InT);
    pack_all<<<dim3(1088), blk, 0, stream>>>(W1, W2, Wl1, Wl2,
                                             W1p, W2p, Wl1p, Wl2p);

    // ---- Branch 1 (full batch, bf16 D1 roundtrip) ----
    gemm1_mfma<<<dim3(16, 4, 32), blk, 0, stream>>>(W1p, InT, D1bf);
    scan_spike_bf<<<dim3(16384), blk, 0, stream>>>(D1bf);
    gemm2_mfma<<<dim3(16, 2, 32), blk, 0, stream>>>(
        W2p, D1bf, C2p, 2048, 2048, 512LL * 2048, 20LL * 2048, 256, 1310720LL);
    scan_spike_T2<<<dim3(640), blk, 0, stream>>>(C2p, 1310720LL, out, 2204);

    // ---- Branch 2 ----
    gemmL1_mfma<<<dim3(40, 8, 4), blk, 0, stream>>>(Wl1p, Inbf, Zp);
    scan_sum4_perm<<<dim3(256), blk, 0, stream>>>(Zp, perm, L1T);
    gemm2B_mfma<<<dim3(2, 1, 32), blk, 0, stream>>>(Wl2p, L1T, Cl2);
    scan_spike_C_out<<<dim3(3), blk, 0, stream>>>(Cl2, out, 640);

    (void)in_sizes; (void)n_in; (void)out_size; (void)ws_size;
}

// Round 11
// 231.667 us; speedup vs baseline: 1.3228x; 1.1032x over previous
//
#include <hip/hip_runtime.h>

// SLAYER constants
#define ALPHA  0.90483741803595952f   /* exp(-1/10) */
#define ALPHA8 0.44932896411722156f   /* exp(-0.8)  */
#define THETA  10.0f
#define BF1    ((unsigned short)0x3F80) /* 1.0f as bf16 */

typedef short   bf16x8 __attribute__((ext_vector_type(8)));
typedef float   f32x4  __attribute__((ext_vector_type(4)));
typedef float   f32x4v __attribute__((ext_vector_type(4)));
typedef unsigned short ushort4v __attribute__((ext_vector_type(4)));
typedef unsigned short ushort8v __attribute__((ext_vector_type(8)));
typedef unsigned char  uchar4v  __attribute__((ext_vector_type(4)));
typedef unsigned char  uchar8v  __attribute__((ext_vector_type(8)));
typedef long long i64;

// RNE float -> bf16 bits
__device__ __forceinline__ unsigned short f2bf(float f) {
    unsigned int x = __float_as_uint(f);
    unsigned int r = (x + 0x7FFFu + ((x >> 16) & 1u)) >> 16;
    return (unsigned short)r;
}
__device__ __forceinline__ float bf2f(unsigned short h) {
    return __uint_as_float(((unsigned int)h) << 16);
}
// 2-way bf16 split: w ~= h0+h1 (residual ~2^-17 rel)
__device__ __forceinline__ void split2(float w, unsigned short& h0,
                                       unsigned short& h1) {
    h0 = f2bf(w);          float r0 = w - bf2f(h0);
    h1 = f2bf(r0);
}
// HW fp8 converts (format matches the HW MFMA fp8 format on gfx950)
__device__ __forceinline__ unsigned char f2fp8(float f) {
    int pk = __builtin_amdgcn_cvt_pk_fp8_f32(f, 0.f, 0, false);
    return (unsigned char)(pk & 0xFF);
}
__device__ __forceinline__ float fp82f(unsigned char b) {
    return __builtin_amdgcn_cvt_f32_fp8((int)b, 0);
}

// ---------------------------------------------------------------------------
// prep_scan: one block per row (b*156+c) of In [4992][2048]:
//   Inbf[row][t] = bf16(x)          (raw, for branch-2 GEMM)
//   Pbf [row][t] = bf16(psp_t(x))   (scanned; psp commutes with W1-dense)
// ---------------------------------------------------------------------------
__global__ __launch_bounds__(256) void prep_scan(
    const float* __restrict__ In, unsigned short* __restrict__ Inbf,
    unsigned short* __restrict__ Pbf)
{
    const int row = blockIdx.x;
    const int tid = threadIdx.x;
    const float* x = In + (long long)row * 2048 + tid * 8;

    float v[8];
    *(f32x4v*)&v[0] = *(const f32x4v*)x;
    *(f32x4v*)&v[4] = *(const f32x4v*)(x + 4);

    // raw bf16
    ushort8v raw;
    #pragma unroll
    for (int k = 0; k < 8; ++k) raw[k] = f2bf(v[k]);
    *(ushort8v*)(Inbf + (long long)row * 2048 + tid * 8) = raw;

    // local scan
    float y = 0.f;
    #pragma unroll
    for (int k = 0; k < 8; ++k) { y = ALPHA * y + v[k]; v[k] = y; }

    __shared__ float sc[256];
    float val = y;
    sc[tid] = val;
    float m = ALPHA8;
    for (int d = 1; d < 256; d <<= 1) {
        __syncthreads();
        float p = (tid >= d) ? sc[tid - d] : 0.f;
        __syncthreads();
        val += m * p;
        sc[tid] = val;
        m *= m;
    }
    __syncthreads();
    float carry = (tid > 0) ? sc[tid - 1] : 0.f;

    ushort8v pv;
    float ak = ALPHA;
    #pragma unroll
    for (int k = 0; k < 8; ++k) {
        float yk = v[k] + ak * carry;
        ak *= ALPHA;
        pv[k] = f2bf(yk);
    }
    *(ushort8v*)(Pbf + (long long)row * 2048 + tid * 8) = pv;
}

// ---------------------------------------------------------------------------
// transposeP: Pbf [32*156][2048] bf16 -> PT [32][2048][160] (c padded to 160).
// Guarded against the c-row overflow (writes only fully-in-row ushort8).
// ---------------------------------------------------------------------------
__global__ __launch_bounds__(256) void transposeP(
    const unsigned short* __restrict__ Pbf, unsigned short* __restrict__ PT)
{
    __shared__ unsigned short Tile[64][72];
    const int t0 = blockIdx.x * 64;
    const int c0 = blockIdx.y * 64;
    const int b  = blockIdx.z;
    const int tid = threadIdx.x;

    #pragma unroll
    for (int s = 0; s < 2; ++s) {
        int id = tid + s * 256;
        int cc = id >> 3;
        int t8 = (id & 7) * 8;
        ushort8v v = {0,0,0,0,0,0,0,0};
        if (c0 + cc < 156)
            v = *(const ushort8v*)(Pbf + (long long)(b * 156 + c0 + cc) * 2048 + t0 + t8);
        *(ushort8v*)&Tile[cc][t8] = v;
    }
    __syncthreads();

    #pragma unroll
    for (int s = 0; s < 2; ++s) {
        int id = tid + s * 256;
        int t  = id >> 3;
        int c8 = (id & 7) * 8;
        if (c0 + c8 + 7 < 160) {          // stay fully inside the 160-wide row
            unsigned short r[8];
            #pragma unroll
            for (int j = 0; j < 8; ++j) r[j] = Tile[c8 + j][t];
            *(ushort8v*)(PT + (long long)b * 327680 + (long long)(t0 + t) * 160 + c0 + c8)
                = *(ushort8v*)r;
        }
    }
}

// ---------------------------------------------------------------------------
// Pack weights: W1/Wl1/Wl2 -> split-2 bf16 planes; W2 -> split-2 FP8 planes.
// ---------------------------------------------------------------------------
__global__ __launch_bounds__(256) void pack_all(
    const float* __restrict__ W1,  const float* __restrict__ W2,
    const float* __restrict__ Wl1, const float* __restrict__ Wl2,
    unsigned short* __restrict__ W1p,  unsigned char* __restrict__ W2p8,
    unsigned short* __restrict__ Wl1p, unsigned short* __restrict__ Wl2p)
{
    const int bidx = blockIdx.x;
    if (bidx >= 512 && bidx < 544) {       // W2 -> fp8 2-plane
        int m = bidx - 512;
        for (int k = threadIdx.x; k < 512; k += 256) {
            float w = (m < 20) ? W2[(long long)m * 512 + k] : 0.f;
            unsigned char h0 = f2fp8(w);
            float back = fp82f(h0);
            unsigned char h1 = f2fp8(w - back);
            W2p8[(long long)m * 512 + k] = h0;
            W2p8[16384 + (long long)m * 512 + k] = h1;
        }
        return;
    }
    const float* W; unsigned short* P; int M, K, Kp, Mp, m;
    if (bidx < 512)       { W = W1;  P = W1p;  M = 512; K = 156;  Kp = 160;  Mp = 512; m = bidx; }
    else if (bidx < 1056) { W = Wl1; P = Wl1p; M = 512; K = 2048; Kp = 2048; Mp = 512; m = bidx - 544; }
    else                  { W = Wl2; P = Wl2p; M = 20;  K = 512;  Kp = 512;  Mp = 32;  m = bidx - 1056; }

    for (int k = threadIdx.x; k < Kp; k += 256) {
        float v = (m < M && k < K) ? W[(long long)m * K + k] : 0.f;
        unsigned short h0, h1;
        split2(v, h0, h1);
        P[(long long)m * Kp + k] = h0;
        P[(long long)Mp * Kp + (long long)m * Kp + k] = h1;
    }
}

// ---------------------------------------------------------------------------
// Branch-1 GEMM1 (MFMA, packed split-2, register prefetch), FUSED THRESHOLD:
//   u[b][m][n] = sum_c W1[m][c] * psp(In)[b][c][n]  (psp commuted)
//   S1p8[b][m][n] = fp8(u >= THETA)
// Tile 128x128, BK=32, 5 iters. grid (16 n, 4 m, 32 b).
// ---------------------------------------------------------------------------
__global__ __launch_bounds__(256) void gemm1_mfma(
    const unsigned short* __restrict__ W1p,
    const unsigned short* __restrict__ PT,
    unsigned char* __restrict__ S1p8)    // [32][512][2048] fp8 spikes
{
    __shared__ alignas(16) unsigned short As[2][128][40];
    __shared__ alignas(16) unsigned short Bs[128][40];

    const int z  = blockIdx.z;
    const int m0 = blockIdx.y * 128;
    const int n0 = blockIdx.x * 128;
    const int tid  = threadIdx.x;
    const int lane = tid & 63, w = tid >> 6;
    const int wy = w >> 1, wx = w & 1;
    const int l15 = lane & 15, kq = lane >> 4;

    const unsigned short* Tb = PT + (long long)z * 327680;

    int aPl[4], aM[4], aK8[4];
    #pragma unroll
    for (int s = 0; s < 4; ++s) {
        int id = tid + s * 256;
        aPl[s] = id >> 9; int rem = id & 511;
        aM[s] = rem >> 2; aK8[s] = (rem & 3) * 8;
    }
    int bT[2], bC8[2];
    #pragma unroll
    for (int s = 0; s < 2; ++s) {
        int id = tid + s * 256;
        bT[s] = id >> 2; bC8[s] = (id & 3) * 8;
    }

    f32x4 acc[4][4] = {};
    ushort8v aReg[4], bReg[2];

    #pragma unroll
    for (int s = 0; s < 4; ++s)
        aReg[s] = *(const ushort8v*)(W1p + (long long)aPl[s] * 81920 +
                                     (long long)(m0 + aM[s]) * 160 + aK8[s]);
    #pragma unroll
    for (int s = 0; s < 2; ++s)
        bReg[s] = *(const ushort8v*)(Tb + (long long)(n0 + bT[s]) * 160 + bC8[s]);
    #pragma unroll
    for (int s = 0; s < 4; ++s) *(ushort8v*)&As[aPl[s]][aM[s]][aK8[s]] = aReg[s];
    #pragma unroll
    for (int s = 0; s < 2; ++s) *(ushort8v*)&Bs[bT[s]][bC8[s]] = bReg[s];
    __syncthreads();

    #pragma unroll
    for (int it = 0; it < 5; ++it) {
        const int kn = (it + 1) * 32;
        if (it < 4) {
            #pragma unroll
            for (int s = 0; s < 4; ++s)
                aReg[s] = *(const ushort8v*)(W1p + (long long)aPl[s] * 81920 +
                                             (long long)(m0 + aM[s]) * 160 + kn + aK8[s]);
            #pragma unroll
            for (int s = 0; s < 2; ++s)
                bReg[s] = *(const ushort8v*)(Tb + (long long)(n0 + bT[s]) * 160 + kn + bC8[s]);
        }

        bf16x8 bfr[4];
        #pragma unroll
        for (int nt = 0; nt < 4; ++nt)
            bfr[nt] = *(const bf16x8*)&Bs[wx * 64 + nt * 16 + l15][kq * 8];
        #pragma unroll
        for (int s = 0; s < 2; ++s) {
            #pragma unroll
            for (int mt = 0; mt < 4; ++mt) {
                bf16x8 afr = *(const bf16x8*)&As[s][wy * 64 + mt * 16 + l15][kq * 8];
                #pragma unroll
                for (int nt = 0; nt < 4; ++nt)
                    acc[mt][nt] = __builtin_amdgcn_mfma_f32_16x16x32_bf16(
                        afr, bfr[nt], acc[mt][nt], 0, 0, 0);
            }
        }
        __syncthreads();
        if (it < 4) {
            #pragma unroll
            for (int s = 0; s < 4; ++s) *(ushort8v*)&As[aPl[s]][aM[s]][aK8[s]] = aReg[s];
            #pragma unroll
            for (int s = 0; s < 2; ++s) *(ushort8v*)&Bs[bT[s]][bC8[s]] = bReg[s];
            __syncthreads();
        }
    }

    const unsigned char ONE8 = f2fp8(1.0f);
    unsigned char* Db = S1p8 + (long long)z * 512 * 2048;
    #pragma unroll
    for (int mt = 0; mt < 4; ++mt) {
        #pragma unroll
        for (int i = 0; i < 4; ++i) {
            int m = m0 + wy * 64 + mt * 16 + kq * 4 + i;
            #pragma unroll
            for (int nt = 0; nt < 4; ++nt) {
                int n = n0 + wx * 64 + nt * 16 + l15;
                Db[(long long)m * 2048 + n] = (acc[mt][nt][i] >= THETA) ? ONE8 : 0;
            }
        }
    }
}

// ---------------------------------------------------------------------------
// Branch-1 GEMM2 (FP8 MFMA, split-2 fp8 A, split-K, register prefetch):
//   Cpart[y][b][m][n] = sum_{k in slice y} W2[m][k] * s1[b][k][n]
// Tile 32m x 128n, BK=64. grid (16, 2, 32).
// ---------------------------------------------------------------------------
__global__ __launch_bounds__(256) void gemm2_fp8(
    const unsigned char* __restrict__ Ap,    // [2][32][512] fp8 planes
    const unsigned char* __restrict__ Bsp,   // [32][512][2048] fp8 spikes
    float* __restrict__ C,
    int kPerSlice, long long partStride)
{
    __shared__ alignas(16) unsigned char As[2][32][72];
    __shared__ alignas(16) unsigned char Bs[128][72];

    const int b   = blockIdx.z;
    const int n0  = blockIdx.x * 128;
    const int ks0 = blockIdx.y * kPerSlice;
    const int tid  = threadIdx.x;
    const int lane = tid & 63, w = tid >> 6;
    const int l15 = lane & 15, kq = lane >> 4;

    const unsigned char* Bb = Bsp + (long long)b * 1048576;

    int aPl[2], aM[2], aK8[2];
    #pragma unroll
    for (int s = 0; s < 2; ++s) {
        int id = tid + s * 256;
        aPl[s] = id >> 8; int rem = id & 255;
        aM[s] = rem >> 3; aK8[s] = (rem & 7) * 8;
    }
    const int kb = (tid >> 4) * 4;
    const int nb = (tid & 15) * 8;

    f32x4 acc[2][2] = {};
    uchar8v aReg[2], bReg[4];

    auto loadA = [&](int k0) {
        #pragma unroll
        for (int s = 0; s < 2; ++s)
            aReg[s] = *(const uchar8v*)(Ap + (long long)aPl[s] * 16384 +
                                        (long long)aM[s] * 512 + k0 + aK8[s]);
    };
    auto loadB = [&](int k0) {
        #pragma unroll
        for (int kk2 = 0; kk2 < 4; ++kk2)
            bReg[kk2] = *(const uchar8v*)(Bb + (long long)(k0 + kb + kk2) * 2048 + n0 + nb);
    };
    auto stage = [&]() {
        #pragma unroll
        for (int s = 0; s < 2; ++s) *(uchar8v*)&As[aPl[s]][aM[s]][aK8[s]] = aReg[s];
        #pragma unroll
        for (int j = 0; j < 8; ++j) {
            uchar4v v4 = { bReg[0][j], bReg[1][j], bReg[2][j], bReg[3][j] };
            *(uchar4v*)&Bs[nb + j][kb] = v4;
        }
    };

    const int nIter = kPerSlice >> 6;
    loadA(ks0); loadB(ks0);
    stage();
    __syncthreads();

    for (int it = 0; it < nIter; ++it) {
        const int kn = ks0 + (it + 1) * 64;
        if (it < nIter - 1) { loadA(kn); loadB(kn); }

        #pragma unroll
        for (int ks = 0; ks < 2; ++ks) {
            i64 bfr[2];
            #pragma unroll
            for (int nt = 0; nt < 2; ++nt)
                bfr[nt] = *(const i64*)&Bs[w * 32 + nt * 16 + l15][ks * 32 + kq * 8];
            #pragma unroll
            for (int s = 0; s < 2; ++s) {
                #pragma unroll
                for (int mt = 0; mt < 2; ++mt) {
                    i64 afr = *(const i64*)&As[s][mt * 16 + l15][ks * 32 + kq * 8];
                    #pragma unroll
                    for (int nt = 0; nt < 2; ++nt)
                        acc[mt][nt] = __builtin_amdgcn_mfma_f32_16x16x32_fp8_fp8(
                            afr, bfr[nt], acc[mt][nt], 0, 0, 0);
                }
            }
        }
        __syncthreads();
        if (it < nIter - 1) {
            stage();
            __syncthreads();
        }
    }

    float* Cb = C + (long long)b * 20 * 2048 + (long long)blockIdx.y * partStride;
    #pragma unroll
    for (int mt = 0; mt < 2; ++mt) {
        #pragma unroll
        for (int i = 0; i < 4; ++i) {
            int m = mt * 16 + kq * 4 + i;
            if (m >= 20) continue;
            #pragma unroll
            for (int nt = 0; nt < 2; ++nt) {
                int n = n0 + w * 32 + nt * 16 + l15;
                Cb[(long long)m * 2048 + n] = acc[mt][nt][i];
            }
        }
    }
}

// ---------------------------------------------------------------------------
// Branch-2 GEMM1 (MFMA, packed split-2), batch merged into N, SPLIT-K x4,
// register prefetch. Tile 64m x 128n. grid (40, 8, 4) (x padded for XCD
// alignment of shared B n-tiles). Epilogue: LDS transpose -> c-major Zp.
// ---------------------------------------------------------------------------
__global__ __launch_bounds__(256) void gemmL1_mfma(
    const unsigned short* __restrict__ Wl1p,  // [2][512][2048]
    const unsigned short* __restrict__ InF,   // [4992][2048] bf16
    float* __restrict__ Zp)                   // [4][156][16384] c-major partials
{
    __shared__ alignas(16) unsigned short SMEM[18432];  // 36.9 KB
    auto As = (unsigned short (*)[64][72])SMEM;
    auto Bs = (unsigned short (*)[72])(SMEM + 9216);

    if (blockIdx.x >= 39) return;
    const int n0  = blockIdx.x * 128;
    const int m0  = blockIdx.y * 64;
    const int ks0 = blockIdx.z * 512;
    const int tid  = threadIdx.x;
    const int lane = tid & 63, w = tid >> 6;
    const int wy = w >> 1, wx = w & 1;
    const int l15 = lane & 15, kq = lane >> 4;

    int aPl[4], aM[4], aK8[4];
    #pragma unroll
    for (int s = 0; s < 4; ++s) {
        int id = tid + s * 256;
        aPl[s] = id >> 9; int rem = id & 511;
        aM[s] = rem >> 3; aK8[s] = (rem & 7) * 8;
    }
    int bN[4], bK8[4];
    #pragma unroll
    for (int s = 0; s < 4; ++s) {
        int id = tid + s * 256;
        bN[s] = id >> 3; bK8[s] = (id & 7) * 8;
    }

    f32x4 acc[2][4] = {};
    ushort8v aReg[4], bReg[4];

    #pragma unroll
    for (int s = 0; s < 4; ++s)
        aReg[s] = *(const ushort8v*)(Wl1p + (long long)aPl[s] * 1048576 +
                                     (long long)(m0 + aM[s]) * 2048 + ks0 + aK8[s]);
    #pragma unroll
    for (int s = 0; s < 4; ++s)
        bReg[s] = *(const ushort8v*)(InF + (long long)(n0 + bN[s]) * 2048 + ks0 + bK8[s]);
    #pragma unroll
    for (int s = 0; s < 4; ++s) *(ushort8v*)&As[aPl[s]][aM[s]][aK8[s]] = aReg[s];
    #pragma unroll
    for (int s = 0; s < 4; ++s) *(ushort8v*)&Bs[bN[s]][bK8[s]] = bReg[s];
    __syncthreads();

    for (int it = 0; it < 8; ++it) {
        const int kn = ks0 + (it + 1) * 64;
        if (it < 7) {
            #pragma unroll
            for (int s = 0; s < 4; ++s)
                aReg[s] = *(const ushort8v*)(Wl1p + (long long)aPl[s] * 1048576 +
                                             (long long)(m0 + aM[s]) * 2048 + kn + aK8[s]);
            #pragma unroll
            for (int s = 0; s < 4; ++s)
                bReg[s] = *(const ushort8v*)(InF + (long long)(n0 + bN[s]) * 2048 + kn + bK8[s]);
        }

        #pragma unroll
        for (int ks = 0; ks < 2; ++ks) {
            bf16x8 bfr[4];
            #pragma unroll
            for (int nt = 0; nt < 4; ++nt)
                bfr[nt] = *(const bf16x8*)&Bs[wx * 64 + nt * 16 + l15][ks * 32 + kq * 8];
            #pragma unroll
            for (int s = 0; s < 2; ++s) {
                #pragma unroll
                for (int mt = 0; mt < 2; ++mt) {
                    bf16x8 afr = *(const bf16x8*)&As[s][wy * 32 + mt * 16 + l15][ks * 32 + kq * 8];
                    #pragma unroll
                    for (int nt = 0; nt < 4; ++nt)
                        acc[mt][nt] = __builtin_amdgcn_mfma_f32_16x16x32_bf16(
                            afr, bfr[nt], acc[mt][nt], 0, 0, 0);
                }
            }
        }
        __syncthreads();
        if (it < 7) {
            #pragma unroll
            for (int s = 0; s < 4; ++s) *(ushort8v*)&As[aPl[s]][aM[s]][aK8[s]] = aReg[s];
            #pragma unroll
            for (int s = 0; s < 4; ++s) *(ushort8v*)&Bs[bN[s]][bK8[s]] = bReg[s];
            __syncthreads();
        }
    }

    float* T = (float*)SMEM;
    __syncthreads();
    #pragma unroll
    for (int mt = 0; mt < 2; ++mt) {
        #pragma unroll
        for (int i = 0; i < 4; ++i) {
            int mL = wy * 32 + mt * 16 + kq * 4 + i;
            #pragma unroll
            for (int nt = 0; nt < 4; ++nt) {
                int nL = wx * 64 + nt * 16 + l15;
                T[mL * 129 + nL] = acc[mt][nt][i];
            }
        }
    }
    __syncthreads();

    float* Zs = Zp + (long long)blockIdx.z * 2555904;
    #pragma unroll
    for (int s2 = 0; s2 < 32; ++s2) {
        int id = tid + s2 * 256;
        int cL = id >> 6;
        int mL = id & 63;
        int n = n0 + cL;
        int bb = n / 156, cc = n - bb * 156;
        Zs[(long long)cc * 16384 + bb * 512 + m0 + mL] = T[mL * 129 + cL];
    }
}

// ---------------------------------------------------------------------------
// Branch-2 layer-2 GEMM: C[b][m][c] = sum_h Wl2[m][h] * L1T[c][b*512+h]
// ---------------------------------------------------------------------------
__global__ __launch_bounds__(256) void gemm2B_mfma(
    const unsigned short* __restrict__ Ap,   // [2][32][512] Wl2 planes
    const unsigned short* __restrict__ L1T,  // [156][16384] bf16 spikes
    float* __restrict__ Cl2)                 // [32][20][156]
{
    __shared__ alignas(16) unsigned short As[2][32][72];
    __shared__ alignas(16) unsigned short Bs[128][72];

    const int b  = blockIdx.z;
    const int n0 = blockIdx.x * 128;
    const int tid  = threadIdx.x;
    const int lane = tid & 63, w = tid >> 6;
    const int l15 = lane & 15, kq = lane >> 4;

    f32x4 acc[2][2] = {};

    for (int k0 = 0; k0 < 512; k0 += 64) {
        #pragma unroll
        for (int s = 0; s < 2; ++s) {
            int id = tid + s * 256;
            int pl = id >> 8, rem = id & 255;
            int m = rem >> 3, k8 = (rem & 7) * 8;
            ushort8v v = *(const ushort8v*)(Ap + (long long)pl * 16384 +
                                            (long long)m * 512 + k0 + k8);
            *(ushort8v*)&As[pl][m][k8] = v;
        }
        #pragma unroll
        for (int s = 0; s < 4; ++s) {
            int id = tid + s * 256;
            int n = id >> 3, k8 = (id & 7) * 8;
            ushort8v v = {0,0,0,0,0,0,0,0};
            if (n0 + n < 156)
                v = *(const ushort8v*)(L1T + (long long)(n0 + n) * 16384 +
                                       b * 512 + k0 + k8);
            *(ushort8v*)&Bs[n][k8] = v;
        }
        __syncthreads();

        #pragma unroll
        for (int ks = 0; ks < 2; ++ks) {
            bf16x8 bfr[2];
            #pragma unroll
            for (int nt = 0; nt < 2; ++nt)
                bfr[nt] = *(const bf16x8*)&Bs[w * 32 + nt * 16 + l15][ks * 32 + kq * 8];
            #pragma unroll
            for (int s = 0; s < 2; ++s) {
                #pragma unroll
                for (int mt = 0; mt < 2; ++mt) {
                    bf16x8 afr = *(const bf16x8*)&As[s][mt * 16 + l15][ks * 32 + kq * 8];
                    #pragma unroll
                    for (int nt = 0; nt < 2; ++nt)
                        acc[mt][nt] = __builtin_amdgcn_mfma_f32_16x16x32_bf16(
                            afr, bfr[nt], acc[mt][nt], 0, 0, 0);
                }
            }
        }
        __syncthreads();
    }

    float* Cb = Cl2 + (long long)b * 20 * 156;
    #pragma unroll
    for (int mt = 0; mt < 2; ++mt) {
        #pragma unroll
        for (int i = 0; i < 4; ++i) {
            int m = mt * 16 + kq * 4 + i;
            if (m >= 20) continue;
            #pragma unroll
            for (int nt = 0; nt < 2; ++nt) {
                int n = n0 + w * 32 + nt * 16 + l15;
                if (n < 156) Cb[(long long)m * 156 + n] = acc[mt][nt][i];
            }
        }
    }
}

// ---------------------------------------------------------------------------
// Final T-scan summing two split-K partials -> fp32 spikes to d_out.
// ---------------------------------------------------------------------------
__global__ __launch_bounds__(256) void scan_spike_T2(
    const float* __restrict__ in, long long partStride,
    float* __restrict__ out, long long out_stride)
{
    const int row = blockIdx.x;
    const int tid = threadIdx.x;
    const float* x = in + (long long)row * 2048 + tid * 8;

    float v[8];
    #pragma unroll
    for (int k = 0; k < 8; ++k) v[k] = x[k] + x[k + partStride];

    float y = 0.f;
    #pragma unroll
    for (int k = 0; k < 8; ++k) { y = ALPHA * y + v[k]; v[k] = y; }

    __shared__ float sc[256];
    float val = y;
    sc[tid] = val;
    float m = ALPHA8;
    for (int d = 1; d < 256; d <<= 1) {
        __syncthreads();
        float p = (tid >= d) ? sc[tid - d] : 0.f;
        __syncthreads();
        val += m * p;
        sc[tid] = val;
        m *= m;
    }
    __syncthreads();
    float carry = (tid > 0) ? sc[tid - 1] : 0.f;

    float* o = out + (long long)row * out_stride + tid * 8;
    float ak = ALPHA;
    #pragma unroll
    for (int k = 0; k < 8; ++k) {
        float yk = v[k] + ak * carry;
        ak *= ALPHA;
        o[k] = (yk >= THETA) ? 1.0f : 0.0f;
    }
}

// ---------------------------------------------------------------------------
// Branch-2 layer-1 scan, c-major: sum 4 partials Zp[s][c][row] (coalesced),
// scan over c in perm order via LDS, write spikes c-major to L1T[c][row].
// ---------------------------------------------------------------------------
__global__ __launch_bounds__(256) void scan_sum4_perm(
    const float* __restrict__ Zp, const int* __restrict__ perm,
    unsigned short* __restrict__ L1T)
{
    __shared__ float Xs[156][64];
    __shared__ int p[156];

    const int r0  = blockIdx.x * 64;
    const int tid = threadIdx.x;
    for (int i = tid; i < 156; i += 256) p[i] = perm[i];

    const int row = tid & 63;
    const int cq  = tid >> 6;
    #pragma unroll
    for (int it = 0; it < 39; ++it) {
        int c = it * 4 + cq;
        long long base = (long long)c * 16384 + r0 + row;
        float s = Zp[base] + Zp[base + 2555904] +
                  Zp[base + 2 * 2555904] + Zp[base + 3 * 2555904];
        Xs[c][row] = s;
    }
    __syncthreads();

    if (tid < 64) {
        float y = 0.f;
        for (int c = 0; c < 156; ++c) {
            y = ALPHA * y + Xs[p[c]][tid];
            L1T[(long long)c * 16384 + r0 + tid] = (y >= THETA) ? BF1 : 0;
        }
    }
}

__global__ __launch_bounds__(256) void scan_spike_C_out(
    const float* __restrict__ in, float* __restrict__ out, int rows)
{
    int row = blockIdx.x * blockDim.x + threadIdx.x;
    if (row >= rows) return;
    const float* x = in + (long long)row * 156;
    float* o = out + (long long)row * 2204 + 2048;
    float y = 0.f;
    for (int c = 0; c < 156; ++c) {
        y = ALPHA * y + x[c];
        o[c] = (y >= THETA) ? 1.0f : 0.0f;
    }
}

// ---------------------------------------------------------------------------
// B=32, C_IN=156, T=2048, HID=512, OUT=20. Output [32,20,2204].
// ---------------------------------------------------------------------------
extern "C" void kernel_launch(void* const* d_in, const int* in_sizes, int n_in,
                              void* d_out, int out_size, void* d_ws, size_t ws_size,
                              hipStream_t stream)
{
    const float* In  = (const float*)d_in[0];  // [32][156][2048]
    const float* W1  = (const float*)d_in[1];  // [512][156]
    const float* W2  = (const float*)d_in[2];  // [20][512]
    const float* Wl1 = (const float*)d_in[3];  // [512][2048]
    const float* Wl2 = (const float*)d_in[4];  // [20][512]
    const int*  perm = (const int*)d_in[5];    // [156]
    float* out = (float*)d_out;                // [32][20][2204]

    float* ws = (float*)d_ws;
    // Layout (float offsets), total ~116 MB (ws is 256 MiB):
    unsigned char*  S1p8 = (unsigned char*)ws;                 // [32][512][2048] fp8
    float* C2p = ws + 8388608LL;                               // [2][32][20][2048]
    unsigned short* Inbf = (unsigned short*)(ws + 11010048LL); // [4992][2048]
    unsigned short* Pbf  = (unsigned short*)(ws + 16121856LL); // [4992][2048]
    unsigned short* PT   = (unsigned short*)(ws + 21233664LL); // [32][2048][160]
    unsigned short* W1p  = (unsigned short*)(ws + 26476544LL); // [2][512][160]
    unsigned char*  W2p8 = (unsigned char*)(ws + 26558464LL);  // [2][32][512] fp8
    unsigned short* Wl1p = (unsigned short*)(ws + 26566656LL); // [2][512][2048]
    unsigned short* Wl2p = (unsigned short*)(ws + 27615232LL); // [2][32][512]
    // Branch-2 phase reuses the dead S1p8+C2p region (11.0M floats >= 10.2M):
    float* Zp = ws;                                            // [4][156][16384]
    unsigned short* L1T = (unsigned short*)(ws + 27631616LL);  // [156][16384]
    float* Cl2 = ws + 28909568LL;                              // [32][20][156]

    dim3 blk(256);

    // ---- Preprocess: scan input (psp commuted past the dense), pack weights
    prep_scan<<<dim3(4992), blk, 0, stream>>>(In, Inbf, Pbf);
    transposeP<<<dim3(32, 3, 32), blk, 0, stream>>>(Pbf, PT);
    pack_all<<<dim3(1088), blk, 0, stream>>>(W1, W2, Wl1, Wl2,
                                             W1p, W2p8, Wl1p, Wl2p);

    // ---- Branch 1: u = W1*psp(In); spike fused into GEMM epilogue (fp8) ----
    gemm1_mfma<<<dim3(16, 4, 32), blk, 0, stream>>>(W1p, PT, S1p8);
    gemm2_fp8<<<dim3(16, 2, 32), blk, 0, stream>>>(W2p8, S1p8, C2p, 256, 1310720LL);
    scan_spike_T2<<<dim3(640), blk, 0, stream>>>(C2p, 1310720LL, out, 2204);

    // ---- Branch 2 ----
    gemmL1_mfma<<<dim3(40, 8, 4), blk, 0, stream>>>(Wl1p, Inbf, Zp);
    scan_sum4_perm<<<dim3(256), blk, 0, stream>>>(Zp, perm, L1T);
    gemm2B_mfma<<<dim3(2, 1, 32), blk, 0, stream>>>(Wl2p, L1T, Cl2);
    scan_spike_C_out<<<dim3(3), blk, 0, stream>>>(Cl2, out, 640);

    (void)in_sizes; (void)n_in; (void)out_size; (void)ws_size;
}

// Round 12
// 226.143 us; speedup vs baseline: 1.3551x; 1.0244x over previous
//
#include <hip/hip_runtime.h>

// SLAYER constants
#define ALPHA  0.90483741803595952f   /* exp(-1/10) */
#define ALPHA8 0.44932896411722156f   /* exp(-0.8)  */
#define THETA  10.0f
#define BF1    ((unsigned short)0x3F80) /* 1.0f as bf16 */

typedef short   bf16x8 __attribute__((ext_vector_type(8)));
typedef float   f32x4  __attribute__((ext_vector_type(4)));
typedef float   f32x4v __attribute__((ext_vector_type(4)));
typedef unsigned short ushort4v __attribute__((ext_vector_type(4)));
typedef unsigned short ushort8v __attribute__((ext_vector_type(8)));
typedef unsigned char  uchar4v  __attribute__((ext_vector_type(4)));
typedef unsigned char  uchar8v  __attribute__((ext_vector_type(8)));
typedef long long i64;

// RNE float -> bf16 bits
__device__ __forceinline__ unsigned short f2bf(float f) {
    unsigned int x = __float_as_uint(f);
    unsigned int r = (x + 0x7FFFu + ((x >> 16) & 1u)) >> 16;
    return (unsigned short)r;
}
__device__ __forceinline__ float bf2f(unsigned short h) {
    return __uint_as_float(((unsigned int)h) << 16);
}
// 2-way bf16 split: w ~= h0+h1 (residual ~2^-17 rel)
__device__ __forceinline__ void split2(float w, unsigned short& h0,
                                       unsigned short& h1) {
    h0 = f2bf(w);          float r0 = w - bf2f(h0);
    h1 = f2bf(r0);
}
// HW fp8 converts
__device__ __forceinline__ unsigned char f2fp8(float f) {
    int pk = __builtin_amdgcn_cvt_pk_fp8_f32(f, 0.f, 0, false);
    return (unsigned char)(pk & 0xFF);
}
__device__ __forceinline__ float fp82f(unsigned char b) {
    return __builtin_amdgcn_cvt_f32_fp8((int)b, 0);
}

// ---------------------------------------------------------------------------
// prep_scan: one block per row (b*156+c) of In [4992][2048]:
//   Inbf[row][t] = bf16(x)          (raw, for branch-2 GEMM)
//   Pbf [row][t] = bf16(psp_t(x))   (scanned; psp commutes with W1-dense)
// ---------------------------------------------------------------------------
__global__ __launch_bounds__(256) void prep_scan(
    const float* __restrict__ In, unsigned short* __restrict__ Inbf,
    unsigned short* __restrict__ Pbf)
{
    const int row = blockIdx.x;
    const int tid = threadIdx.x;
    const float* x = In + (long long)row * 2048 + tid * 8;

    float v[8];
    *(f32x4v*)&v[0] = *(const f32x4v*)x;
    *(f32x4v*)&v[4] = *(const f32x4v*)(x + 4);

    ushort8v raw;
    #pragma unroll
    for (int k = 0; k < 8; ++k) raw[k] = f2bf(v[k]);
    *(ushort8v*)(Inbf + (long long)row * 2048 + tid * 8) = raw;

    float y = 0.f;
    #pragma unroll
    for (int k = 0; k < 8; ++k) { y = ALPHA * y + v[k]; v[k] = y; }

    __shared__ float sc[256];
    float val = y;
    sc[tid] = val;
    float m = ALPHA8;
    for (int d = 1; d < 256; d <<= 1) {
        __syncthreads();
        float p = (tid >= d) ? sc[tid - d] : 0.f;
        __syncthreads();
        val += m * p;
        sc[tid] = val;
        m *= m;
    }
    __syncthreads();
    float carry = (tid > 0) ? sc[tid - 1] : 0.f;

    ushort8v pv;
    float ak = ALPHA;
    #pragma unroll
    for (int k = 0; k < 8; ++k) {
        float yk = v[k] + ak * carry;
        ak *= ALPHA;
        pv[k] = f2bf(yk);
    }
    *(ushort8v*)(Pbf + (long long)row * 2048 + tid * 8) = pv;
}

// ---------------------------------------------------------------------------
// transposeP: Pbf [32*156][2048] bf16 -> PT [32][2048][160] (c padded to 160).
// ---------------------------------------------------------------------------
__global__ __launch_bounds__(256) void transposeP(
    const unsigned short* __restrict__ Pbf, unsigned short* __restrict__ PT)
{
    __shared__ unsigned short Tile[64][72];
    const int t0 = blockIdx.x * 64;
    const int c0 = blockIdx.y * 64;
    const int b  = blockIdx.z;
    const int tid = threadIdx.x;

    #pragma unroll
    for (int s = 0; s < 2; ++s) {
        int id = tid + s * 256;
        int cc = id >> 3;
        int t8 = (id & 7) * 8;
        ushort8v v = {0,0,0,0,0,0,0,0};
        if (c0 + cc < 156)
            v = *(const ushort8v*)(Pbf + (long long)(b * 156 + c0 + cc) * 2048 + t0 + t8);
        *(ushort8v*)&Tile[cc][t8] = v;
    }
    __syncthreads();

    #pragma unroll
    for (int s = 0; s < 2; ++s) {
        int id = tid + s * 256;
        int t  = id >> 3;
        int c8 = (id & 7) * 8;
        if (c0 + c8 + 7 < 160) {
            unsigned short r[8];
            #pragma unroll
            for (int j = 0; j < 8; ++j) r[j] = Tile[c8 + j][t];
            *(ushort8v*)(PT + (long long)b * 327680 + (long long)(t0 + t) * 160 + c0 + c8)
                = *(ushort8v*)r;
        }
    }
}

// ---------------------------------------------------------------------------
// Pack weights: W1/Wl1/Wl2 -> split-2 bf16 planes; W2 -> split-2 FP8 planes.
// ---------------------------------------------------------------------------
__global__ __launch_bounds__(256) void pack_all(
    const float* __restrict__ W1,  const float* __restrict__ W2,
    const float* __restrict__ Wl1, const float* __restrict__ Wl2,
    unsigned short* __restrict__ W1p,  unsigned char* __restrict__ W2p8,
    unsigned short* __restrict__ Wl1p, unsigned short* __restrict__ Wl2p)
{
    const int bidx = blockIdx.x;
    if (bidx >= 512 && bidx < 544) {
        int m = bidx - 512;
        for (int k = threadIdx.x; k < 512; k += 256) {
            float w = (m < 20) ? W2[(long long)m * 512 + k] : 0.f;
            unsigned char h0 = f2fp8(w);
            float back = fp82f(h0);
            unsigned char h1 = f2fp8(w - back);
            W2p8[(long long)m * 512 + k] = h0;
            W2p8[16384 + (long long)m * 512 + k] = h1;
        }
        return;
    }
    const float* W; unsigned short* P; int M, K, Kp, Mp, m;
    if (bidx < 512)       { W = W1;  P = W1p;  M = 512; K = 156;  Kp = 160;  Mp = 512; m = bidx; }
    else if (bidx < 1056) { W = Wl1; P = Wl1p; M = 512; K = 2048; Kp = 2048; Mp = 512; m = bidx - 544; }
    else                  { W = Wl2; P = Wl2p; M = 20;  K = 512;  Kp = 512;  Mp = 32;  m = bidx - 1056; }

    for (int k = threadIdx.x; k < Kp; k += 256) {
        float v = (m < M && k < K) ? W[(long long)m * K + k] : 0.f;
        unsigned short h0, h1;
        split2(v, h0, h1);
        P[(long long)m * Kp + k] = h0;
        P[(long long)Mp * Kp + (long long)m * Kp + k] = h1;
    }
}

// ---------------------------------------------------------------------------
// Branch-1 GEMM1 (MFMA, packed split-2, register prefetch), FUSED THRESHOLD,
// BIT-PACKED spike output (exact):
//   u[b][m][n] = sum_c W1[m][c] * psp(In)[b][c][n]
//   S1bits[b][m][n/16] bit n%16 = (u >= THETA)
// Tile 128x128, BK=32, 5 iters. grid (16 n, 4 m, 32 b).
// ---------------------------------------------------------------------------
__global__ __launch_bounds__(256) void gemm1_mfma(
    const unsigned short* __restrict__ W1p,
    const unsigned short* __restrict__ PT,
    unsigned short* __restrict__ S1bits)   // [32][512][128] ushort bit-chunks
{
    __shared__ alignas(16) unsigned short As[2][128][40];
    __shared__ alignas(16) unsigned short Bs[128][40];

    const int z  = blockIdx.z;
    const int m0 = blockIdx.y * 128;
    const int n0 = blockIdx.x * 128;
    const int tid  = threadIdx.x;
    const int lane = tid & 63, w = tid >> 6;
    const int wy = w >> 1, wx = w & 1;
    const int l15 = lane & 15, kq = lane >> 4;

    const unsigned short* Tb = PT + (long long)z * 327680;

    int aPl[4], aM[4], aK8[4];
    #pragma unroll
    for (int s = 0; s < 4; ++s) {
        int id = tid + s * 256;
        aPl[s] = id >> 9; int rem = id & 511;
        aM[s] = rem >> 2; aK8[s] = (rem & 3) * 8;
    }
    int bT[2], bC8[2];
    #pragma unroll
    for (int s = 0; s < 2; ++s) {
        int id = tid + s * 256;
        bT[s] = id >> 2; bC8[s] = (id & 3) * 8;
    }

    f32x4 acc[4][4] = {};
    ushort8v aReg[4], bReg[2];

    #pragma unroll
    for (int s = 0; s < 4; ++s)
        aReg[s] = *(const ushort8v*)(W1p + (long long)aPl[s] * 81920 +
                                     (long long)(m0 + aM[s]) * 160 + aK8[s]);
    #pragma unroll
    for (int s = 0; s < 2; ++s)
        bReg[s] = *(const ushort8v*)(Tb + (long long)(n0 + bT[s]) * 160 + bC8[s]);
    #pragma unroll
    for (int s = 0; s < 4; ++s) *(ushort8v*)&As[aPl[s]][aM[s]][aK8[s]] = aReg[s];
    #pragma unroll
    for (int s = 0; s < 2; ++s) *(ushort8v*)&Bs[bT[s]][bC8[s]] = bReg[s];
    __syncthreads();

    #pragma unroll
    for (int it = 0; it < 5; ++it) {
        const int kn = (it + 1) * 32;
        if (it < 4) {
            #pragma unroll
            for (int s = 0; s < 4; ++s)
                aReg[s] = *(const ushort8v*)(W1p + (long long)aPl[s] * 81920 +
                                             (long long)(m0 + aM[s]) * 160 + kn + aK8[s]);
            #pragma unroll
            for (int s = 0; s < 2; ++s)
                bReg[s] = *(const ushort8v*)(Tb + (long long)(n0 + bT[s]) * 160 + kn + bC8[s]);
        }

        bf16x8 bfr[4];
        #pragma unroll
        for (int nt = 0; nt < 4; ++nt)
            bfr[nt] = *(const bf16x8*)&Bs[wx * 64 + nt * 16 + l15][kq * 8];
        #pragma unroll
        for (int s = 0; s < 2; ++s) {
            #pragma unroll
            for (int mt = 0; mt < 4; ++mt) {
                bf16x8 afr = *(const bf16x8*)&As[s][wy * 64 + mt * 16 + l15][kq * 8];
                #pragma unroll
                for (int nt = 0; nt < 4; ++nt)
                    acc[mt][nt] = __builtin_amdgcn_mfma_f32_16x16x32_bf16(
                        afr, bfr[nt], acc[mt][nt], 0, 0, 0);
            }
        }
        __syncthreads();
        if (it < 4) {
            #pragma unroll
            for (int s = 0; s < 4; ++s) *(ushort8v*)&As[aPl[s]][aM[s]][aK8[s]] = aReg[s];
            #pragma unroll
            for (int s = 0; s < 2; ++s) *(ushort8v*)&Bs[bT[s]][bC8[s]] = bReg[s];
            __syncthreads();
        }
    }

    // Epilogue: ballot-pack spikes. One ballot covers 4 m-rows (kq) x 16 n
    // (l15); lane l15==0 of each kq-group stores that row's 16-bit chunk.
    unsigned short* Db = S1bits + (long long)z * 512 * 128;
    #pragma unroll
    for (int mt = 0; mt < 4; ++mt) {
        #pragma unroll
        for (int i = 0; i < 4; ++i) {
            int m = m0 + wy * 64 + mt * 16 + kq * 4 + i;
            #pragma unroll
            for (int nt = 0; nt < 4; ++nt) {
                unsigned long long mask = __ballot(acc[mt][nt][i] >= THETA);
                if (l15 == 0) {
                    int nchunk = (n0 + wx * 64 + nt * 16) >> 4;
                    Db[(long long)m * 128 + nchunk] =
                        (unsigned short)((mask >> (kq * 16)) & 0xFFFFu);
                }
            }
        }
    }
}

// ---------------------------------------------------------------------------
// Branch-1 GEMM2 (FP8 MFMA, split-2 fp8 A, split-K, register prefetch),
// B expanded from bit-packed spikes during staging:
//   Cpart[y][b][m][n] = sum_{k in slice y} W2[m][k] * s1[b][k][n]
// Tile 32m x 128n, BK=64. grid (16, 2, 32).
// ---------------------------------------------------------------------------
__global__ __launch_bounds__(256) void gemm2_fp8(
    const unsigned char* __restrict__ Ap,     // [2][32][512] fp8 planes
    const unsigned short* __restrict__ S1bits,// [32][512][128] bit chunks
    float* __restrict__ C,
    int kPerSlice, long long partStride)
{
    __shared__ alignas(16) unsigned char As[2][32][72];
    __shared__ alignas(16) unsigned char Bs[128][72];

    const int b   = blockIdx.z;
    const int n0  = blockIdx.x * 128;
    const int ks0 = blockIdx.y * kPerSlice;
    const int tid  = threadIdx.x;
    const int lane = tid & 63, w = tid >> 6;
    const int l15 = lane & 15, kq = lane >> 4;

    const unsigned short* Bb = S1bits + (long long)b * 512 * 128;
    const unsigned char ONE8 = f2fp8(1.0f);

    int aPl[2], aM[2], aK8[2];
    #pragma unroll
    for (int s = 0; s < 2; ++s) {
        int id = tid + s * 256;
        aPl[s] = id >> 8; int rem = id & 255;
        aM[s] = rem >> 3; aK8[s] = (rem & 7) * 8;
    }
    const int kb = (tid >> 4) * 4;
    const int nb = (tid & 15) * 8;
    const int nchunk = (n0 + nb) >> 4;
    const int nshift = nb & 15;          // 0 or 8

    f32x4 acc[2][2] = {};
    uchar8v aReg[2];
    unsigned short bBits[4];

    auto loadA = [&](int k0) {
        #pragma unroll
        for (int s = 0; s < 2; ++s)
            aReg[s] = *(const uchar8v*)(Ap + (long long)aPl[s] * 16384 +
                                        (long long)aM[s] * 512 + k0 + aK8[s]);
    };
    auto loadB = [&](int k0) {
        #pragma unroll
        for (int kk2 = 0; kk2 < 4; ++kk2)
            bBits[kk2] = Bb[(long long)(k0 + kb + kk2) * 128 + nchunk];
    };
    auto stage = [&]() {
        #pragma unroll
        for (int s = 0; s < 2; ++s) *(uchar8v*)&As[aPl[s]][aM[s]][aK8[s]] = aReg[s];
        unsigned char bv[4][8];
        #pragma unroll
        for (int kk2 = 0; kk2 < 4; ++kk2) {
            unsigned int bits = ((unsigned int)bBits[kk2] >> nshift) & 0xFFu;
            #pragma unroll
            for (int j = 0; j < 8; ++j)
                bv[kk2][j] = ((bits >> j) & 1u) ? ONE8 : (unsigned char)0;
        }
        #pragma unroll
        for (int j = 0; j < 8; ++j) {
            uchar4v v4 = { bv[0][j], bv[1][j], bv[2][j], bv[3][j] };
            *(uchar4v*)&Bs[nb + j][kb] = v4;
        }
    };

    const int nIter = kPerSlice >> 6;
    loadA(ks0); loadB(ks0);
    stage();
    __syncthreads();

    for (int it = 0; it < nIter; ++it) {
        const int kn = ks0 + (it + 1) * 64;
        if (it < nIter - 1) { loadA(kn); loadB(kn); }

        #pragma unroll
        for (int ks = 0; ks < 2; ++ks) {
            i64 bfr[2];
            #pragma unroll
            for (int nt = 0; nt < 2; ++nt)
                bfr[nt] = *(const i64*)&Bs[w * 32 + nt * 16 + l15][ks * 32 + kq * 8];
            #pragma unroll
            for (int s = 0; s < 2; ++s) {
                #pragma unroll
                for (int mt = 0; mt < 2; ++mt) {
                    i64 afr = *(const i64*)&As[s][mt * 16 + l15][ks * 32 + kq * 8];
                    #pragma unroll
                    for (int nt = 0; nt < 2; ++nt)
                        acc[mt][nt] = __builtin_amdgcn_mfma_f32_16x16x32_fp8_fp8(
                            afr, bfr[nt], acc[mt][nt], 0, 0, 0);
                }
            }
        }
        __syncthreads();
        if (it < nIter - 1) {
            stage();
            __syncthreads();
        }
    }

    float* Cb = C + (long long)b * 20 * 2048 + (long long)blockIdx.y * partStride;
    #pragma unroll
    for (int mt = 0; mt < 2; ++mt) {
        #pragma unroll
        for (int i = 0; i < 4; ++i) {
            int m = mt * 16 + kq * 4 + i;
            if (m >= 20) continue;
            #pragma unroll
            for (int nt = 0; nt < 2; ++nt) {
                int n = n0 + w * 32 + nt * 16 + l15;
                Cb[(long long)m * 2048 + n] = acc[mt][nt][i];
            }
        }
    }
}

// ---------------------------------------------------------------------------
// Branch-2 GEMM1 (MFMA, packed split-2), batch merged into N, SPLIT-K x4,
// register prefetch. Tile 64m x 128n, grid (40, 8, 4) (XCD-aligned pad).
// Epilogue: LDS transpose -> coalesced c-major BF16 partials.
// ---------------------------------------------------------------------------
__global__ __launch_bounds__(256) void gemmL1_mfma(
    const unsigned short* __restrict__ Wl1p,  // [2][512][2048]
    const unsigned short* __restrict__ InF,   // [4992][2048] bf16
    unsigned short* __restrict__ Zp)          // [4][156][16384] c-major bf16
{
    __shared__ alignas(16) unsigned short SMEM[18432];  // 36.9 KB
    auto As = (unsigned short (*)[64][72])SMEM;
    auto Bs = (unsigned short (*)[72])(SMEM + 9216);

    if (blockIdx.x >= 39) return;
    const int n0  = blockIdx.x * 128;
    const int m0  = blockIdx.y * 64;
    const int ks0 = blockIdx.z * 512;
    const int tid  = threadIdx.x;
    const int lane = tid & 63, w = tid >> 6;
    const int wy = w >> 1, wx = w & 1;
    const int l15 = lane & 15, kq = lane >> 4;

    int aPl[4], aM[4], aK8[4];
    #pragma unroll
    for (int s = 0; s < 4; ++s) {
        int id = tid + s * 256;
        aPl[s] = id >> 9; int rem = id & 511;
        aM[s] = rem >> 3; aK8[s] = (rem & 7) * 8;
    }
    int bN[4], bK8[4];
    #pragma unroll
    for (int s = 0; s < 4; ++s) {
        int id = tid + s * 256;
        bN[s] = id >> 3; bK8[s] = (id & 7) * 8;
    }

    f32x4 acc[2][4] = {};
    ushort8v aReg[4], bReg[4];

    #pragma unroll
    for (int s = 0; s < 4; ++s)
        aReg[s] = *(const ushort8v*)(Wl1p + (long long)aPl[s] * 1048576 +
                                     (long long)(m0 + aM[s]) * 2048 + ks0 + aK8[s]);
    #pragma unroll
    for (int s = 0; s < 4; ++s)
        bReg[s] = *(const ushort8v*)(InF + (long long)(n0 + bN[s]) * 2048 + ks0 + bK8[s]);
    #pragma unroll
    for (int s = 0; s < 4; ++s) *(ushort8v*)&As[aPl[s]][aM[s]][aK8[s]] = aReg[s];
    #pragma unroll
    for (int s = 0; s < 4; ++s) *(ushort8v*)&Bs[bN[s]][bK8[s]] = bReg[s];
    __syncthreads();

    for (int it = 0; it < 8; ++it) {
        const int kn = ks0 + (it + 1) * 64;
        if (it < 7) {
            #pragma unroll
            for (int s = 0; s < 4; ++s)
                aReg[s] = *(const ushort8v*)(Wl1p + (long long)aPl[s] * 1048576 +
                                             (long long)(m0 + aM[s]) * 2048 + kn + aK8[s]);
            #pragma unroll
            for (int s = 0; s < 4; ++s)
                bReg[s] = *(const ushort8v*)(InF + (long long)(n0 + bN[s]) * 2048 + kn + bK8[s]);
        }

        #pragma unroll
        for (int ks = 0; ks < 2; ++ks) {
            bf16x8 bfr[4];
            #pragma unroll
            for (int nt = 0; nt < 4; ++nt)
                bfr[nt] = *(const bf16x8*)&Bs[wx * 64 + nt * 16 + l15][ks * 32 + kq * 8];
            #pragma unroll
            for (int s = 0; s < 2; ++s) {
                #pragma unroll
                for (int mt = 0; mt < 2; ++mt) {
                    bf16x8 afr = *(const bf16x8*)&As[s][wy * 32 + mt * 16 + l15][ks * 32 + kq * 8];
                    #pragma unroll
                    for (int nt = 0; nt < 4; ++nt)
                        acc[mt][nt] = __builtin_amdgcn_mfma_f32_16x16x32_bf16(
                            afr, bfr[nt], acc[mt][nt], 0, 0, 0);
                }
            }
        }
        __syncthreads();
        if (it < 7) {
            #pragma unroll
            for (int s = 0; s < 4; ++s) *(ushort8v*)&As[aPl[s]][aM[s]][aK8[s]] = aReg[s];
            #pragma unroll
            for (int s = 0; s < 4; ++s) *(ushort8v*)&Bs[bN[s]][bK8[s]] = bReg[s];
            __syncthreads();
        }
    }

    float* T = (float*)SMEM;
    __syncthreads();
    #pragma unroll
    for (int mt = 0; mt < 2; ++mt) {
        #pragma unroll
        for (int i = 0; i < 4; ++i) {
            int mL = wy * 32 + mt * 16 + kq * 4 + i;
            #pragma unroll
            for (int nt = 0; nt < 4; ++nt) {
                int nL = wx * 64 + nt * 16 + l15;
                T[mL * 129 + nL] = acc[mt][nt][i];
            }
        }
    }
    __syncthreads();

    unsigned short* Zs = Zp + (long long)blockIdx.z * 2555904;
    #pragma unroll
    for (int s2 = 0; s2 < 32; ++s2) {
        int id = tid + s2 * 256;
        int cL = id >> 6;
        int mL = id & 63;
        int n = n0 + cL;
        int bb = n / 156, cc = n - bb * 156;
        Zs[(long long)cc * 16384 + bb * 512 + m0 + mL] = f2bf(T[mL * 129 + cL]);
    }
}

// ---------------------------------------------------------------------------
// Branch-2 layer-2 GEMM: C[b][m][c] = sum_h Wl2[m][h] * L1T[c][b*512+h]
// ---------------------------------------------------------------------------
__global__ __launch_bounds__(256) void gemm2B_mfma(
    const unsigned short* __restrict__ Ap,   // [2][32][512] Wl2 planes
    const unsigned short* __restrict__ L1T,  // [156][16384] bf16 spikes
    float* __restrict__ Cl2)                 // [32][20][156]
{
    __shared__ alignas(16) unsigned short As[2][32][72];
    __shared__ alignas(16) unsigned short Bs[128][72];

    const int b  = blockIdx.z;
    const int n0 = blockIdx.x * 128;
    const int tid  = threadIdx.x;
    const int lane = tid & 63, w = tid >> 6;
    const int l15 = lane & 15, kq = lane >> 4;

    f32x4 acc[2][2] = {};

    for (int k0 = 0; k0 < 512; k0 += 64) {
        #pragma unroll
        for (int s = 0; s < 2; ++s) {
            int id = tid + s * 256;
            int pl = id >> 8, rem = id & 255;
            int m = rem >> 3, k8 = (rem & 7) * 8;
            ushort8v v = *(const ushort8v*)(Ap + (long long)pl * 16384 +
                                            (long long)m * 512 + k0 + k8);
            *(ushort8v*)&As[pl][m][k8] = v;
        }
        #pragma unroll
        for (int s = 0; s < 4; ++s) {
            int id = tid + s * 256;
            int n = id >> 3, k8 = (id & 7) * 8;
            ushort8v v = {0,0,0,0,0,0,0,0};
            if (n0 + n < 156)
                v = *(const ushort8v*)(L1T + (long long)(n0 + n) * 16384 +
                                       b * 512 + k0 + k8);
            *(ushort8v*)&Bs[n][k8] = v;
        }
        __syncthreads();

        #pragma unroll
        for (int ks = 0; ks < 2; ++ks) {
            bf16x8 bfr[2];
            #pragma unroll
            for (int nt = 0; nt < 2; ++nt)
                bfr[nt] = *(const bf16x8*)&Bs[w * 32 + nt * 16 + l15][ks * 32 + kq * 8];
            #pragma unroll
            for (int s = 0; s < 2; ++s) {
                #pragma unroll
                for (int mt = 0; mt < 2; ++mt) {
                    bf16x8 afr = *(const bf16x8*)&As[s][mt * 16 + l15][ks * 32 + kq * 8];
                    #pragma unroll
                    for (int nt = 0; nt < 2; ++nt)
                        acc[mt][nt] = __builtin_amdgcn_mfma_f32_16x16x32_bf16(
                            afr, bfr[nt], acc[mt][nt], 0, 0, 0);
                }
            }
        }
        __syncthreads();
    }

    float* Cb = Cl2 + (long long)b * 20 * 156;
    #pragma unroll
    for (int mt = 0; mt < 2; ++mt) {
        #pragma unroll
        for (int i = 0; i < 4; ++i) {
            int m = mt * 16 + kq * 4 + i;
            if (m >= 20) continue;
            #pragma unroll
            for (int nt = 0; nt < 2; ++nt) {
                int n = n0 + w * 32 + nt * 16 + l15;
                if (n < 156) Cb[(long long)m * 156 + n] = acc[mt][nt][i];
            }
        }
    }
}

// ---------------------------------------------------------------------------
// Final T-scan summing two split-K partials -> fp32 spikes to d_out.
// ---------------------------------------------------------------------------
__global__ __launch_bounds__(256) void scan_spike_T2(
    const float* __restrict__ in, long long partStride,
    float* __restrict__ out, long long out_stride)
{
    const int row = blockIdx.x;
    const int tid = threadIdx.x;
    const float* x = in + (long long)row * 2048 + tid * 8;

    float v[8];
    #pragma unroll
    for (int k = 0; k < 8; ++k) v[k] = x[k] + x[k + partStride];

    float y = 0.f;
    #pragma unroll
    for (int k = 0; k < 8; ++k) { y = ALPHA * y + v[k]; v[k] = y; }

    __shared__ float sc[256];
    float val = y;
    sc[tid] = val;
    float m = ALPHA8;
    for (int d = 1; d < 256; d <<= 1) {
        __syncthreads();
        float p = (tid >= d) ? sc[tid - d] : 0.f;
        __syncthreads();
        val += m * p;
        sc[tid] = val;
        m *= m;
    }
    __syncthreads();
    float carry = (tid > 0) ? sc[tid - 1] : 0.f;

    float* o = out + (long long)row * out_stride + tid * 8;
    float ak = ALPHA;
    #pragma unroll
    for (int k = 0; k < 8; ++k) {
        float yk = v[k] + ak * carry;
        ak *= ALPHA;
        o[k] = (yk >= THETA) ? 1.0f : 0.0f;
    }
}

// ---------------------------------------------------------------------------
// Branch-2 layer-1 scan, c-major: sum 4 BF16 partials Zp[s][c][row]
// (coalesced), scan over c in perm order via LDS, spikes -> L1T[c][row].
// ---------------------------------------------------------------------------
__global__ __launch_bounds__(256) void scan_sum4_perm(
    const unsigned short* __restrict__ Zp, const int* __restrict__ perm,
    unsigned short* __restrict__ L1T)
{
    __shared__ float Xs[156][64];
    __shared__ int p[156];

    const int r0  = blockIdx.x * 64;
    const int tid = threadIdx.x;
    for (int i = tid; i < 156; i += 256) p[i] = perm[i];

    const int row = tid & 63;
    const int cq  = tid >> 6;
    #pragma unroll
    for (int it = 0; it < 39; ++it) {
        int c = it * 4 + cq;
        long long base = (long long)c * 16384 + r0 + row;
        float s = bf2f(Zp[base]) + bf2f(Zp[base + 2555904]) +
                  bf2f(Zp[base + 2 * 2555904]) + bf2f(Zp[base + 3 * 2555904]);
        Xs[c][row] = s;
    }
    __syncthreads();

    if (tid < 64) {
        float y = 0.f;
        for (int c = 0; c < 156; ++c) {
            y = ALPHA * y + Xs[p[c]][tid];
            L1T[(long long)c * 16384 + r0 + tid] = (y >= THETA) ? BF1 : 0;
        }
    }
}

__global__ __launch_bounds__(256) void scan_spike_C_out(
    const float* __restrict__ in, float* __restrict__ out, int rows)
{
    int row = blockIdx.x * blockDim.x + threadIdx.x;
    if (row >= rows) return;
    const float* x = in + (long long)row * 156;
    float* o = out + (long long)row * 2204 + 2048;
    float y = 0.f;
    for (int c = 0; c < 156; ++c) {
        y = ALPHA * y + x[c];
        o[c] = (y >= THETA) ? 1.0f : 0.0f;
    }
}

// ---------------------------------------------------------------------------
// B=32, C_IN=156, T=2048, HID=512, OUT=20. Output [32,20,2204].
// ---------------------------------------------------------------------------
extern "C" void kernel_launch(void* const* d_in, const int* in_sizes, int n_in,
                              void* d_out, int out_size, void* d_ws, size_t ws_size,
                              hipStream_t stream)
{
    const float* In  = (const float*)d_in[0];  // [32][156][2048]
    const float* W1  = (const float*)d_in[1];  // [512][156]
    const float* W2  = (const float*)d_in[2];  // [20][512]
    const float* Wl1 = (const float*)d_in[3];  // [512][2048]
    const float* Wl2 = (const float*)d_in[4];  // [20][512]
    const int*  perm = (const int*)d_in[5];    // [156]
    float* out = (float*)d_out;                // [32][20][2204]

    float* ws = (float*)d_ws;
    // Disjoint layout (float offsets), total ~87 MB (ws is 256 MiB):
    unsigned short* S1bits = (unsigned short*)ws;              // [32][512][128]
    float* C2p = ws + 1048576LL;                               // [2][32][20][2048]
    unsigned short* Inbf = (unsigned short*)(ws + 3670016LL);  // [4992][2048]
    unsigned short* Pbf  = (unsigned short*)(ws + 6225920LL);  // [4992][2048]
    unsigned short* PT   = (unsigned short*)(ws + 8781824LL);  // [32][2048][160]
    unsigned short* W1p  = (unsigned short*)(ws + 14024704LL); // [2][512][160]
    unsigned char*  W2p8 = (unsigned char*)(ws + 14106624LL);  // [2][32][512] fp8
    unsigned short* Wl1p = (unsigned short*)(ws + 14114816LL); // [2][512][2048]
    unsigned short* Wl2p = (unsigned short*)(ws + 15163392LL); // [2][32][512]
    unsigned short* Zpbf = (unsigned short*)(ws + 15179776LL); // [4][156][16384] bf16
    unsigned short* L1T  = (unsigned short*)(ws + 20291584LL); // [156][16384]
    float* Cl2 = ws + 21569536LL;                              // [32][20][156]

    dim3 blk(256);

    // ---- Preprocess ----
    prep_scan<<<dim3(4992), blk, 0, stream>>>(In, Inbf, Pbf);
    transposeP<<<dim3(32, 3, 32), blk, 0, stream>>>(Pbf, PT);
    pack_all<<<dim3(1088), blk, 0, stream>>>(W1, W2, Wl1, Wl2,
                                             W1p, W2p8, Wl1p, Wl2p);

    // ---- Branch 1: u = W1*psp(In); spike fused + bit-packed ----
    gemm1_mfma<<<dim3(16, 4, 32), blk, 0, stream>>>(W1p, PT, S1bits);
    gemm2_fp8<<<dim3(16, 2, 32), blk, 0, stream>>>(W2p8, S1bits, C2p, 256, 1310720LL);
    scan_spike_T2<<<dim3(640), blk, 0, stream>>>(C2p, 1310720LL, out, 2204);

    // ---- Branch 2 ----
    gemmL1_mfma<<<dim3(40, 8, 4), blk, 0, stream>>>(Wl1p, Inbf, Zpbf);
    scan_sum4_perm<<<dim3(256), blk, 0, stream>>>(Zpbf, perm, L1T);
    gemm2B_mfma<<<dim3(2, 1, 32), blk, 0, stream>>>(Wl2p, L1T, Cl2);
    scan_spike_C_out<<<dim3(3), blk, 0, stream>>>(Cl2, out, 640);

    (void)in_sizes; (void)n_in; (void)out_size; (void)ws_size;
}

// Round 13
// 222.141 us; speedup vs baseline: 1.3795x; 1.0180x over previous
//
#include <hip/hip_runtime.h>

// SLAYER constants
#define ALPHA  0.90483741803595952f   /* exp(-1/10) */
#define ALPHA8 0.44932896411722156f   /* exp(-0.8)  */
#define THETA  10.0f
#define BF1    ((unsigned short)0x3F80) /* 1.0f as bf16 */
#define ISCALE 0.015625f               /* 1/64, exact */

typedef short   bf16x8 __attribute__((ext_vector_type(8)));
typedef float   f32x4  __attribute__((ext_vector_type(4)));
typedef float   f32x4v __attribute__((ext_vector_type(4)));
typedef unsigned short ushort4v __attribute__((ext_vector_type(4)));
typedef unsigned short ushort8v __attribute__((ext_vector_type(8)));
typedef unsigned char  uchar4v  __attribute__((ext_vector_type(4)));
typedef unsigned char  uchar8v  __attribute__((ext_vector_type(8)));
typedef long long i64;

// RNE float -> bf16 bits
__device__ __forceinline__ unsigned short f2bf(float f) {
    unsigned int x = __float_as_uint(f);
    unsigned int r = (x + 0x7FFFu + ((x >> 16) & 1u)) >> 16;
    return (unsigned short)r;
}
__device__ __forceinline__ float bf2f(unsigned short h) {
    return __uint_as_float(((unsigned int)h) << 16);
}
// 2-way bf16 split: w ~= h0+h1 (residual ~2^-17 rel)
__device__ __forceinline__ void split2(float w, unsigned short& h0,
                                       unsigned short& h1) {
    h0 = f2bf(w);          float r0 = w - bf2f(h0);
    h1 = f2bf(r0);
}
// HW fp8 converts
__device__ __forceinline__ unsigned char f2fp8(float f) {
    int pk = __builtin_amdgcn_cvt_pk_fp8_f32(f, 0.f, 0, false);
    return (unsigned char)(pk & 0xFF);
}
__device__ __forceinline__ float fp82f(unsigned char b) {
    return __builtin_amdgcn_cvt_f32_fp8((int)b, 0);
}

// ---------------------------------------------------------------------------
// prep_scan_pack: fused input prep + weight packing.
// Blocks 0..4991: row (b*156+c) of In [4992][2048]:
//   InBits[row][t/8] bit t%8 = (x >= 0.5)   (exact: x binary)
//   Pbf [row][t] = bf16(psp_t(x))           (psp commutes with W1-dense)
// Blocks 4992..6079: weight packing:
//   W1 -> split-2 bf16; W2 -> split-2 fp8; Wl1 -> split-2 fp8 x64-scaled;
//   Wl2 -> split-2 bf16.
// ---------------------------------------------------------------------------
__global__ __launch_bounds__(256) void prep_scan_pack(
    const float* __restrict__ In, unsigned char* __restrict__ InBits,
    unsigned short* __restrict__ Pbf,
    const float* __restrict__ W1,  const float* __restrict__ W2,
    const float* __restrict__ Wl1, const float* __restrict__ Wl2,
    unsigned short* __restrict__ W1p,  unsigned char* __restrict__ W2p8,
    unsigned char* __restrict__ Wl1p8, unsigned short* __restrict__ Wl2p)
{
    const int blk = blockIdx.x;
    if (blk >= 4992) {
        const int bidx = blk - 4992;
        if (bidx >= 512 && bidx < 544) {            // W2 -> fp8 split-2
            int m = bidx - 512;
            for (int k = threadIdx.x; k < 512; k += 256) {
                float w = (m < 20) ? W2[(long long)m * 512 + k] : 0.f;
                unsigned char h0 = f2fp8(w);
                unsigned char h1 = f2fp8(w - fp82f(h0));
                W2p8[(long long)m * 512 + k] = h0;
                W2p8[16384 + (long long)m * 512 + k] = h1;
            }
        } else if (bidx >= 544 && bidx < 1056) {    // Wl1 -> fp8 split-2, x64
            int m = bidx - 544;
            for (int k = threadIdx.x; k < 2048; k += 256) {
                float w = Wl1[(long long)m * 2048 + k] * 64.0f;
                unsigned char h0 = f2fp8(w);
                unsigned char h1 = f2fp8(w - fp82f(h0));
                Wl1p8[(long long)m * 2048 + k] = h0;
                Wl1p8[1048576 + (long long)m * 2048 + k] = h1;
            }
        } else {                                    // W1 / Wl2 -> bf16 split-2
            const float* W; unsigned short* P; int M, K, Kp, Mp, m;
            if (bidx < 512) { W = W1;  P = W1p;  M = 512; K = 156; Kp = 160; Mp = 512; m = bidx; }
            else            { W = Wl2; P = Wl2p; M = 20;  K = 512; Kp = 512; Mp = 32;  m = bidx - 1056; }
            for (int k = threadIdx.x; k < Kp; k += 256) {
                float v = (m < M && k < K) ? W[(long long)m * K + k] : 0.f;
                unsigned short h0, h1;
                split2(v, h0, h1);
                P[(long long)m * Kp + k] = h0;
                P[(long long)Mp * Kp + (long long)m * Kp + k] = h1;
            }
        }
        return;
    }

    const int row = blk;
    const int tid = threadIdx.x;
    const float* x = In + (long long)row * 2048 + tid * 8;

    float v[8];
    *(f32x4v*)&v[0] = *(const f32x4v*)x;
    *(f32x4v*)&v[4] = *(const f32x4v*)(x + 4);

    // bit-pack raw binary input (exact)
    unsigned int byte = 0;
    #pragma unroll
    for (int k = 0; k < 8; ++k) byte |= (v[k] >= 0.5f) ? (1u << k) : 0u;
    InBits[(long long)row * 256 + tid] = (unsigned char)byte;

    // scan along t
    float y = 0.f;
    #pragma unroll
    for (int k = 0; k < 8; ++k) { y = ALPHA * y + v[k]; v[k] = y; }

    __shared__ float sc[256];
    float val = y;
    sc[tid] = val;
    float m = ALPHA8;
    for (int d = 1; d < 256; d <<= 1) {
        __syncthreads();
        float p = (tid >= d) ? sc[tid - d] : 0.f;
        __syncthreads();
        val += m * p;
        sc[tid] = val;
        m *= m;
    }
    __syncthreads();
    float carry = (tid > 0) ? sc[tid - 1] : 0.f;

    ushort8v pv;
    float ak = ALPHA;
    #pragma unroll
    for (int k = 0; k < 8; ++k) {
        float yk = v[k] + ak * carry;
        ak *= ALPHA;
        pv[k] = f2bf(yk);
    }
    *(ushort8v*)(Pbf + (long long)row * 2048 + tid * 8) = pv;
}

// ---------------------------------------------------------------------------
// transposeP: Pbf [32*156][2048] bf16 -> PT [32][2048][160] (c padded to 160).
// ---------------------------------------------------------------------------
__global__ __launch_bounds__(256) void transposeP(
    const unsigned short* __restrict__ Pbf, unsigned short* __restrict__ PT)
{
    __shared__ unsigned short Tile[64][72];
    const int t0 = blockIdx.x * 64;
    const int c0 = blockIdx.y * 64;
    const int b  = blockIdx.z;
    const int tid = threadIdx.x;

    #pragma unroll
    for (int s = 0; s < 2; ++s) {
        int id = tid + s * 256;
        int cc = id >> 3;
        int t8 = (id & 7) * 8;
        ushort8v v = {0,0,0,0,0,0,0,0};
        if (c0 + cc < 156)
            v = *(const ushort8v*)(Pbf + (long long)(b * 156 + c0 + cc) * 2048 + t0 + t8);
        *(ushort8v*)&Tile[cc][t8] = v;
    }
    __syncthreads();

    #pragma unroll
    for (int s = 0; s < 2; ++s) {
        int id = tid + s * 256;
        int t  = id >> 3;
        int c8 = (id & 7) * 8;
        if (c0 + c8 + 7 < 160) {
            unsigned short r[8];
            #pragma unroll
            for (int j = 0; j < 8; ++j) r[j] = Tile[c8 + j][t];
            *(ushort8v*)(PT + (long long)b * 327680 + (long long)(t0 + t) * 160 + c0 + c8)
                = *(ushort8v*)r;
        }
    }
}

// ---------------------------------------------------------------------------
// Branch-1 GEMM1 (MFMA, packed split-2, register prefetch), FUSED THRESHOLD,
// BIT-PACKED spike output (exact):
//   u[b][m][n] = sum_c W1[m][c] * psp(In)[b][c][n]
//   S1bits[b][m][n/16] bit n%16 = (u >= THETA)
// Tile 128x128, BK=32, 5 iters. grid (16 n, 4 m, 32 b).
// ---------------------------------------------------------------------------
__global__ __launch_bounds__(256) void gemm1_mfma(
    const unsigned short* __restrict__ W1p,
    const unsigned short* __restrict__ PT,
    unsigned short* __restrict__ S1bits)   // [32][512][128] ushort bit-chunks
{
    __shared__ alignas(16) unsigned short As[2][128][40];
    __shared__ alignas(16) unsigned short Bs[128][40];

    const int z  = blockIdx.z;
    const int m0 = blockIdx.y * 128;
    const int n0 = blockIdx.x * 128;
    const int tid  = threadIdx.x;
    const int lane = tid & 63, w = tid >> 6;
    const int wy = w >> 1, wx = w & 1;
    const int l15 = lane & 15, kq = lane >> 4;

    const unsigned short* Tb = PT + (long long)z * 327680;

    int aPl[4], aM[4], aK8[4];
    #pragma unroll
    for (int s = 0; s < 4; ++s) {
        int id = tid + s * 256;
        aPl[s] = id >> 9; int rem = id & 511;
        aM[s] = rem >> 2; aK8[s] = (rem & 3) * 8;
    }
    int bT[2], bC8[2];
    #pragma unroll
    for (int s = 0; s < 2; ++s) {
        int id = tid + s * 256;
        bT[s] = id >> 2; bC8[s] = (id & 3) * 8;
    }

    f32x4 acc[4][4] = {};
    ushort8v aReg[4], bReg[2];

    #pragma unroll
    for (int s = 0; s < 4; ++s)
        aReg[s] = *(const ushort8v*)(W1p + (long long)aPl[s] * 81920 +
                                     (long long)(m0 + aM[s]) * 160 + aK8[s]);
    #pragma unroll
    for (int s = 0; s < 2; ++s)
        bReg[s] = *(const ushort8v*)(Tb + (long long)(n0 + bT[s]) * 160 + bC8[s]);
    #pragma unroll
    for (int s = 0; s < 4; ++s) *(ushort8v*)&As[aPl[s]][aM[s]][aK8[s]] = aReg[s];
    #pragma unroll
    for (int s = 0; s < 2; ++s) *(ushort8v*)&Bs[bT[s]][bC8[s]] = bReg[s];
    __syncthreads();

    #pragma unroll
    for (int it = 0; it < 5; ++it) {
        const int kn = (it + 1) * 32;
        if (it < 4) {
            #pragma unroll
            for (int s = 0; s < 4; ++s)
                aReg[s] = *(const ushort8v*)(W1p + (long long)aPl[s] * 81920 +
                                             (long long)(m0 + aM[s]) * 160 + kn + aK8[s]);
            #pragma unroll
            for (int s = 0; s < 2; ++s)
                bReg[s] = *(const ushort8v*)(Tb + (long long)(n0 + bT[s]) * 160 + kn + bC8[s]);
        }

        bf16x8 bfr[4];
        #pragma unroll
        for (int nt = 0; nt < 4; ++nt)
            bfr[nt] = *(const bf16x8*)&Bs[wx * 64 + nt * 16 + l15][kq * 8];
        #pragma unroll
        for (int s = 0; s < 2; ++s) {
            #pragma unroll
            for (int mt = 0; mt < 4; ++mt) {
                bf16x8 afr = *(const bf16x8*)&As[s][wy * 64 + mt * 16 + l15][kq * 8];
                #pragma unroll
                for (int nt = 0; nt < 4; ++nt)
                    acc[mt][nt] = __builtin_amdgcn_mfma_f32_16x16x32_bf16(
                        afr, bfr[nt], acc[mt][nt], 0, 0, 0);
            }
        }
        __syncthreads();
        if (it < 4) {
            #pragma unroll
            for (int s = 0; s < 4; ++s) *(ushort8v*)&As[aPl[s]][aM[s]][aK8[s]] = aReg[s];
            #pragma unroll
            for (int s = 0; s < 2; ++s) *(ushort8v*)&Bs[bT[s]][bC8[s]] = bReg[s];
            __syncthreads();
        }
    }

    unsigned short* Db = S1bits + (long long)z * 512 * 128;
    #pragma unroll
    for (int mt = 0; mt < 4; ++mt) {
        #pragma unroll
        for (int i = 0; i < 4; ++i) {
            int m = m0 + wy * 64 + mt * 16 + kq * 4 + i;
            #pragma unroll
            for (int nt = 0; nt < 4; ++nt) {
                unsigned long long mask = __ballot(acc[mt][nt][i] >= THETA);
                if (l15 == 0) {
                    int nchunk = (n0 + wx * 64 + nt * 16) >> 4;
                    Db[(long long)m * 128 + nchunk] =
                        (unsigned short)((mask >> (kq * 16)) & 0xFFFFu);
                }
            }
        }
    }
}

// ---------------------------------------------------------------------------
// Branch-1 GEMM2 (FP8 MFMA, split-2 fp8 A, split-K, register prefetch),
// B expanded from bit-packed spikes during staging.
// Tile 32m x 128n, BK=64. grid (16, 2, 32).
// ---------------------------------------------------------------------------
__global__ __launch_bounds__(256) void gemm2_fp8(
    const unsigned char* __restrict__ Ap,     // [2][32][512] fp8 planes
    const unsigned short* __restrict__ S1bits,// [32][512][128] bit chunks
    float* __restrict__ C,
    int kPerSlice, long long partStride)
{
    __shared__ alignas(16) unsigned char As[2][32][72];
    __shared__ alignas(16) unsigned char Bs[128][72];

    const int b   = blockIdx.z;
    const int n0  = blockIdx.x * 128;
    const int ks0 = blockIdx.y * kPerSlice;
    const int tid  = threadIdx.x;
    const int lane = tid & 63, w = tid >> 6;
    const int l15 = lane & 15, kq = lane >> 4;

    const unsigned short* Bb = S1bits + (long long)b * 512 * 128;
    const unsigned char ONE8 = f2fp8(1.0f);

    int aPl[2], aM[2], aK8[2];
    #pragma unroll
    for (int s = 0; s < 2; ++s) {
        int id = tid + s * 256;
        aPl[s] = id >> 8; int rem = id & 255;
        aM[s] = rem >> 3; aK8[s] = (rem & 7) * 8;
    }
    const int kb = (tid >> 4) * 4;
    const int nb = (tid & 15) * 8;
    const int nchunk = (n0 + nb) >> 4;
    const int nshift = nb & 15;

    f32x4 acc[2][2] = {};
    uchar8v aReg[2];
    unsigned short bBits[4];

    auto loadA = [&](int k0) {
        #pragma unroll
        for (int s = 0; s < 2; ++s)
            aReg[s] = *(const uchar8v*)(Ap + (long long)aPl[s] * 16384 +
                                        (long long)aM[s] * 512 + k0 + aK8[s]);
    };
    auto loadB = [&](int k0) {
        #pragma unroll
        for (int kk2 = 0; kk2 < 4; ++kk2)
            bBits[kk2] = Bb[(long long)(k0 + kb + kk2) * 128 + nchunk];
    };
    auto stage = [&]() {
        #pragma unroll
        for (int s = 0; s < 2; ++s) *(uchar8v*)&As[aPl[s]][aM[s]][aK8[s]] = aReg[s];
        unsigned char bv[4][8];
        #pragma unroll
        for (int kk2 = 0; kk2 < 4; ++kk2) {
            unsigned int bits = ((unsigned int)bBits[kk2] >> nshift) & 0xFFu;
            #pragma unroll
            for (int j = 0; j < 8; ++j)
                bv[kk2][j] = ((bits >> j) & 1u) ? ONE8 : (unsigned char)0;
        }
        #pragma unroll
        for (int j = 0; j < 8; ++j) {
            uchar4v v4 = { bv[0][j], bv[1][j], bv[2][j], bv[3][j] };
            *(uchar4v*)&Bs[nb + j][kb] = v4;
        }
    };

    const int nIter = kPerSlice >> 6;
    loadA(ks0); loadB(ks0);
    stage();
    __syncthreads();

    for (int it = 0; it < nIter; ++it) {
        const int kn = ks0 + (it + 1) * 64;
        if (it < nIter - 1) { loadA(kn); loadB(kn); }

        #pragma unroll
        for (int ks = 0; ks < 2; ++ks) {
            i64 bfr[2];
            #pragma unroll
            for (int nt = 0; nt < 2; ++nt)
                bfr[nt] = *(const i64*)&Bs[w * 32 + nt * 16 + l15][ks * 32 + kq * 8];
            #pragma unroll
            for (int s = 0; s < 2; ++s) {
                #pragma unroll
                for (int mt = 0; mt < 2; ++mt) {
                    i64 afr = *(const i64*)&As[s][mt * 16 + l15][ks * 32 + kq * 8];
                    #pragma unroll
                    for (int nt = 0; nt < 2; ++nt)
                        acc[mt][nt] = __builtin_amdgcn_mfma_f32_16x16x32_fp8_fp8(
                            afr, bfr[nt], acc[mt][nt], 0, 0, 0);
                }
            }
        }
        __syncthreads();
        if (it < nIter - 1) {
            stage();
            __syncthreads();
        }
    }

    float* Cb = C + (long long)b * 20 * 2048 + (long long)blockIdx.y * partStride;
    #pragma unroll
    for (int mt = 0; mt < 2; ++mt) {
        #pragma unroll
        for (int i = 0; i < 4; ++i) {
            int m = mt * 16 + kq * 4 + i;
            if (m >= 20) continue;
            #pragma unroll
            for (int nt = 0; nt < 2; ++nt) {
                int n = n0 + w * 32 + nt * 16 + l15;
                Cb[(long long)m * 2048 + n] = acc[mt][nt][i];
            }
        }
    }
}

// ---------------------------------------------------------------------------
// Branch-2 GEMM1 (FP8 MFMA): A = Wl1 split-2 fp8 planes (x64-scaled),
// B = binary input expanded from bit-packed InBits (exact). SPLIT-K x4,
// register prefetch. Tile 64m x 128n, BK=64, grid (40, 8, 4) (XCD pad).
// LDS halves vs bf16 (18.4 KB) -> attacks the LDS-read bound.
// Epilogue: x(1/64), bf16 transpose in LDS -> coalesced c-major partials.
// ---------------------------------------------------------------------------
__global__ __launch_bounds__(256) void gemmL1_fp8(
    const unsigned char* __restrict__ Wl1p8,  // [2][512][2048] fp8
    const unsigned char* __restrict__ InBits, // [4992][256] bit-packed
    unsigned short* __restrict__ Zp)          // [4][156][16384] c-major bf16
{
    __shared__ alignas(16) unsigned char SMEM[18432];
    auto As8 = (unsigned char (*)[64][72])SMEM;       // [2][64][72]
    auto Bs8 = (unsigned char (*)[72])(SMEM + 9216);  // [128][72]

    if (blockIdx.x >= 39) return;
    const int n0  = blockIdx.x * 128;
    const int m0  = blockIdx.y * 64;
    const int ks0 = blockIdx.z * 512;
    const int tid  = threadIdx.x;
    const int lane = tid & 63, w = tid >> 6;
    const int wy = w >> 1, wx = w & 1;   // wy: m-half (32), wx: n-half (64)
    const int l15 = lane & 15, kq = lane >> 4;
    const unsigned char ONE8 = f2fp8(1.0f);

    // A staging: 2 planes x 64m x 64k bytes = 1024 uchar8 chunks, 4/thread
    int aPl[4], aM[4], aK8[4];
    #pragma unroll
    for (int s = 0; s < 4; ++s) {
        int id = tid + s * 256;
        aPl[s] = id >> 9; int rem = id & 511;
        aM[s] = rem >> 3; aK8[s] = (rem & 7) * 8;
    }
    // B staging: thread covers (n = tid>>1, 32 k-bits at k32 = (tid&1)*32)
    const int bn  = tid >> 1;
    const int k32 = (tid & 1) * 32;

    f32x4 acc[2][4] = {};
    uchar8v aReg[4];
    unsigned int bBits;

    auto loadA = [&](int k0) {
        #pragma unroll
        for (int s = 0; s < 4; ++s)
            aReg[s] = *(const uchar8v*)(Wl1p8 + (long long)aPl[s] * 1048576 +
                                        (long long)(m0 + aM[s]) * 2048 + k0 + aK8[s]);
    };
    auto loadB = [&](int k0) {
        bBits = *(const unsigned int*)(InBits + (long long)(n0 + bn) * 256 +
                                       ((k0 + k32) >> 3));
    };
    auto stage = [&]() {
        #pragma unroll
        for (int s = 0; s < 4; ++s) *(uchar8v*)&As8[aPl[s]][aM[s]][aK8[s]] = aReg[s];
        unsigned char bv[32];
        #pragma unroll
        for (int j = 0; j < 32; ++j)
            bv[j] = ((bBits >> j) & 1u) ? ONE8 : (unsigned char)0;
        #pragma unroll
        for (int q = 0; q < 4; ++q)
            *(uchar8v*)&Bs8[bn][k32 + q * 8] = *(uchar8v*)&bv[q * 8];
    };

    loadA(ks0); loadB(ks0);
    stage();
    __syncthreads();

    for (int it = 0; it < 8; ++it) {
        const int kn = ks0 + (it + 1) * 64;
        if (it < 7) { loadA(kn); loadB(kn); }

        #pragma unroll
        for (int ks = 0; ks < 2; ++ks) {
            i64 bfr[4];
            #pragma unroll
            for (int nt = 0; nt < 4; ++nt)
                bfr[nt] = *(const i64*)&Bs8[wx * 64 + nt * 16 + l15][ks * 32 + kq * 8];
            #pragma unroll
            for (int s = 0; s < 2; ++s) {
                #pragma unroll
                for (int mt = 0; mt < 2; ++mt) {
                    i64 afr = *(const i64*)&As8[s][wy * 32 + mt * 16 + l15][ks * 32 + kq * 8];
                    #pragma unroll
                    for (int nt = 0; nt < 4; ++nt)
                        acc[mt][nt] = __builtin_amdgcn_mfma_f32_16x16x32_fp8_fp8(
                            afr, bfr[nt], acc[mt][nt], 0, 0, 0);
                }
            }
        }
        __syncthreads();
        if (it < 7) {
            stage();
            __syncthreads();
        }
    }

    // Epilogue: scale by 1/64, transpose 64m x 128n through LDS as bf16
    // (64 x 129 ushorts = 16.5 KB <= 18.4 KB), then c-major stores.
    unsigned short* Tu = (unsigned short*)SMEM;
    #pragma unroll
    for (int mt = 0; mt < 2; ++mt) {
        #pragma unroll
        for (int i = 0; i < 4; ++i) {
            int mL = wy * 32 + mt * 16 + kq * 4 + i;
            #pragma unroll
            for (int nt = 0; nt < 4; ++nt) {
                int nL = wx * 64 + nt * 16 + l15;
                Tu[mL * 129 + nL] = f2bf(acc[mt][nt][i] * ISCALE);
            }
        }
    }
    __syncthreads();

    unsigned short* Zs = Zp + (long long)blockIdx.z * 2555904;
    #pragma unroll
    for (int s2 = 0; s2 < 32; ++s2) {
        int id = tid + s2 * 256;
        int cL = id >> 6;
        int mL = id & 63;
        int n = n0 + cL;
        int bb = n / 156, cc = n - bb * 156;
        Zs[(long long)cc * 16384 + bb * 512 + m0 + mL] = Tu[mL * 129 + cL];
    }
}

// ---------------------------------------------------------------------------
// Branch-2 layer-2 GEMM: C[b][m][c] = sum_h Wl2[m][h] * L1T[c][b*512+h]
// ---------------------------------------------------------------------------
__global__ __launch_bounds__(256) void gemm2B_mfma(
    const unsigned short* __restrict__ Ap,   // [2][32][512] Wl2 planes
    const unsigned short* __restrict__ L1T,  // [156][16384] bf16 spikes
    float* __restrict__ Cl2)                 // [32][20][156]
{
    __shared__ alignas(16) unsigned short As[2][32][72];
    __shared__ alignas(16) unsigned short Bs[128][72];

    const int b  = blockIdx.z;
    const int n0 = blockIdx.x * 128;
    const int tid  = threadIdx.x;
    const int lane = tid & 63, w = tid >> 6;
    const int l15 = lane & 15, kq = lane >> 4;

    f32x4 acc[2][2] = {};

    for (int k0 = 0; k0 < 512; k0 += 64) {
        #pragma unroll
        for (int s = 0; s < 2; ++s) {
            int id = tid + s * 256;
            int pl = id >> 8, rem = id & 255;
            int m = rem >> 3, k8 = (rem & 7) * 8;
            ushort8v v = *(const ushort8v*)(Ap + (long long)pl * 16384 +
                                            (long long)m * 512 + k0 + k8);
            *(ushort8v*)&As[pl][m][k8] = v;
        }
        #pragma unroll
        for (int s = 0; s < 4; ++s) {
            int id = tid + s * 256;
            int n = id >> 3, k8 = (id & 7) * 8;
            ushort8v v = {0,0,0,0,0,0,0,0};
            if (n0 + n < 156)
                v = *(const ushort8v*)(L1T + (long long)(n0 + n) * 16384 +
                                       b * 512 + k0 + k8);
            *(ushort8v*)&Bs[n][k8] = v;
        }
        __syncthreads();

        #pragma unroll
        for (int ks = 0; ks < 2; ++ks) {
            bf16x8 bfr[2];
            #pragma unroll
            for (int nt = 0; nt < 2; ++nt)
                bfr[nt] = *(const bf16x8*)&Bs[w * 32 + nt * 16 + l15][ks * 32 + kq * 8];
            #pragma unroll
            for (int s = 0; s < 2; ++s) {
                #pragma unroll
                for (int mt = 0; mt < 2; ++mt) {
                    bf16x8 afr = *(const bf16x8*)&As[s][mt * 16 + l15][ks * 32 + kq * 8];
                    #pragma unroll
                    for (int nt = 0; nt < 2; ++nt)
                        acc[mt][nt] = __builtin_amdgcn_mfma_f32_16x16x32_bf16(
                            afr, bfr[nt], acc[mt][nt], 0, 0, 0);
                }
            }
        }
        __syncthreads();
    }

    float* Cb = Cl2 + (long long)b * 20 * 156;
    #pragma unroll
    for (int mt = 0; mt < 2; ++mt) {
        #pragma unroll
        for (int i = 0; i < 4; ++i) {
            int m = mt * 16 + kq * 4 + i;
            if (m >= 20) continue;
            #pragma unroll
            for (int nt = 0; nt < 2; ++nt) {
                int n = n0 + w * 32 + nt * 16 + l15;
                if (n < 156) Cb[(long long)m * 156 + n] = acc[mt][nt][i];
            }
        }
    }
}

// ---------------------------------------------------------------------------
// Final T-scan summing two split-K partials -> fp32 spikes to d_out.
// ---------------------------------------------------------------------------
__global__ __launch_bounds__(256) void scan_spike_T2(
    const float* __restrict__ in, long long partStride,
    float* __restrict__ out, long long out_stride)
{
    const int row = blockIdx.x;
    const int tid = threadIdx.x;
    const float* x = in + (long long)row * 2048 + tid * 8;

    float v[8];
    #pragma unroll
    for (int k = 0; k < 8; ++k) v[k] = x[k] + x[k + partStride];

    float y = 0.f;
    #pragma unroll
    for (int k = 0; k < 8; ++k) { y = ALPHA * y + v[k]; v[k] = y; }

    __shared__ float sc[256];
    float val = y;
    sc[tid] = val;
    float m = ALPHA8;
    for (int d = 1; d < 256; d <<= 1) {
        __syncthreads();
        float p = (tid >= d) ? sc[tid - d] : 0.f;
        __syncthreads();
        val += m * p;
        sc[tid] = val;
        m *= m;
    }
    __syncthreads();
    float carry = (tid > 0) ? sc[tid - 1] : 0.f;

    float* o = out + (long long)row * out_stride + tid * 8;
    float ak = ALPHA;
    #pragma unroll
    for (int k = 0; k < 8; ++k) {
        float yk = v[k] + ak * carry;
        ak *= ALPHA;
        o[k] = (yk >= THETA) ? 1.0f : 0.0f;
    }
}

// ---------------------------------------------------------------------------
// Branch-2 layer-1 scan, c-major: sum 4 BF16 partials Zp[s][c][row]
// (coalesced), scan over c in perm order via LDS, spikes -> L1T[c][row].
// ---------------------------------------------------------------------------
__global__ __launch_bounds__(256) void scan_sum4_perm(
    const unsigned short* __restrict__ Zp, const int* __restrict__ perm,
    unsigned short* __restrict__ L1T)
{
    __shared__ float Xs[156][64];
    __shared__ int p[156];

    const int r0  = blockIdx.x * 64;
    const int tid = threadIdx.x;
    for (int i = tid; i < 156; i += 256) p[i] = perm[i];

    const int row = tid & 63;
    const int cq  = tid >> 6;
    #pragma unroll
    for (int it = 0; it < 39; ++it) {
        int c = it * 4 + cq;
        long long base = (long long)c * 16384 + r0 + row;
        float s = bf2f(Zp[base]) + bf2f(Zp[base + 2555904]) +
                  bf2f(Zp[base + 2 * 2555904]) + bf2f(Zp[base + 3 * 2555904]);
        Xs[c][row] = s;
    }
    __syncthreads();

    if (tid < 64) {
        float y = 0.f;
        for (int c = 0; c < 156; ++c) {
            y = ALPHA * y + Xs[p[c]][tid];
            L1T[(long long)c * 16384 + r0 + tid] = (y >= THETA) ? BF1 : 0;
        }
    }
}

__global__ __launch_bounds__(256) void scan_spike_C_out(
    const float* __restrict__ in, float* __restrict__ out, int rows)
{
    int row = blockIdx.x * blockDim.x + threadIdx.x;
    if (row >= rows) return;
    const float* x = in + (long long)row * 156;
    float* o = out + (long long)row * 2204 + 2048;
    float y = 0.f;
    for (int c = 0; c < 156; ++c) {
        y = ALPHA * y + x[c];
        o[c] = (y >= THETA) ? 1.0f : 0.0f;
    }
}

// ---------------------------------------------------------------------------
// B=32, C_IN=156, T=2048, HID=512, OUT=20. Output [32,20,2204].
// ---------------------------------------------------------------------------
extern "C" void kernel_launch(void* const* d_in, const int* in_sizes, int n_in,
                              void* d_out, int out_size, void* d_ws, size_t ws_size,
                              hipStream_t stream)
{
    const float* In  = (const float*)d_in[0];  // [32][156][2048]
    const float* W1  = (const float*)d_in[1];  // [512][156]
    const float* W2  = (const float*)d_in[2];  // [20][512]
    const float* Wl1 = (const float*)d_in[3];  // [512][2048]
    const float* Wl2 = (const float*)d_in[4];  // [20][512]
    const int*  perm = (const int*)d_in[5];    // [156]
    float* out = (float*)d_out;                // [32][20][2204]

    float* ws = (float*)d_ws;
    // Disjoint layout (float offsets), total ~86 MB (ws is 256 MiB):
    unsigned short* S1bits = (unsigned short*)ws;              // [32][512][128]
    float* C2p = ws + 1048576LL;                               // [2][32][20][2048]
    unsigned char*  InBits = (unsigned char*)(ws + 3670016LL); // [4992][256]
    unsigned short* Pbf  = (unsigned short*)(ws + 3989504LL);  // [4992][2048]
    unsigned short* PT   = (unsigned short*)(ws + 9101312LL);  // [32][2048][160]
    unsigned short* W1p  = (unsigned short*)(ws + 14344192LL); // [2][512][160]
    unsigned char*  W2p8 = (unsigned char*)(ws + 14426112LL);  // [2][32][512] fp8
    unsigned char*  Wl1p8= (unsigned char*)(ws + 14434304LL);  // [2][512][2048] fp8
    unsigned short* Wl2p = (unsigned short*)(ws + 14958592LL); // [2][32][512]
    unsigned short* Zpbf = (unsigned short*)(ws + 14974976LL); // [4][156][16384] bf16
    unsigned short* L1T  = (unsigned short*)(ws + 20086784LL); // [156][16384]
    float* Cl2 = ws + 21364736LL;                              // [32][20][156]

    dim3 blk(256);

    // ---- Preprocess (fused scan + pack) ----
    prep_scan_pack<<<dim3(6080), blk, 0, stream>>>(
        In, InBits, Pbf, W1, W2, Wl1, Wl2, W1p, W2p8, Wl1p8, Wl2p);
    transposeP<<<dim3(32, 3, 32), blk, 0, stream>>>(Pbf, PT);

    // ---- Branch 1: u = W1*psp(In); spike fused + bit-packed ----
    gemm1_mfma<<<dim3(16, 4, 32), blk, 0, stream>>>(W1p, PT, S1bits);
    gemm2_fp8<<<dim3(16, 2, 32), blk, 0, stream>>>(W2p8, S1bits, C2p, 256, 1310720LL);
    scan_spike_T2<<<dim3(640), blk, 0, stream>>>(C2p, 1310720LL, out, 2204);

    // ---- Branch 2 (fp8 GEMM over bit-packed binary input) ----
    gemmL1_fp8<<<dim3(40, 8, 4), blk, 0, stream>>>(Wl1p8, InBits, Zpbf);
    scan_sum4_perm<<<dim3(256), blk, 0, stream>>>(Zpbf, perm, L1T);
    gemm2B_mfma<<<dim3(2, 1, 32), blk, 0, stream>>>(Wl2p, L1T, Cl2);
    scan_spike_C_out<<<dim3(3), blk, 0, stream>>>(Cl2, out, 640);

    (void)in_sizes; (void)n_in; (void)out_size; (void)ws_size;
}

// Round 14
// 216.047 us; speedup vs baseline: 1.4184x; 1.0282x over previous
//
#include <hip/hip_runtime.h>

// SLAYER constants
#define ALPHA  0.90483741803595952f   /* exp(-1/10) */
#define ALPHA8 0.44932896411722156f   /* exp(-0.8)  */
#define THETA  10.0f
#define BF1    ((unsigned short)0x3F80) /* 1.0f as bf16 */
#define ISCALE 0.015625f               /* 1/64, exact */

typedef short   bf16x8 __attribute__((ext_vector_type(8)));
typedef float   f32x4  __attribute__((ext_vector_type(4)));
typedef float   f32x4v __attribute__((ext_vector_type(4)));
typedef unsigned short ushort4v __attribute__((ext_vector_type(4)));
typedef unsigned short ushort8v __attribute__((ext_vector_type(8)));
typedef unsigned char  uchar4v  __attribute__((ext_vector_type(4)));
typedef unsigned char  uchar8v  __attribute__((ext_vector_type(8)));
typedef long long i64;

// RNE float -> bf16 bits
__device__ __forceinline__ unsigned short f2bf(float f) {
    unsigned int x = __float_as_uint(f);
    unsigned int r = (x + 0x7FFFu + ((x >> 16) & 1u)) >> 16;
    return (unsigned short)r;
}
__device__ __forceinline__ float bf2f(unsigned short h) {
    return __uint_as_float(((unsigned int)h) << 16);
}
// 2-way bf16 split: w ~= h0+h1 (residual ~2^-17 rel)
__device__ __forceinline__ void split2(float w, unsigned short& h0,
                                       unsigned short& h1) {
    h0 = f2bf(w);          float r0 = w - bf2f(h0);
    h1 = f2bf(r0);
}
// HW fp8 converts
__device__ __forceinline__ unsigned char f2fp8(float f) {
    int pk = __builtin_amdgcn_cvt_pk_fp8_f32(f, 0.f, 0, false);
    return (unsigned char)(pk & 0xFF);
}
__device__ __forceinline__ float fp82f(unsigned char b) {
    return __builtin_amdgcn_cvt_f32_fp8((int)b, 0);
}

// ---------------------------------------------------------------------------
// prep_scan_pack: fused input prep + weight packing.
// Blocks 0..4991: row (b*156+c) of In [4992][2048]:
//   Infp8[row][t] = fp8(x)   (exact: x binary {0,1})
//   Pbf [row][t]  = bf16(psp_t(x))   (psp commutes with W1-dense)
// Blocks 4992..6079: weight packing:
//   W1 -> split-2 bf16; W2 -> split-2 fp8; Wl1 -> split-2 fp8 x64-scaled;
//   Wl2 -> split-2 bf16.
// ---------------------------------------------------------------------------
__global__ __launch_bounds__(256) void prep_scan_pack(
    const float* __restrict__ In, unsigned char* __restrict__ Infp8,
    unsigned short* __restrict__ Pbf,
    const float* __restrict__ W1,  const float* __restrict__ W2,
    const float* __restrict__ Wl1, const float* __restrict__ Wl2,
    unsigned short* __restrict__ W1p,  unsigned char* __restrict__ W2p8,
    unsigned char* __restrict__ Wl1p8, unsigned short* __restrict__ Wl2p)
{
    const int blk = blockIdx.x;
    if (blk >= 4992) {
        const int bidx = blk - 4992;
        if (bidx >= 512 && bidx < 544) {            // W2 -> fp8 split-2
            int m = bidx - 512;
            for (int k = threadIdx.x; k < 512; k += 256) {
                float w = (m < 20) ? W2[(long long)m * 512 + k] : 0.f;
                unsigned char h0 = f2fp8(w);
                unsigned char h1 = f2fp8(w - fp82f(h0));
                W2p8[(long long)m * 512 + k] = h0;
                W2p8[16384 + (long long)m * 512 + k] = h1;
            }
        } else if (bidx >= 544 && bidx < 1056) {    // Wl1 -> fp8 split-2, x64
            int m = bidx - 544;
            for (int k = threadIdx.x; k < 2048; k += 256) {
                float w = Wl1[(long long)m * 2048 + k] * 64.0f;
                unsigned char h0 = f2fp8(w);
                unsigned char h1 = f2fp8(w - fp82f(h0));
                Wl1p8[(long long)m * 2048 + k] = h0;
                Wl1p8[1048576 + (long long)m * 2048 + k] = h1;
            }
        } else {                                    // W1 / Wl2 -> bf16 split-2
            const float* W; unsigned short* P; int M, K, Kp, Mp, m;
            if (bidx < 512) { W = W1;  P = W1p;  M = 512; K = 156; Kp = 160; Mp = 512; m = bidx; }
            else            { W = Wl2; P = Wl2p; M = 20;  K = 512; Kp = 512; Mp = 32;  m = bidx - 1056; }
            for (int k = threadIdx.x; k < Kp; k += 256) {
                float v = (m < M && k < K) ? W[(long long)m * K + k] : 0.f;
                unsigned short h0, h1;
                split2(v, h0, h1);
                P[(long long)m * Kp + k] = h0;
                P[(long long)Mp * Kp + (long long)m * Kp + k] = h1;
            }
        }
        return;
    }

    const int row = blk;
    const int tid = threadIdx.x;
    const float* x = In + (long long)row * 2048 + tid * 8;
    const unsigned char ONE8 = f2fp8(1.0f);

    float v[8];
    *(f32x4v*)&v[0] = *(const f32x4v*)x;
    *(f32x4v*)&v[4] = *(const f32x4v*)(x + 4);

    // raw binary input as fp8 (exact)
    uchar8v raw;
    #pragma unroll
    for (int k = 0; k < 8; ++k) raw[k] = (v[k] >= 0.5f) ? ONE8 : (unsigned char)0;
    *(uchar8v*)(Infp8 + (long long)row * 2048 + tid * 8) = raw;

    // scan along t
    float y = 0.f;
    #pragma unroll
    for (int k = 0; k < 8; ++k) { y = ALPHA * y + v[k]; v[k] = y; }

    __shared__ float sc[256];
    float val = y;
    sc[tid] = val;
    float m = ALPHA8;
    for (int d = 1; d < 256; d <<= 1) {
        __syncthreads();
        float p = (tid >= d) ? sc[tid - d] : 0.f;
        __syncthreads();
        val += m * p;
        sc[tid] = val;
        m *= m;
    }
    __syncthreads();
    float carry = (tid > 0) ? sc[tid - 1] : 0.f;

    ushort8v pv;
    float ak = ALPHA;
    #pragma unroll
    for (int k = 0; k < 8; ++k) {
        float yk = v[k] + ak * carry;
        ak *= ALPHA;
        pv[k] = f2bf(yk);
    }
    *(ushort8v*)(Pbf + (long long)row * 2048 + tid * 8) = pv;
}

// ---------------------------------------------------------------------------
// transposeP: Pbf [32*156][2048] bf16 -> PT [32][2048][160] (c padded to 160).
// ---------------------------------------------------------------------------
__global__ __launch_bounds__(256) void transposeP(
    const unsigned short* __restrict__ Pbf, unsigned short* __restrict__ PT)
{
    __shared__ unsigned short Tile[64][72];
    const int t0 = blockIdx.x * 64;
    const int c0 = blockIdx.y * 64;
    const int b  = blockIdx.z;
    const int tid = threadIdx.x;

    #pragma unroll
    for (int s = 0; s < 2; ++s) {
        int id = tid + s * 256;
        int cc = id >> 3;
        int t8 = (id & 7) * 8;
        ushort8v v = {0,0,0,0,0,0,0,0};
        if (c0 + cc < 156)
            v = *(const ushort8v*)(Pbf + (long long)(b * 156 + c0 + cc) * 2048 + t0 + t8);
        *(ushort8v*)&Tile[cc][t8] = v;
    }
    __syncthreads();

    #pragma unroll
    for (int s = 0; s < 2; ++s) {
        int id = tid + s * 256;
        int t  = id >> 3;
        int c8 = (id & 7) * 8;
        if (c0 + c8 + 7 < 160) {
            unsigned short r[8];
            #pragma unroll
            for (int j = 0; j < 8; ++j) r[j] = Tile[c8 + j][t];
            *(ushort8v*)(PT + (long long)b * 327680 + (long long)(t0 + t) * 160 + c0 + c8)
                = *(ushort8v*)r;
        }
    }
}

// ---------------------------------------------------------------------------
// Branch-1 GEMM1 (MFMA, packed split-2, register prefetch), FUSED THRESHOLD,
// BIT-PACKED spike output (exact):
//   u[b][m][n] = sum_c W1[m][c] * psp(In)[b][c][n]
//   S1bits[b][m][n/16] bit n%16 = (u >= THETA)
// Tile 128x128, BK=32, 5 iters. grid (16 n, 4 m, 32 b).
// ---------------------------------------------------------------------------
__global__ __launch_bounds__(256) void gemm1_mfma(
    const unsigned short* __restrict__ W1p,
    const unsigned short* __restrict__ PT,
    unsigned short* __restrict__ S1bits)   // [32][512][128] ushort bit-chunks
{
    __shared__ alignas(16) unsigned short As[2][128][40];
    __shared__ alignas(16) unsigned short Bs[128][40];

    const int z  = blockIdx.z;
    const int m0 = blockIdx.y * 128;
    const int n0 = blockIdx.x * 128;
    const int tid  = threadIdx.x;
    const int lane = tid & 63, w = tid >> 6;
    const int wy = w >> 1, wx = w & 1;
    const int l15 = lane & 15, kq = lane >> 4;

    const unsigned short* Tb = PT + (long long)z * 327680;

    int aPl[4], aM[4], aK8[4];
    #pragma unroll
    for (int s = 0; s < 4; ++s) {
        int id = tid + s * 256;
        aPl[s] = id >> 9; int rem = id & 511;
        aM[s] = rem >> 2; aK8[s] = (rem & 3) * 8;
    }
    int bT[2], bC8[2];
    #pragma unroll
    for (int s = 0; s < 2; ++s) {
        int id = tid + s * 256;
        bT[s] = id >> 2; bC8[s] = (id & 3) * 8;
    }

    f32x4 acc[4][4] = {};
    ushort8v aReg[4], bReg[2];

    #pragma unroll
    for (int s = 0; s < 4; ++s)
        aReg[s] = *(const ushort8v*)(W1p + (long long)aPl[s] * 81920 +
                                     (long long)(m0 + aM[s]) * 160 + aK8[s]);
    #pragma unroll
    for (int s = 0; s < 2; ++s)
        bReg[s] = *(const ushort8v*)(Tb + (long long)(n0 + bT[s]) * 160 + bC8[s]);
    #pragma unroll
    for (int s = 0; s < 4; ++s) *(ushort8v*)&As[aPl[s]][aM[s]][aK8[s]] = aReg[s];
    #pragma unroll
    for (int s = 0; s < 2; ++s) *(ushort8v*)&Bs[bT[s]][bC8[s]] = bReg[s];
    __syncthreads();

    #pragma unroll
    for (int it = 0; it < 5; ++it) {
        const int kn = (it + 1) * 32;
        if (it < 4) {
            #pragma unroll
            for (int s = 0; s < 4; ++s)
                aReg[s] = *(const ushort8v*)(W1p + (long long)aPl[s] * 81920 +
                                             (long long)(m0 + aM[s]) * 160 + kn + aK8[s]);
            #pragma unroll
            for (int s = 0; s < 2; ++s)
                bReg[s] = *(const ushort8v*)(Tb + (long long)(n0 + bT[s]) * 160 + kn + bC8[s]);
        }

        bf16x8 bfr[4];
        #pragma unroll
        for (int nt = 0; nt < 4; ++nt)
            bfr[nt] = *(const bf16x8*)&Bs[wx * 64 + nt * 16 + l15][kq * 8];
        #pragma unroll
        for (int s = 0; s < 2; ++s) {
            #pragma unroll
            for (int mt = 0; mt < 4; ++mt) {
                bf16x8 afr = *(const bf16x8*)&As[s][wy * 64 + mt * 16 + l15][kq * 8];
                #pragma unroll
                for (int nt = 0; nt < 4; ++nt)
                    acc[mt][nt] = __builtin_amdgcn_mfma_f32_16x16x32_bf16(
                        afr, bfr[nt], acc[mt][nt], 0, 0, 0);
            }
        }
        __syncthreads();
        if (it < 4) {
            #pragma unroll
            for (int s = 0; s < 4; ++s) *(ushort8v*)&As[aPl[s]][aM[s]][aK8[s]] = aReg[s];
            #pragma unroll
            for (int s = 0; s < 2; ++s) *(ushort8v*)&Bs[bT[s]][bC8[s]] = bReg[s];
            __syncthreads();
        }
    }

    unsigned short* Db = S1bits + (long long)z * 512 * 128;
    #pragma unroll
    for (int mt = 0; mt < 4; ++mt) {
        #pragma unroll
        for (int i = 0; i < 4; ++i) {
            int m = m0 + wy * 64 + mt * 16 + kq * 4 + i;
            #pragma unroll
            for (int nt = 0; nt < 4; ++nt) {
                unsigned long long mask = __ballot(acc[mt][nt][i] >= THETA);
                if (l15 == 0) {
                    int nchunk = (n0 + wx * 64 + nt * 16) >> 4;
                    Db[(long long)m * 128 + nchunk] =
                        (unsigned short)((mask >> (kq * 16)) & 0xFFFFu);
                }
            }
        }
    }
}

// ---------------------------------------------------------------------------
// Branch-1 GEMM2 (FP8 MFMA, split-2 fp8 A, split-K, register prefetch),
// B expanded from bit-packed spikes during staging (only 4 iters).
// Tile 32m x 128n, BK=64. grid (16, 2, 32).
// ---------------------------------------------------------------------------
__global__ __launch_bounds__(256) void gemm2_fp8(
    const unsigned char* __restrict__ Ap,     // [2][32][512] fp8 planes
    const unsigned short* __restrict__ S1bits,// [32][512][128] bit chunks
    float* __restrict__ C,
    int kPerSlice, long long partStride)
{
    __shared__ alignas(16) unsigned char As[2][32][72];
    __shared__ alignas(16) unsigned char Bs[128][72];

    const int b   = blockIdx.z;
    const int n0  = blockIdx.x * 128;
    const int ks0 = blockIdx.y * kPerSlice;
    const int tid  = threadIdx.x;
    const int lane = tid & 63, w = tid >> 6;
    const int l15 = lane & 15, kq = lane >> 4;

    const unsigned short* Bb = S1bits + (long long)b * 512 * 128;
    const unsigned char ONE8 = f2fp8(1.0f);

    int aPl[2], aM[2], aK8[2];
    #pragma unroll
    for (int s = 0; s < 2; ++s) {
        int id = tid + s * 256;
        aPl[s] = id >> 8; int rem = id & 255;
        aM[s] = rem >> 3; aK8[s] = (rem & 7) * 8;
    }
    const int kb = (tid >> 4) * 4;
    const int nb = (tid & 15) * 8;
    const int nchunk = (n0 + nb) >> 4;
    const int nshift = nb & 15;

    f32x4 acc[2][2] = {};
    uchar8v aReg[2];
    unsigned short bBits[4];

    auto loadA = [&](int k0) {
        #pragma unroll
        for (int s = 0; s < 2; ++s)
            aReg[s] = *(const uchar8v*)(Ap + (long long)aPl[s] * 16384 +
                                        (long long)aM[s] * 512 + k0 + aK8[s]);
    };
    auto loadB = [&](int k0) {
        #pragma unroll
        for (int kk2 = 0; kk2 < 4; ++kk2)
            bBits[kk2] = Bb[(long long)(k0 + kb + kk2) * 128 + nchunk];
    };
    auto stage = [&]() {
        #pragma unroll
        for (int s = 0; s < 2; ++s) *(uchar8v*)&As[aPl[s]][aM[s]][aK8[s]] = aReg[s];
        unsigned char bv[4][8];
        #pragma unroll
        for (int kk2 = 0; kk2 < 4; ++kk2) {
            unsigned int bits = ((unsigned int)bBits[kk2] >> nshift) & 0xFFu;
            #pragma unroll
            for (int j = 0; j < 8; ++j)
                bv[kk2][j] = ((bits >> j) & 1u) ? ONE8 : (unsigned char)0;
        }
        #pragma unroll
        for (int j = 0; j < 8; ++j) {
            uchar4v v4 = { bv[0][j], bv[1][j], bv[2][j], bv[3][j] };
            *(uchar4v*)&Bs[nb + j][kb] = v4;
        }
    };

    const int nIter = kPerSlice >> 6;
    loadA(ks0); loadB(ks0);
    stage();
    __syncthreads();

    for (int it = 0; it < nIter; ++it) {
        const int kn = ks0 + (it + 1) * 64;
        if (it < nIter - 1) { loadA(kn); loadB(kn); }

        #pragma unroll
        for (int ks = 0; ks < 2; ++ks) {
            i64 bfr[2];
            #pragma unroll
            for (int nt = 0; nt < 2; ++nt)
                bfr[nt] = *(const i64*)&Bs[w * 32 + nt * 16 + l15][ks * 32 + kq * 8];
            #pragma unroll
            for (int s = 0; s < 2; ++s) {
                #pragma unroll
                for (int mt = 0; mt < 2; ++mt) {
                    i64 afr = *(const i64*)&As[s][mt * 16 + l15][ks * 32 + kq * 8];
                    #pragma unroll
                    for (int nt = 0; nt < 2; ++nt)
                        acc[mt][nt] = __builtin_amdgcn_mfma_f32_16x16x32_fp8_fp8(
                            afr, bfr[nt], acc[mt][nt], 0, 0, 0);
                }
            }
        }
        __syncthreads();
        if (it < nIter - 1) {
            stage();
            __syncthreads();
        }
    }

    float* Cb = C + (long long)b * 20 * 2048 + (long long)blockIdx.y * partStride;
    #pragma unroll
    for (int mt = 0; mt < 2; ++mt) {
        #pragma unroll
        for (int i = 0; i < 4; ++i) {
            int m = mt * 16 + kq * 4 + i;
            if (m >= 20) continue;
            #pragma unroll
            for (int nt = 0; nt < 2; ++nt) {
                int n = n0 + w * 32 + nt * 16 + l15;
                Cb[(long long)m * 2048 + n] = acc[mt][nt][i];
            }
        }
    }
}

// ---------------------------------------------------------------------------
// Branch-2 GEMM1 (FP8 MFMA): A = Wl1 split-2 fp8 planes (x64-scaled),
// B = binary input as fp8 (exact) — staging is pure uchar8 copies, no
// expansion VALU. SPLIT-K x4, register prefetch. Tile 64m x 128n, BK=64,
// grid (40, 8, 4) (XCD pad). LDS 18.4 KB.
// Epilogue: x(1/64), bf16 transpose in LDS -> coalesced c-major partials.
// ---------------------------------------------------------------------------
__global__ __launch_bounds__(256) void gemmL1_fp8(
    const unsigned char* __restrict__ Wl1p8,  // [2][512][2048] fp8
    const unsigned char* __restrict__ Infp8,  // [4992][2048] fp8
    unsigned short* __restrict__ Zp)          // [4][156][16384] c-major bf16
{
    __shared__ alignas(16) unsigned char SMEM[18432];
    auto As8 = (unsigned char (*)[64][72])SMEM;       // [2][64][72]
    auto Bs8 = (unsigned char (*)[72])(SMEM + 9216);  // [128][72]

    if (blockIdx.x >= 39) return;
    const int n0  = blockIdx.x * 128;
    const int m0  = blockIdx.y * 64;
    const int ks0 = blockIdx.z * 512;
    const int tid  = threadIdx.x;
    const int lane = tid & 63, w = tid >> 6;
    const int wy = w >> 1, wx = w & 1;
    const int l15 = lane & 15, kq = lane >> 4;

    // A staging: 2 planes x 64m x 64k bytes = 1024 uchar8 chunks, 4/thread
    int aPl[4], aM[4], aK8[4];
    #pragma unroll
    for (int s = 0; s < 4; ++s) {
        int id = tid + s * 256;
        aPl[s] = id >> 9; int rem = id & 511;
        aM[s] = rem >> 3; aK8[s] = (rem & 7) * 8;
    }
    // B staging: 128n x 64k bytes = 1024 uchar8 chunks, 4/thread
    int bN[4], bK8[4];
    #pragma unroll
    for (int s = 0; s < 4; ++s) {
        int id = tid + s * 256;
        bN[s] = id >> 3; bK8[s] = (id & 7) * 8;
    }

    f32x4 acc[2][4] = {};
    uchar8v aReg[4], bReg[4];

    auto loadA = [&](int k0) {
        #pragma unroll
        for (int s = 0; s < 4; ++s)
            aReg[s] = *(const uchar8v*)(Wl1p8 + (long long)aPl[s] * 1048576 +
                                        (long long)(m0 + aM[s]) * 2048 + k0 + aK8[s]);
    };
    auto loadB = [&](int k0) {
        #pragma unroll
        for (int s = 0; s < 4; ++s)
            bReg[s] = *(const uchar8v*)(Infp8 + (long long)(n0 + bN[s]) * 2048 + k0 + bK8[s]);
    };
    auto stage = [&]() {
        #pragma unroll
        for (int s = 0; s < 4; ++s) *(uchar8v*)&As8[aPl[s]][aM[s]][aK8[s]] = aReg[s];
        #pragma unroll
        for (int s = 0; s < 4; ++s) *(uchar8v*)&Bs8[bN[s]][bK8[s]] = bReg[s];
    };

    loadA(ks0); loadB(ks0);
    stage();
    __syncthreads();

    for (int it = 0; it < 8; ++it) {
        const int kn = ks0 + (it + 1) * 64;
        if (it < 7) { loadA(kn); loadB(kn); }

        #pragma unroll
        for (int ks = 0; ks < 2; ++ks) {
            i64 bfr[4];
            #pragma unroll
            for (int nt = 0; nt < 4; ++nt)
                bfr[nt] = *(const i64*)&Bs8[wx * 64 + nt * 16 + l15][ks * 32 + kq * 8];
            #pragma unroll
            for (int s = 0; s < 2; ++s) {
                #pragma unroll
                for (int mt = 0; mt < 2; ++mt) {
                    i64 afr = *(const i64*)&As8[s][wy * 32 + mt * 16 + l15][ks * 32 + kq * 8];
                    #pragma unroll
                    for (int nt = 0; nt < 4; ++nt)
                        acc[mt][nt] = __builtin_amdgcn_mfma_f32_16x16x32_fp8_fp8(
                            afr, bfr[nt], acc[mt][nt], 0, 0, 0);
                }
            }
        }
        __syncthreads();
        if (it < 7) {
            stage();
            __syncthreads();
        }
    }

    // Epilogue: scale by 1/64, transpose 64m x 128n through LDS as bf16
    // (64 x 129 ushorts = 16.5 KB <= 18.4 KB), then c-major stores.
    unsigned short* Tu = (unsigned short*)SMEM;
    #pragma unroll
    for (int mt = 0; mt < 2; ++mt) {
        #pragma unroll
        for (int i = 0; i < 4; ++i) {
            int mL = wy * 32 + mt * 16 + kq * 4 + i;
            #pragma unroll
            for (int nt = 0; nt < 4; ++nt) {
                int nL = wx * 64 + nt * 16 + l15;
                Tu[mL * 129 + nL] = f2bf(acc[mt][nt][i] * ISCALE);
            }
        }
    }
    __syncthreads();

    unsigned short* Zs = Zp + (long long)blockIdx.z * 2555904;
    #pragma unroll
    for (int s2 = 0; s2 < 32; ++s2) {
        int id = tid + s2 * 256;
        int cL = id >> 6;
        int mL = id & 63;
        int n = n0 + cL;
        int bb = n / 156, cc = n - bb * 156;
        Zs[(long long)cc * 16384 + bb * 512 + m0 + mL] = Tu[mL * 129 + cL];
    }
}

// ---------------------------------------------------------------------------
// Branch-2 layer-2 GEMM: C[b][m][c] = sum_h Wl2[m][h] * L1T[c][b*512+h]
// ---------------------------------------------------------------------------
__global__ __launch_bounds__(256) void gemm2B_mfma(
    const unsigned short* __restrict__ Ap,   // [2][32][512] Wl2 planes
    const unsigned short* __restrict__ L1T,  // [156][16384] bf16 spikes
    float* __restrict__ Cl2)                 // [32][20][156]
{
    __shared__ alignas(16) unsigned short As[2][32][72];
    __shared__ alignas(16) unsigned short Bs[128][72];

    const int b  = blockIdx.z;
    const int n0 = blockIdx.x * 128;
    const int tid  = threadIdx.x;
    const int lane = tid & 63, w = tid >> 6;
    const int l15 = lane & 15, kq = lane >> 4;

    f32x4 acc[2][2] = {};

    for (int k0 = 0; k0 < 512; k0 += 64) {
        #pragma unroll
        for (int s = 0; s < 2; ++s) {
            int id = tid + s * 256;
            int pl = id >> 8, rem = id & 255;
            int m = rem >> 3, k8 = (rem & 7) * 8;
            ushort8v v = *(const ushort8v*)(Ap + (long long)pl * 16384 +
                                            (long long)m * 512 + k0 + k8);
            *(ushort8v*)&As[pl][m][k8] = v;
        }
        #pragma unroll
        for (int s = 0; s < 4; ++s) {
            int id = tid + s * 256;
            int n = id >> 3, k8 = (id & 7) * 8;
            ushort8v v = {0,0,0,0,0,0,0,0};
            if (n0 + n < 156)
                v = *(const ushort8v*)(L1T + (long long)(n0 + n) * 16384 +
                                       b * 512 + k0 + k8);
            *(ushort8v*)&Bs[n][k8] = v;
        }
        __syncthreads();

        #pragma unroll
        for (int ks = 0; ks < 2; ++ks) {
            bf16x8 bfr[2];
            #pragma unroll
            for (int nt = 0; nt < 2; ++nt)
                bfr[nt] = *(const bf16x8*)&Bs[w * 32 + nt * 16 + l15][ks * 32 + kq * 8];
            #pragma unroll
            for (int s = 0; s < 2; ++s) {
                #pragma unroll
                for (int mt = 0; mt < 2; ++mt) {
                    bf16x8 afr = *(const bf16x8*)&As[s][mt * 16 + l15][ks * 32 + kq * 8];
                    #pragma unroll
                    for (int nt = 0; nt < 2; ++nt)
                        acc[mt][nt] = __builtin_amdgcn_mfma_f32_16x16x32_bf16(
                            afr, bfr[nt], acc[mt][nt], 0, 0, 0);
                }
            }
        }
        __syncthreads();
    }

    float* Cb = Cl2 + (long long)b * 20 * 156;
    #pragma unroll
    for (int mt = 0; mt < 2; ++mt) {
        #pragma unroll
        for (int i = 0; i < 4; ++i) {
            int m = mt * 16 + kq * 4 + i;
            if (m >= 20) continue;
            #pragma unroll
            for (int nt = 0; nt < 2; ++nt) {
                int n = n0 + w * 32 + nt * 16 + l15;
                if (n < 156) Cb[(long long)m * 156 + n] = acc[mt][nt][i];
            }
        }
    }
}

// ---------------------------------------------------------------------------
// Final T-scan summing two split-K partials -> fp32 spikes to d_out.
// ---------------------------------------------------------------------------
__global__ __launch_bounds__(256) void scan_spike_T2(
    const float* __restrict__ in, long long partStride,
    float* __restrict__ out, long long out_stride)
{
    const int row = blockIdx.x;
    const int tid = threadIdx.x;
    const float* x = in + (long long)row * 2048 + tid * 8;

    float v[8];
    #pragma unroll
    for (int k = 0; k < 8; ++k) v[k] = x[k] + x[k + partStride];

    float y = 0.f;
    #pragma unroll
    for (int k = 0; k < 8; ++k) { y = ALPHA * y + v[k]; v[k] = y; }

    __shared__ float sc[256];
    float val = y;
    sc[tid] = val;
    float m = ALPHA8;
    for (int d = 1; d < 256; d <<= 1) {
        __syncthreads();
        float p = (tid >= d) ? sc[tid - d] : 0.f;
        __syncthreads();
        val += m * p;
        sc[tid] = val;
        m *= m;
    }
    __syncthreads();
    float carry = (tid > 0) ? sc[tid - 1] : 0.f;

    float* o = out + (long long)row * out_stride + tid * 8;
    float ak = ALPHA;
    #pragma unroll
    for (int k = 0; k < 8; ++k) {
        float yk = v[k] + ak * carry;
        ak *= ALPHA;
        o[k] = (yk >= THETA) ? 1.0f : 0.0f;
    }
}

// ---------------------------------------------------------------------------
// Branch-2 layer-1 scan, c-major: sum 4 BF16 partials Zp[s][c][row]
// (coalesced), scan over c in perm order via LDS, spikes -> L1T[c][row].
// ---------------------------------------------------------------------------
__global__ __launch_bounds__(256) void scan_sum4_perm(
    const unsigned short* __restrict__ Zp, const int* __restrict__ perm,
    unsigned short* __restrict__ L1T)
{
    __shared__ float Xs[156][64];
    __shared__ int p[156];

    const int r0  = blockIdx.x * 64;
    const int tid = threadIdx.x;
    for (int i = tid; i < 156; i += 256) p[i] = perm[i];

    const int row = tid & 63;
    const int cq  = tid >> 6;
    #pragma unroll
    for (int it = 0; it < 39; ++it) {
        int c = it * 4 + cq;
        long long base = (long long)c * 16384 + r0 + row;
        float s = bf2f(Zp[base]) + bf2f(Zp[base + 2555904]) +
                  bf2f(Zp[base + 2 * 2555904]) + bf2f(Zp[base + 3 * 2555904]);
        Xs[c][row] = s;
    }
    __syncthreads();

    if (tid < 64) {
        float y = 0.f;
        for (int c = 0; c < 156; ++c) {
            y = ALPHA * y + Xs[p[c]][tid];
            L1T[(long long)c * 16384 + r0 + tid] = (y >= THETA) ? BF1 : 0;
        }
    }
}

__global__ __launch_bounds__(256) void scan_spike_C_out(
    const float* __restrict__ in, float* __restrict__ out, int rows)
{
    int row = blockIdx.x * blockDim.x + threadIdx.x;
    if (row >= rows) return;
    const float* x = in + (long long)row * 156;
    float* o = out + (long long)row * 2204 + 2048;
    float y = 0.f;
    for (int c = 0; c < 156; ++c) {
        y = ALPHA * y + x[c];
        o[c] = (y >= THETA) ? 1.0f : 0.0f;
    }
}

// ---------------------------------------------------------------------------
// B=32, C_IN=156, T=2048, HID=512, OUT=20. Output [32,20,2204].
// ---------------------------------------------------------------------------
extern "C" void kernel_launch(void* const* d_in, const int* in_sizes, int n_in,
                              void* d_out, int out_size, void* d_ws, size_t ws_size,
                              hipStream_t stream)
{
    const float* In  = (const float*)d_in[0];  // [32][156][2048]
    const float* W1  = (const float*)d_in[1];  // [512][156]
    const float* W2  = (const float*)d_in[2];  // [20][512]
    const float* Wl1 = (const float*)d_in[3];  // [512][2048]
    const float* Wl2 = (const float*)d_in[4];  // [20][512]
    const int*  perm = (const int*)d_in[5];    // [156]
    float* out = (float*)d_out;                // [32][20][2204]

    float* ws = (float*)d_ws;
    // Disjoint layout (float offsets), total ~95 MB (ws is 256 MiB):
    unsigned short* S1bits = (unsigned short*)ws;              // [32][512][128]
    float* C2p = ws + 1048576LL;                               // [2][32][20][2048]
    unsigned char*  Infp8 = (unsigned char*)(ws + 3670016LL);  // [4992][2048] fp8
    unsigned short* Pbf  = (unsigned short*)(ws + 6225920LL);  // [4992][2048]
    unsigned short* PT   = (unsigned short*)(ws + 11337728LL); // [32][2048][160]
    unsigned short* W1p  = (unsigned short*)(ws + 16580608LL); // [2][512][160]
    unsigned char*  W2p8 = (unsigned char*)(ws + 16662528LL);  // [2][32][512] fp8
    unsigned char*  Wl1p8= (unsigned char*)(ws + 16670720LL);  // [2][512][2048] fp8
    unsigned short* Wl2p = (unsigned short*)(ws + 17195008LL); // [2][32][512]
    unsigned short* Zpbf = (unsigned short*)(ws + 17211392LL); // [4][156][16384] bf16
    unsigned short* L1T  = (unsigned short*)(ws + 22323200LL); // [156][16384]
    float* Cl2 = ws + 23601152LL;                              // [32][20][156]

    dim3 blk(256);

    // ---- Preprocess (fused scan + pack) ----
    prep_scan_pack<<<dim3(6080), blk, 0, stream>>>(
        In, Infp8, Pbf, W1, W2, Wl1, Wl2, W1p, W2p8, Wl1p8, Wl2p);
    transposeP<<<dim3(32, 3, 32), blk, 0, stream>>>(Pbf, PT);

    // ---- Branch 1: u = W1*psp(In); spike fused + bit-packed ----
    gemm1_mfma<<<dim3(16, 4, 32), blk, 0, stream>>>(W1p, PT, S1bits);
    gemm2_fp8<<<dim3(16, 2, 32), blk, 0, stream>>>(W2p8, S1bits, C2p, 256, 1310720LL);
    scan_spike_T2<<<dim3(640), blk, 0, stream>>>(C2p, 1310720LL, out, 2204);

    // ---- Branch 2 (fp8 GEMM over fp8 binary input) ----
    gemmL1_fp8<<<dim3(40, 8, 4), blk, 0, stream>>>(Wl1p8, Infp8, Zpbf);
    scan_sum4_perm<<<dim3(256), blk, 0, stream>>>(Zpbf, perm, L1T);
    gemm2B_mfma<<<dim3(2, 1, 32), blk, 0, stream>>>(Wl2p, L1T, Cl2);
    scan_spike_C_out<<<dim3(3), blk, 0, stream>>>(Cl2, out, 640);

    (void)in_sizes; (void)n_in; (void)out_size; (void)ws_size;
}

// Round 15
// 207.367 us; speedup vs baseline: 1.4778x; 1.0419x over previous
//
#include <hip/hip_runtime.h>

// SLAYER constants
#define ALPHA  0.90483741803595952f   /* exp(-1/10) */
#define ALPHA8 0.44932896411722156f   /* exp(-0.8)  */
#define THETA  10.0f
#define BF1    ((unsigned short)0x3F80) /* 1.0f as bf16 */
#define ISCALE 0.015625f               /* 1/64, exact */

typedef short   bf16x8 __attribute__((ext_vector_type(8)));
typedef float   f32x4  __attribute__((ext_vector_type(4)));
typedef float   f32x4v __attribute__((ext_vector_type(4)));
typedef unsigned short ushort4v __attribute__((ext_vector_type(4)));
typedef unsigned short ushort8v __attribute__((ext_vector_type(8)));
typedef unsigned char  uchar4v  __attribute__((ext_vector_type(4)));
typedef unsigned char  uchar8v  __attribute__((ext_vector_type(8)));
typedef long long i64;

// RNE float -> bf16 bits
__device__ __forceinline__ unsigned short f2bf(float f) {
    unsigned int x = __float_as_uint(f);
    unsigned int r = (x + 0x7FFFu + ((x >> 16) & 1u)) >> 16;
    return (unsigned short)r;
}
__device__ __forceinline__ float bf2f(unsigned short h) {
    return __uint_as_float(((unsigned int)h) << 16);
}
// 2-way bf16 split: w ~= h0+h1 (residual ~2^-17 rel)
__device__ __forceinline__ void split2(float w, unsigned short& h0,
                                       unsigned short& h1) {
    h0 = f2bf(w);          float r0 = w - bf2f(h0);
    h1 = f2bf(r0);
}
// HW fp8 converts
__device__ __forceinline__ unsigned char f2fp8(float f) {
    int pk = __builtin_amdgcn_cvt_pk_fp8_f32(f, 0.f, 0, false);
    return (unsigned char)(pk & 0xFF);
}
__device__ __forceinline__ float fp82f(unsigned char b) {
    return __builtin_amdgcn_cvt_f32_fp8((int)b, 0);
}

// ---------------------------------------------------------------------------
// prep_scan_pack: fused input prep + weight packing (unchanged from r14).
// ---------------------------------------------------------------------------
__global__ __launch_bounds__(256) void prep_scan_pack(
    const float* __restrict__ In, unsigned char* __restrict__ Infp8,
    unsigned short* __restrict__ Pbf,
    const float* __restrict__ W1,  const float* __restrict__ W2,
    const float* __restrict__ Wl1, const float* __restrict__ Wl2,
    unsigned short* __restrict__ W1p,  unsigned char* __restrict__ W2p8,
    unsigned char* __restrict__ Wl1p8, unsigned short* __restrict__ Wl2p)
{
    const int blk = blockIdx.x;
    if (blk >= 4992) {
        const int bidx = blk - 4992;
        if (bidx >= 512 && bidx < 544) {            // W2 -> fp8 split-2
            int m = bidx - 512;
            for (int k = threadIdx.x; k < 512; k += 256) {
                float w = (m < 20) ? W2[(long long)m * 512 + k] : 0.f;
                unsigned char h0 = f2fp8(w);
                unsigned char h1 = f2fp8(w - fp82f(h0));
                W2p8[(long long)m * 512 + k] = h0;
                W2p8[16384 + (long long)m * 512 + k] = h1;
            }
        } else if (bidx >= 544 && bidx < 1056) {    // Wl1 -> fp8 split-2, x64
            int m = bidx - 544;
            for (int k = threadIdx.x; k < 2048; k += 256) {
                float w = Wl1[(long long)m * 2048 + k] * 64.0f;
                unsigned char h0 = f2fp8(w);
                unsigned char h1 = f2fp8(w - fp82f(h0));
                Wl1p8[(long long)m * 2048 + k] = h0;
                Wl1p8[1048576 + (long long)m * 2048 + k] = h1;
            }
        } else {                                    // W1 / Wl2 -> bf16 split-2
            const float* W; unsigned short* P; int M, K, Kp, Mp, m;
            if (bidx < 512) { W = W1;  P = W1p;  M = 512; K = 156; Kp = 160; Mp = 512; m = bidx; }
            else            { W = Wl2; P = Wl2p; M = 20;  K = 512; Kp = 512; Mp = 32;  m = bidx - 1056; }
            for (int k = threadIdx.x; k < Kp; k += 256) {
                float v = (m < M && k < K) ? W[(long long)m * K + k] : 0.f;
                unsigned short h0, h1;
                split2(v, h0, h1);
                P[(long long)m * Kp + k] = h0;
                P[(long long)Mp * Kp + (long long)m * Kp + k] = h1;
            }
        }
        return;
    }

    const int row = blk;
    const int tid = threadIdx.x;
    const float* x = In + (long long)row * 2048 + tid * 8;
    const unsigned char ONE8 = f2fp8(1.0f);

    float v[8];
    *(f32x4v*)&v[0] = *(const f32x4v*)x;
    *(f32x4v*)&v[4] = *(const f32x4v*)(x + 4);

    uchar8v raw;
    #pragma unroll
    for (int k = 0; k < 8; ++k) raw[k] = (v[k] >= 0.5f) ? ONE8 : (unsigned char)0;
    *(uchar8v*)(Infp8 + (long long)row * 2048 + tid * 8) = raw;

    float y = 0.f;
    #pragma unroll
    for (int k = 0; k < 8; ++k) { y = ALPHA * y + v[k]; v[k] = y; }

    __shared__ float sc[256];
    float val = y;
    sc[tid] = val;
    float m = ALPHA8;
    for (int d = 1; d < 256; d <<= 1) {
        __syncthreads();
        float p = (tid >= d) ? sc[tid - d] : 0.f;
        __syncthreads();
        val += m * p;
        sc[tid] = val;
        m *= m;
    }
    __syncthreads();
    float carry = (tid > 0) ? sc[tid - 1] : 0.f;

    ushort8v pv;
    float ak = ALPHA;
    #pragma unroll
    for (int k = 0; k < 8; ++k) {
        float yk = v[k] + ak * carry;
        ak *= ALPHA;
        pv[k] = f2bf(yk);
    }
    *(ushort8v*)(Pbf + (long long)row * 2048 + tid * 8) = pv;
}

// ---------------------------------------------------------------------------
// transposeP: Pbf [32*156][2048] bf16 -> PT [32][2048][160] (c padded to 160).
// ---------------------------------------------------------------------------
__global__ __launch_bounds__(256) void transposeP(
    const unsigned short* __restrict__ Pbf, unsigned short* __restrict__ PT)
{
    __shared__ unsigned short Tile[64][72];
    const int t0 = blockIdx.x * 64;
    const int c0 = blockIdx.y * 64;
    const int b  = blockIdx.z;
    const int tid = threadIdx.x;

    #pragma unroll
    for (int s = 0; s < 2; ++s) {
        int id = tid + s * 256;
        int cc = id >> 3;
        int t8 = (id & 7) * 8;
        ushort8v v = {0,0,0,0,0,0,0,0};
        if (c0 + cc < 156)
            v = *(const ushort8v*)(Pbf + (long long)(b * 156 + c0 + cc) * 2048 + t0 + t8);
        *(ushort8v*)&Tile[cc][t8] = v;
    }
    __syncthreads();

    #pragma unroll
    for (int s = 0; s < 2; ++s) {
        int id = tid + s * 256;
        int t  = id >> 3;
        int c8 = (id & 7) * 8;
        if (c0 + c8 + 7 < 160) {
            unsigned short r[8];
            #pragma unroll
            for (int j = 0; j < 8; ++j) r[j] = Tile[c8 + j][t];
            *(ushort8v*)(PT + (long long)b * 327680 + (long long)(t0 + t) * 160 + c0 + c8)
                = *(ushort8v*)r;
        }
    }
}

// ---------------------------------------------------------------------------
// MEGA1: blocks [0,2048)  = branch-1 GEMM1 (bf16 MFMA, fused threshold,
//                           bit-packed spike output)
//        blocks [2048,3328) = branch-2 GEMM1 (fp8 MFMA, split-K x4), laid out
//                           n + 40*(m + 8*ks) to preserve XCD mod-8 reuse.
// ---------------------------------------------------------------------------
__global__ __launch_bounds__(256) void mega_gemm1(
    const unsigned short* __restrict__ W1p,
    const unsigned short* __restrict__ PT,
    unsigned short* __restrict__ S1bits,     // [32][512][128]
    const unsigned char* __restrict__ Wl1p8, // [2][512][2048] fp8
    const unsigned char* __restrict__ Infp8, // [4992][2048] fp8
    unsigned short* __restrict__ Zp)         // [4][156][16384] c-major bf16
{
    __shared__ alignas(16) unsigned char SMEM[30720];
    const int bx  = blockIdx.x;
    const int tid = threadIdx.x;
    const int lane = tid & 63, w = tid >> 6;
    const int wy = w >> 1, wx = w & 1;
    const int l15 = lane & 15, kq = lane >> 4;

    if (bx < 2048) {
        // ================= branch-1 GEMM1 =================
        auto As = (unsigned short (*)[128][40])SMEM;       // [2][128][40]
        auto Bs = (unsigned short (*)[40])(SMEM + 20480);  // [128][40]

        const int z  = bx >> 6;
        const int m0 = ((bx >> 4) & 3) * 128;
        const int n0 = (bx & 15) * 128;
        const unsigned short* Tb = PT + (long long)z * 327680;

        int aPl[4], aM[4], aK8[4];
        #pragma unroll
        for (int s = 0; s < 4; ++s) {
            int id = tid + s * 256;
            aPl[s] = id >> 9; int rem = id & 511;
            aM[s] = rem >> 2; aK8[s] = (rem & 3) * 8;
        }
        int bT[2], bC8[2];
        #pragma unroll
        for (int s = 0; s < 2; ++s) {
            int id = tid + s * 256;
            bT[s] = id >> 2; bC8[s] = (id & 3) * 8;
        }

        f32x4 acc[4][4] = {};
        ushort8v aReg[4], bReg[2];

        #pragma unroll
        for (int s = 0; s < 4; ++s)
            aReg[s] = *(const ushort8v*)(W1p + (long long)aPl[s] * 81920 +
                                         (long long)(m0 + aM[s]) * 160 + aK8[s]);
        #pragma unroll
        for (int s = 0; s < 2; ++s)
            bReg[s] = *(const ushort8v*)(Tb + (long long)(n0 + bT[s]) * 160 + bC8[s]);
        #pragma unroll
        for (int s = 0; s < 4; ++s) *(ushort8v*)&As[aPl[s]][aM[s]][aK8[s]] = aReg[s];
        #pragma unroll
        for (int s = 0; s < 2; ++s) *(ushort8v*)&Bs[bT[s]][bC8[s]] = bReg[s];
        __syncthreads();

        #pragma unroll
        for (int it = 0; it < 5; ++it) {
            const int kn = (it + 1) * 32;
            if (it < 4) {
                #pragma unroll
                for (int s = 0; s < 4; ++s)
                    aReg[s] = *(const ushort8v*)(W1p + (long long)aPl[s] * 81920 +
                                                 (long long)(m0 + aM[s]) * 160 + kn + aK8[s]);
                #pragma unroll
                for (int s = 0; s < 2; ++s)
                    bReg[s] = *(const ushort8v*)(Tb + (long long)(n0 + bT[s]) * 160 + kn + bC8[s]);
            }

            bf16x8 bfr[4];
            #pragma unroll
            for (int nt = 0; nt < 4; ++nt)
                bfr[nt] = *(const bf16x8*)&Bs[wx * 64 + nt * 16 + l15][kq * 8];
            #pragma unroll
            for (int s = 0; s < 2; ++s) {
                #pragma unroll
                for (int mt = 0; mt < 4; ++mt) {
                    bf16x8 afr = *(const bf16x8*)&As[s][wy * 64 + mt * 16 + l15][kq * 8];
                    #pragma unroll
                    for (int nt = 0; nt < 4; ++nt)
                        acc[mt][nt] = __builtin_amdgcn_mfma_f32_16x16x32_bf16(
                            afr, bfr[nt], acc[mt][nt], 0, 0, 0);
                }
            }
            __syncthreads();
            if (it < 4) {
                #pragma unroll
                for (int s = 0; s < 4; ++s) *(ushort8v*)&As[aPl[s]][aM[s]][aK8[s]] = aReg[s];
                #pragma unroll
                for (int s = 0; s < 2; ++s) *(ushort8v*)&Bs[bT[s]][bC8[s]] = bReg[s];
                __syncthreads();
            }
        }

        unsigned short* Db = S1bits + (long long)z * 512 * 128;
        #pragma unroll
        for (int mt = 0; mt < 4; ++mt) {
            #pragma unroll
            for (int i = 0; i < 4; ++i) {
                int m = m0 + wy * 64 + mt * 16 + kq * 4 + i;
                #pragma unroll
                for (int nt = 0; nt < 4; ++nt) {
                    unsigned long long mask = __ballot(acc[mt][nt][i] >= THETA);
                    if (l15 == 0) {
                        int nchunk = (n0 + wx * 64 + nt * 16) >> 4;
                        Db[(long long)m * 128 + nchunk] =
                            (unsigned short)((mask >> (kq * 16)) & 0xFFFFu);
                    }
                }
            }
        }
    } else {
        // ================= branch-2 GEMM1 (fp8) =================
        auto As8 = (unsigned char (*)[64][72])SMEM;        // [2][64][72]
        auto Bs8 = (unsigned char (*)[72])(SMEM + 9216);   // [128][72]

        const int id0 = bx - 2048;
        const int nIdx = id0 % 40;
        if (nIdx >= 39) return;
        const int rest = id0 / 40;
        const int n0  = nIdx * 128;
        const int m0  = (rest & 7) * 64;
        const int ksl = rest >> 3;
        const int ks0 = ksl * 512;

        int aPl[4], aM[4], aK8[4];
        #pragma unroll
        for (int s = 0; s < 4; ++s) {
            int id = tid + s * 256;
            aPl[s] = id >> 9; int rem = id & 511;
            aM[s] = rem >> 3; aK8[s] = (rem & 7) * 8;
        }
        int bN[4], bK8[4];
        #pragma unroll
        for (int s = 0; s < 4; ++s) {
            int id = tid + s * 256;
            bN[s] = id >> 3; bK8[s] = (id & 7) * 8;
        }

        f32x4 acc[2][4] = {};
        uchar8v aReg[4], bReg[4];

        #pragma unroll
        for (int s = 0; s < 4; ++s)
            aReg[s] = *(const uchar8v*)(Wl1p8 + (long long)aPl[s] * 1048576 +
                                        (long long)(m0 + aM[s]) * 2048 + ks0 + aK8[s]);
        #pragma unroll
        for (int s = 0; s < 4; ++s)
            bReg[s] = *(const uchar8v*)(Infp8 + (long long)(n0 + bN[s]) * 2048 + ks0 + bK8[s]);
        #pragma unroll
        for (int s = 0; s < 4; ++s) *(uchar8v*)&As8[aPl[s]][aM[s]][aK8[s]] = aReg[s];
        #pragma unroll
        for (int s = 0; s < 4; ++s) *(uchar8v*)&Bs8[bN[s]][bK8[s]] = bReg[s];
        __syncthreads();

        for (int it = 0; it < 8; ++it) {
            const int kn = ks0 + (it + 1) * 64;
            if (it < 7) {
                #pragma unroll
                for (int s = 0; s < 4; ++s)
                    aReg[s] = *(const uchar8v*)(Wl1p8 + (long long)aPl[s] * 1048576 +
                                                (long long)(m0 + aM[s]) * 2048 + kn + aK8[s]);
                #pragma unroll
                for (int s = 0; s < 4; ++s)
                    bReg[s] = *(const uchar8v*)(Infp8 + (long long)(n0 + bN[s]) * 2048 + kn + bK8[s]);
            }

            #pragma unroll
            for (int ks = 0; ks < 2; ++ks) {
                i64 bfr[4];
                #pragma unroll
                for (int nt = 0; nt < 4; ++nt)
                    bfr[nt] = *(const i64*)&Bs8[wx * 64 + nt * 16 + l15][ks * 32 + kq * 8];
                #pragma unroll
                for (int s = 0; s < 2; ++s) {
                    #pragma unroll
                    for (int mt = 0; mt < 2; ++mt) {
                        i64 afr = *(const i64*)&As8[s][wy * 32 + mt * 16 + l15][ks * 32 + kq * 8];
                        #pragma unroll
                        for (int nt = 0; nt < 4; ++nt)
                            acc[mt][nt] = __builtin_amdgcn_mfma_f32_16x16x32_fp8_fp8(
                                afr, bfr[nt], acc[mt][nt], 0, 0, 0);
                    }
                }
            }
            __syncthreads();
            if (it < 7) {
                #pragma unroll
                for (int s = 0; s < 4; ++s) *(uchar8v*)&As8[aPl[s]][aM[s]][aK8[s]] = aReg[s];
                #pragma unroll
                for (int s = 0; s < 4; ++s) *(uchar8v*)&Bs8[bN[s]][bK8[s]] = bReg[s];
                __syncthreads();
            }
        }

        unsigned short* Tu = (unsigned short*)SMEM;
        #pragma unroll
        for (int mt = 0; mt < 2; ++mt) {
            #pragma unroll
            for (int i = 0; i < 4; ++i) {
                int mL = wy * 32 + mt * 16 + kq * 4 + i;
                #pragma unroll
                for (int nt = 0; nt < 4; ++nt) {
                    int nL = wx * 64 + nt * 16 + l15;
                    Tu[mL * 129 + nL] = f2bf(acc[mt][nt][i] * ISCALE);
                }
            }
        }
        __syncthreads();

        unsigned short* Zs = Zp + (long long)ksl * 2555904;
        #pragma unroll
        for (int s2 = 0; s2 < 32; ++s2) {
            int id = tid + s2 * 256;
            int cL = id >> 6;
            int mL = id & 63;
            int n = n0 + cL;
            int bb = n / 156, cc = n - bb * 156;
            Zs[(long long)cc * 16384 + bb * 512 + m0 + mL] = Tu[mL * 129 + cL];
        }
    }
}

// ---------------------------------------------------------------------------
// MEGA2: blocks [0,1024)    = branch-1 GEMM2 (fp8 MFMA, split-K x2, bit-
//                             expanded B)
//        blocks [1024,1536) = branch-2 scan_sum4_perm (32 rows/block)
// ---------------------------------------------------------------------------
__global__ __launch_bounds__(256) void mega_stage2(
    const unsigned char* __restrict__ W2p8,
    const unsigned short* __restrict__ S1bits,
    float* __restrict__ C2p,
    const unsigned short* __restrict__ Zp,
    const int* __restrict__ perm,
    unsigned short* __restrict__ L1T)
{
    __shared__ alignas(16) unsigned char SMEM[20608];
    const int bx  = blockIdx.x;
    const int tid = threadIdx.x;

    if (bx < 1024) {
        // ================= gemm2 fp8 =================
        auto As = (unsigned char (*)[32][72])SMEM;        // [2][32][72]
        auto Bs = (unsigned char (*)[72])(SMEM + 4608);   // [128][72]

        const int lane = tid & 63, w = tid >> 6;
        const int l15 = lane & 15, kq = lane >> 4;
        const int n0  = (bx & 15) * 128;
        const int ksl = (bx >> 4) & 1;
        const int b   = bx >> 5;
        const int ks0 = ksl * 256;

        const unsigned short* Bb = S1bits + (long long)b * 512 * 128;
        const unsigned char ONE8 = f2fp8(1.0f);

        int aPl[2], aM[2], aK8[2];
        #pragma unroll
        for (int s = 0; s < 2; ++s) {
            int id = tid + s * 256;
            aPl[s] = id >> 8; int rem = id & 255;
            aM[s] = rem >> 3; aK8[s] = (rem & 7) * 8;
        }
        const int kb = (tid >> 4) * 4;
        const int nb = (tid & 15) * 8;
        const int nchunk = (n0 + nb) >> 4;
        const int nshift = nb & 15;

        f32x4 acc[2][2] = {};
        uchar8v aReg[2];
        unsigned short bBits[4];

        auto loadA = [&](int k0) {
            #pragma unroll
            for (int s = 0; s < 2; ++s)
                aReg[s] = *(const uchar8v*)(W2p8 + (long long)aPl[s] * 16384 +
                                            (long long)aM[s] * 512 + k0 + aK8[s]);
        };
        auto loadB = [&](int k0) {
            #pragma unroll
            for (int kk2 = 0; kk2 < 4; ++kk2)
                bBits[kk2] = Bb[(long long)(k0 + kb + kk2) * 128 + nchunk];
        };
        auto stage = [&]() {
            #pragma unroll
            for (int s = 0; s < 2; ++s) *(uchar8v*)&As[aPl[s]][aM[s]][aK8[s]] = aReg[s];
            unsigned char bv[4][8];
            #pragma unroll
            for (int kk2 = 0; kk2 < 4; ++kk2) {
                unsigned int bits = ((unsigned int)bBits[kk2] >> nshift) & 0xFFu;
                #pragma unroll
                for (int j = 0; j < 8; ++j)
                    bv[kk2][j] = ((bits >> j) & 1u) ? ONE8 : (unsigned char)0;
            }
            #pragma unroll
            for (int j = 0; j < 8; ++j) {
                uchar4v v4 = { bv[0][j], bv[1][j], bv[2][j], bv[3][j] };
                *(uchar4v*)&Bs[nb + j][kb] = v4;
            }
        };

        loadA(ks0); loadB(ks0);
        stage();
        __syncthreads();

        #pragma unroll
        for (int it = 0; it < 4; ++it) {
            const int kn = ks0 + (it + 1) * 64;
            if (it < 3) { loadA(kn); loadB(kn); }

            #pragma unroll
            for (int ks = 0; ks < 2; ++ks) {
                i64 bfr[2];
                #pragma unroll
                for (int nt = 0; nt < 2; ++nt)
                    bfr[nt] = *(const i64*)&Bs[w * 32 + nt * 16 + l15][ks * 32 + kq * 8];
                #pragma unroll
                for (int s = 0; s < 2; ++s) {
                    #pragma unroll
                    for (int mt = 0; mt < 2; ++mt) {
                        i64 afr = *(const i64*)&As[s][mt * 16 + l15][ks * 32 + kq * 8];
                        #pragma unroll
                        for (int nt = 0; nt < 2; ++nt)
                            acc[mt][nt] = __builtin_amdgcn_mfma_f32_16x16x32_fp8_fp8(
                                afr, bfr[nt], acc[mt][nt], 0, 0, 0);
                    }
                }
            }
            __syncthreads();
            if (it < 3) {
                stage();
                __syncthreads();
            }
        }

        float* Cb = C2p + (long long)b * 20 * 2048 + (long long)ksl * 1310720LL;
        #pragma unroll
        for (int mt = 0; mt < 2; ++mt) {
            #pragma unroll
            for (int i = 0; i < 4; ++i) {
                int m = mt * 16 + kq * 4 + i;
                if (m >= 20) continue;
                #pragma unroll
                for (int nt = 0; nt < 2; ++nt) {
                    int n = n0 + w * 32 + nt * 16 + l15;
                    Cb[(long long)m * 2048 + n] = acc[mt][nt][i];
                }
            }
        }
    } else {
        // ================= scan_sum4_perm (32 rows/block) =================
        auto Xs = (float (*)[32])SMEM;              // [156][32] = 19968 B
        int* p  = (int*)(SMEM + 19968);             // [156]

        const int r0 = (bx - 1024) * 32;
        for (int i = tid; i < 156; i += 256) p[i] = perm[i];

        const int row = tid & 31;
        const int cq  = tid >> 5;                   // 0..7
        #pragma unroll
        for (int it = 0; it < 20; ++it) {
            int c = it * 8 + cq;
            if (c < 156) {
                long long base = (long long)c * 16384 + r0 + row;
                float s = bf2f(Zp[base]) + bf2f(Zp[base + 2555904]) +
                          bf2f(Zp[base + 2 * 2555904]) + bf2f(Zp[base + 3 * 2555904]);
                Xs[c][row] = s;
            }
        }
        __syncthreads();

        if (tid < 32) {
            float y = 0.f;
            for (int c = 0; c < 156; ++c) {
                y = ALPHA * y + Xs[p[c]][tid];
                L1T[(long long)c * 16384 + r0 + tid] = (y >= THETA) ? BF1 : 0;
            }
        }
    }
}

// ---------------------------------------------------------------------------
// MEGA3: blocks [0,640)   = branch-1 final T-scan (sum 2 partials -> spikes)
//        blocks [640,704) = branch-2 GEMM2 (bf16 MFMA)
// ---------------------------------------------------------------------------
__global__ __launch_bounds__(256) void mega_stage3(
    const float* __restrict__ C2p, float* __restrict__ out,
    const unsigned short* __restrict__ Wl2p,
    const unsigned short* __restrict__ L1T,
    float* __restrict__ Cl2)
{
    __shared__ alignas(16) unsigned char SMEM[27648];
    const int bx  = blockIdx.x;
    const int tid = threadIdx.x;

    if (bx < 640) {
        // ================= scan_spike_T2 =================
        float* sc = (float*)SMEM;
        const int row = bx;
        const float* x = C2p + (long long)row * 2048 + tid * 8;

        float v[8];
        #pragma unroll
        for (int k = 0; k < 8; ++k) v[k] = x[k] + x[k + 1310720LL];

        float y = 0.f;
        #pragma unroll
        for (int k = 0; k < 8; ++k) { y = ALPHA * y + v[k]; v[k] = y; }

        float val = y;
        sc[tid] = val;
        float m = ALPHA8;
        for (int d = 1; d < 256; d <<= 1) {
            __syncthreads();
            float p = (tid >= d) ? sc[tid - d] : 0.f;
            __syncthreads();
            val += m * p;
            sc[tid] = val;
            m *= m;
        }
        __syncthreads();
        float carry = (tid > 0) ? sc[tid - 1] : 0.f;

        float* o = out + (long long)row * 2204 + tid * 8;
        float ak = ALPHA;
        #pragma unroll
        for (int k = 0; k < 8; ++k) {
            float yk = v[k] + ak * carry;
            ak *= ALPHA;
            o[k] = (yk >= THETA) ? 1.0f : 0.0f;
        }
    } else {
        // ================= gemm2B (bf16) =================
        auto As = (unsigned short (*)[32][72])SMEM;         // [2][32][72]
        auto Bs = (unsigned short (*)[72])(SMEM + 9216);    // [128][72]

        const int id2 = bx - 640;
        const int n0 = (id2 & 1) * 128;
        const int b  = id2 >> 1;
        const int lane = tid & 63, w = tid >> 6;
        const int l15 = lane & 15, kq = lane >> 4;

        f32x4 acc[2][2] = {};

        for (int k0 = 0; k0 < 512; k0 += 64) {
            #pragma unroll
            for (int s = 0; s < 2; ++s) {
                int id = tid + s * 256;
                int pl = id >> 8, rem = id & 255;
                int m = rem >> 3, k8 = (rem & 7) * 8;
                ushort8v v = *(const ushort8v*)(Wl2p + (long long)pl * 16384 +
                                                (long long)m * 512 + k0 + k8);
                *(ushort8v*)&As[pl][m][k8] = v;
            }
            #pragma unroll
            for (int s = 0; s < 4; ++s) {
                int id = tid + s * 256;
                int n = id >> 3, k8 = (id & 7) * 8;
                ushort8v v = {0,0,0,0,0,0,0,0};
                if (n0 + n < 156)
                    v = *(const ushort8v*)(L1T + (long long)(n0 + n) * 16384 +
                                           b * 512 + k0 + k8);
                *(ushort8v*)&Bs[n][k8] = v;
            }
            __syncthreads();

            #pragma unroll
            for (int ks = 0; ks < 2; ++ks) {
                bf16x8 bfr[2];
                #pragma unroll
                for (int nt = 0; nt < 2; ++nt)
                    bfr[nt] = *(const bf16x8*)&Bs[w * 32 + nt * 16 + l15][ks * 32 + kq * 8];
                #pragma unroll
                for (int s = 0; s < 2; ++s) {
                    #pragma unroll
                    for (int mt = 0; mt < 2; ++mt) {
                        bf16x8 afr = *(const bf16x8*)&As[s][mt * 16 + l15][ks * 32 + kq * 8];
                        #pragma unroll
                        for (int nt = 0; nt < 2; ++nt)
                            acc[mt][nt] = __builtin_amdgcn_mfma_f32_16x16x32_bf16(
                                afr, bfr[nt], acc[mt][nt], 0, 0, 0);
                    }
                }
            }
            __syncthreads();
        }

        float* Cb = Cl2 + (long long)b * 20 * 156;
        #pragma unroll
        for (int mt = 0; mt < 2; ++mt) {
            #pragma unroll
            for (int i = 0; i < 4; ++i) {
                int m = mt * 16 + kq * 4 + i;
                if (m >= 20) continue;
                #pragma unroll
                for (int nt = 0; nt < 2; ++nt) {
                    int n = n0 + w * 32 + nt * 16 + l15;
                    if (n < 156) Cb[(long long)m * 156 + n] = acc[mt][nt][i];
                }
            }
        }
    }
}

// ---------------------------------------------------------------------------
// Final branch-2 output scan (length 156 per row, 640 rows).
// ---------------------------------------------------------------------------
__global__ __launch_bounds__(256) void scan_spike_C_out(
    const float* __restrict__ in, float* __restrict__ out, int rows)
{
    int row = blockIdx.x * blockDim.x + threadIdx.x;
    if (row >= rows) return;
    const float* x = in + (long long)row * 156;
    float* o = out + (long long)row * 2204 + 2048;
    float y = 0.f;
    for (int c = 0; c < 156; ++c) {
        y = ALPHA * y + x[c];
        o[c] = (y >= THETA) ? 1.0f : 0.0f;
    }
}

// ---------------------------------------------------------------------------
// B=32, C_IN=156, T=2048, HID=512, OUT=20. Output [32,20,2204].
// ---------------------------------------------------------------------------
extern "C" void kernel_launch(void* const* d_in, const int* in_sizes, int n_in,
                              void* d_out, int out_size, void* d_ws, size_t ws_size,
                              hipStream_t stream)
{
    const float* In  = (const float*)d_in[0];  // [32][156][2048]
    const float* W1  = (const float*)d_in[1];  // [512][156]
    const float* W2  = (const float*)d_in[2];  // [20][512]
    const float* Wl1 = (const float*)d_in[3];  // [512][2048]
    const float* Wl2 = (const float*)d_in[4];  // [20][512]
    const int*  perm = (const int*)d_in[5];    // [156]
    float* out = (float*)d_out;                // [32][20][2204]

    float* ws = (float*)d_ws;
    // Disjoint layout (float offsets), total ~95 MB (ws is 256 MiB):
    unsigned short* S1bits = (unsigned short*)ws;              // [32][512][128]
    float* C2p = ws + 1048576LL;                               // [2][32][20][2048]
    unsigned char*  Infp8 = (unsigned char*)(ws + 3670016LL);  // [4992][2048] fp8
    unsigned short* Pbf  = (unsigned short*)(ws + 6225920LL);  // [4992][2048]
    unsigned short* PT   = (unsigned short*)(ws + 11337728LL); // [32][2048][160]
    unsigned short* W1p  = (unsigned short*)(ws + 16580608LL); // [2][512][160]
    unsigned char*  W2p8 = (unsigned char*)(ws + 16662528LL);  // [2][32][512] fp8
    unsigned char*  Wl1p8= (unsigned char*)(ws + 16670720LL);  // [2][512][2048] fp8
    unsigned short* Wl2p = (unsigned short*)(ws + 17195008LL); // [2][32][512]
    unsigned short* Zpbf = (unsigned short*)(ws + 17211392LL); // [4][156][16384] bf16
    unsigned short* L1T  = (unsigned short*)(ws + 22323200LL); // [156][16384]
    float* Cl2 = ws + 23601152LL;                              // [32][20][156]

    dim3 blk(256);

    // ---- Preprocess (fused scan + pack) ----
    prep_scan_pack<<<dim3(6080), blk, 0, stream>>>(
        In, Infp8, Pbf, W1, W2, Wl1, Wl2, W1p, W2p8, Wl1p8, Wl2p);
    transposeP<<<dim3(32, 3, 32), blk, 0, stream>>>(Pbf, PT);

    // ---- Stage 1: both branch GEMM1s in one launch ----
    mega_gemm1<<<dim3(3328), blk, 0, stream>>>(W1p, PT, S1bits,
                                               Wl1p8, Infp8, Zpbf);
    // ---- Stage 2: branch-1 GEMM2 + branch-2 perm-scan ----
    mega_stage2<<<dim3(1536), blk, 0, stream>>>(W2p8, S1bits, C2p,
                                                Zpbf, perm, L1T);
    // ---- Stage 3: branch-1 final scan + branch-2 GEMM2 ----
    mega_stage3<<<dim3(704), blk, 0, stream>>>(C2p, out, Wl2p, L1T, Cl2);
    // ---- Branch-2 output scan ----
    scan_spike_C_out<<<dim3(3), blk, 0, stream>>>(Cl2, out, 640);

    (void)in_sizes; (void)n_in; (void)out_size; (void)ws_size;
}